// Round 1
// baseline (4821.099 us; speedup 1.0000x reference)
//
#include <hip/hip_runtime.h>
#include <stdint.h>

#define BLOCK 256
#define KMAX 8
#define NWAVES (BLOCK / 64)

// One block per image. Greedy sequential scan; per-step work parallelized
// over the block. All per-proposal data held in registers (8 elems/thread).
__global__ __launch_bounds__(BLOCK) void tagloss_kernel(
    const float* __restrict__ pred,       // (IMGS, N, 4)
    const int*   __restrict__ gt_inds,    // (IMGS, N)
    const float* __restrict__ proposals,  // (IMGS, N, 5)
    float*       __restrict__ ws,         // (IMGS, 2): push, pull per image
    int N)
{
    const int img  = blockIdx.x;
    const int t    = threadIdx.x;
    const int lane = t & 63;
    const int wav  = t >> 6;

    const float* P = proposals + (size_t)img * N * 5;
    const float* E = pred      + (size_t)img * N * 4;
    const int*   G = gt_inds   + (size_t)img * N;

    float x1[KMAX], y1[KMAX], x2[KMAX], y2[KMAX], sc[KMAX];
    float e0[KMAX], e1[KMAX], e2[KMAX], e3[KMAX];
    int   gt[KMAX];
    unsigned amask = 0u;   // per-thread alive bits (element k*BLOCK+t)
    int local_alive = 0;

#pragma unroll
    for (int k = 0; k < KMAX; ++k) {
        int j = k * BLOCK + t;
        if (j < N) {
            x1[k] = P[j*5+0]; y1[k] = P[j*5+1];
            x2[k] = P[j*5+2]; y2[k] = P[j*5+3];
            sc[k] = P[j*5+4];
            e0[k] = E[j*4+0]; e1[k] = E[j*4+1];
            e2[k] = E[j*4+2]; e3[k] = E[j*4+3];
            gt[k] = G[j];
            // valid = (gt >= 0) & (height > MIN_HEIGHT=0.0)
            if (gt[k] >= 0 && (y2[k] - y1[k]) > 0.0f) { amask |= 1u << k; local_alive++; }
        } else {
            x1[k]=y1[k]=x2[k]=y2[k]=0.f; sc[k]=0.f;
            e0[k]=e1[k]=e2[k]=e3[k]=0.f; gt[k]=-1;
        }
    }

    __shared__ unsigned long long s_key[NWAVES];
    __shared__ float s_b[9];              // broadcast: box(4), tag(4), gt
    __shared__ float s_part[NWAVES][5];   // cross-wave partials

    // ---- initial alive count (block sum) ----
    int alive_count;
    {
        float v = (float)local_alive;
#pragma unroll
        for (int o = 32; o > 0; o >>= 1) v += __shfl_down(v, o);
        if (lane == 0) s_part[wav][0] = v;
        __syncthreads();
        float tot = 0.f;
#pragma unroll
        for (int w = 0; w < NWAVES; ++w) tot += s_part[w][0];
        alive_count = (int)tot;
    }

    float tot_pull = 0.f, tot_push = 0.f, pull_cnt = 0.f, push_cnt = 0.f;

    // Once sum(alive) < 2 the reference scan is a frozen no-op: exact early exit.
    while (alive_count >= 2) {
        // ---- phase A: argmax over alive scores (tie -> lowest index) ----
        unsigned long long key = 0ull;
#pragma unroll
        for (int k = 0; k < KMAX; ++k) {
            if (amask & (1u << k)) {
                // scores are >= 0 so float bits order as unsigned
                unsigned long long kk =
                    ((unsigned long long)__float_as_uint(sc[k]) << 32)
                    | (unsigned long long)(0xFFFFFFFFu - (unsigned)(k*BLOCK + t));
                if (kk > key) key = kk;
            }
        }
#pragma unroll
        for (int o = 32; o > 0; o >>= 1) {
            unsigned long long ok = __shfl_down(key, o);
            if (ok > key) key = ok;
        }
        if (lane == 0) s_key[wav] = key;
        __syncthreads();                                  // S1
        unsigned long long bk = s_key[0];
#pragma unroll
        for (int w = 1; w < NWAVES; ++w) if (s_key[w] > bk) bk = s_key[w];
        const int i = (int)(0xFFFFFFFFu - (unsigned)(bk & 0xFFFFFFFFull));

        // owner thread broadcasts element i's data
        if ((i & (BLOCK - 1)) == t) {
            int k = i / BLOCK;
            s_b[0]=x1[k]; s_b[1]=y1[k]; s_b[2]=x2[k]; s_b[3]=y2[k];
            s_b[4]=e0[k]; s_b[5]=e1[k]; s_b[6]=e2[k]; s_b[7]=e3[k];
            s_b[8]=__int_as_float(gt[k]);
        }
        __syncthreads();                                  // S2
        const float bx1=s_b[0], by1=s_b[1], bx2=s_b[2], by2=s_b[3];
        const float f0=s_b[4], f1=s_b[5], f2=s_b[6], f3=s_b[7];
        const int   bgt = __float_as_int(s_b[8]);
        const float areai = (bx2-bx1)*(by2-by1);

        // ---- phase B: elementwise over rem = alive \ {i} ----
        float psum=0.f, qsum=0.f, pn=0.f, qn=0.f, scnt=0.f;
#pragma unroll
        for (int k = 0; k < KMAX; ++k) {
            if (!(amask & (1u << k))) continue;
            int j = k*BLOCK + t;
            if (j == i) { amask &= ~(1u << k); continue; }   // remove i itself
            float iw = fmaxf(fminf(x2[k],bx2) - fmaxf(x1[k],bx1), 0.f);
            float ih = fmaxf(fminf(y2[k],by2) - fmaxf(y1[k],by1), 0.f);
            float inter = iw * ih;
            float uni = (x2[k]-x1[k])*(y2[k]-y1[k]) + areai - inter;
            float iou = inter / fmaxf(uni, 1e-12f);
            if (iou > 0.f) {
                float d0=e0[k]-f0, d1=e1[k]-f1, d2=e2[k]-f2, d3=e3[k]-f3;
                float diff = 0.25f*(d0*d0 + d1*d1 + d2*d2 + d3*d3);  // mean over D=4
                bool check = diff < 0.1f;   // TAG_THR
                bool same  = (gt[k] == bgt);
                if (same && !check) { psum += diff * sc[k];         pn += 1.f; }
                if (!same && check) { qsum += __expf(-diff)*sc[k];  qn += 1.f; }
                if (check)          { amask &= ~(1u << k);          scnt += 1.f; }
            }
        }

        // ---- block reduce 5 sums ----
        float r0=psum, r1=pn, r2=qsum, r3=qn, r4=scnt;
#pragma unroll
        for (int o = 32; o > 0; o >>= 1) {
            r0 += __shfl_down(r0,o); r1 += __shfl_down(r1,o);
            r2 += __shfl_down(r2,o); r3 += __shfl_down(r3,o);
            r4 += __shfl_down(r4,o);
        }
        if (lane == 0) {
            s_part[wav][0]=r0; s_part[wav][1]=r1; s_part[wav][2]=r2;
            s_part[wav][3]=r3; s_part[wav][4]=r4;
        }
        __syncthreads();                                  // S3
        float T0=0.f,T1=0.f,T2=0.f,T3=0.f,T4=0.f;
#pragma unroll
        for (int w = 0; w < NWAVES; ++w) {
            T0+=s_part[w][0]; T1+=s_part[w][1]; T2+=s_part[w][2];
            T3+=s_part[w][3]; T4+=s_part[w][4];
        }
        if (T1 > 0.f) { tot_pull += T0 / T1; pull_cnt += 1.f; }
        if (T3 > 0.f) { tot_push += T2 / T3; push_cnt += 1.f; }
        alive_count -= 1 + (int)T4;
    }

    if (t == 0) {
        ws[img*2 + 0] = tot_push / (push_cnt + 1e-6f);  // push per image
        ws[img*2 + 1] = tot_pull / (pull_cnt + 1e-6f);  // pull per image
    }
}

__global__ void finalize_kernel(const float* __restrict__ ws,
                                float* __restrict__ out, int imgs)
{
    if (threadIdx.x == 0 && blockIdx.x == 0) {
        float push = 0.f, pull = 0.f;
        for (int k = 0; k < imgs; ++k) { push += ws[2*k]; pull += ws[2*k+1]; }
        float inv = 1.0f / (float)imgs;
        out[0] = push * inv;   // push_loss (PUSH_WEIGHT = 1)
        out[1] = pull * inv;   // pull_loss (PULL_WEIGHT = 1)
    }
}

extern "C" void kernel_launch(void* const* d_in, const int* in_sizes, int n_in,
                              void* d_out, int out_size, void* d_ws, size_t ws_size,
                              hipStream_t stream) {
    const float* pred      = (const float*)d_in[0];
    const int*   gt_inds   = (const int*)  d_in[1];
    const float* proposals = (const float*)d_in[2];
    // d_in[3] = gt_bboxes: unused by the reference loss

    const int imgs = in_sizes[3] / 80;        // gt_bboxes is (IMGS, 20, 4)
    const int N    = in_sizes[1] / imgs;      // gt_inds is (IMGS, N)

    float* ws = (float*)d_ws;                 // 2*imgs floats, fully overwritten

    tagloss_kernel<<<imgs, BLOCK, 0, stream>>>(pred, gt_inds, proposals, ws, N);
    finalize_kernel<<<1, 64, 0, stream>>>(ws, (float*)d_out, imgs);
}

// Round 2
// 669.614 us; speedup vs baseline: 7.1998x; 7.1998x over previous
//
#include <hip/hip_runtime.h>
#include <stdint.h>

#define BLOCK 256
#define KMAX 8
#define NWAVES (BLOCK / 64)
#define S2 2048          // padded N (pow2 for bitonic sort); N=2000 fits
#define NW 32            // 64-bit words per row (S2/64)

// =====================================================================
// NEW PATH: sort -> suppression bitmatrix -> 1-wave NMS scan -> parallel
// per-step pair sums. The only sequential part is the scan, which has no
// reductions/barriers in its loop body.
// =====================================================================

// K1: per-image bitonic sort by (score desc, idx asc); emit sorted SoA,
// validity (init dead mask), and effective_rank init (INF valid / 0 invalid).
__global__ __launch_bounds__(BLOCK) void sort_kernel(
    const float* __restrict__ pred, const int* __restrict__ gt_inds,
    const float* __restrict__ proposals,
    float* __restrict__ soa, int* __restrict__ sgt,
    int* __restrict__ eff, unsigned long long* __restrict__ init_dead,
    int N, int imgs)
{
    const int img = blockIdx.x, t = threadIdx.x;
    __shared__ unsigned long long key[S2];
    const float* P = proposals + (size_t)img * N * 5;
    const float* E = pred      + (size_t)img * N * 4;
    const int*   G = gt_inds   + (size_t)img * N;

    for (int k = 0; k < 8; ++k) {
        int p = k * BLOCK + t;
        float sc = (p < N) ? P[p*5 + 4] : 0.f;
        // ascending sort == score desc (inverted bits; scores >= 0), idx asc
        key[p] = ((unsigned long long)(~__float_as_uint(sc)) << 32) | (unsigned)p;
    }
    __syncthreads();
    for (int sz = 2; sz <= S2; sz <<= 1)
        for (int st = sz >> 1; st > 0; st >>= 1) {
            for (int m = 0; m < 8; ++m) {
                int i = m * BLOCK + t, l = i ^ st;
                if (l > i) {
                    bool up = ((i & sz) == 0);
                    unsigned long long a = key[i], b = key[l];
                    if ((a > b) == up) { key[i] = b; key[l] = a; }
                }
            }
            __syncthreads();
        }

    const size_t stride = (size_t)imgs * S2;
    const size_t base   = (size_t)img * S2;
    for (int k = 0; k < 8; ++k) {
        int p = k * BLOCK + t;
        int orig = (int)(key[p] & 0xFFFFFFFFull);
        bool real = (p < N);   // pads have max keys -> sort last
        float x1=0,y1=0,x2=0,y2=0,sc=0,e0=0,e1=0,e2=0,e3=0; int g = -1;
        if (real) {
            x1 = P[orig*5+0]; y1 = P[orig*5+1];
            x2 = P[orig*5+2]; y2 = P[orig*5+3]; sc = P[orig*5+4];
            e0 = E[orig*4+0]; e1 = E[orig*4+1];
            e2 = E[orig*4+2]; e3 = E[orig*4+3]; g = G[orig];
        }
        soa[0*stride + base + p] = x1; soa[1*stride + base + p] = y1;
        soa[2*stride + base + p] = x2; soa[3*stride + base + p] = y2;
        soa[4*stride + base + p] = sc;
        soa[5*stride + base + p] = e0; soa[6*stride + base + p] = e1;
        soa[7*stride + base + p] = e2; soa[8*stride + base + p] = e3;
        sgt[base + p] = g;
        bool valid = real && (g >= 0) && ((y2 - y1) > 0.f);  // MIN_HEIGHT=0
        eff[base + p] = valid ? 0x7FFFFFFF : 0;
        unsigned long long db = __ballot(!valid);
        if ((t & 63) == 0) init_dead[(size_t)img * NW + (k*4 + (t>>6))] = db;
    }
}

// K2: suppression bitmatrix in sorted space. suppress(i,j) = inter>0 && diff<TAG_THR.
__global__ __launch_bounds__(BLOCK) void supmat_kernel(
    const float* __restrict__ soa, unsigned long long* __restrict__ sup,
    int N, int imgs)
{
    const int i = blockIdx.x, img = blockIdx.y, t = threadIdx.x;
    const size_t stride = (size_t)imgs * S2, base = (size_t)img * S2;
    unsigned long long* row = sup + ((size_t)img * S2 + i) * NW;
    if (i >= N) { if (t < NW) row[t] = 0ull; return; }
    const float bx1 = soa[0*stride+base+i], by1 = soa[1*stride+base+i];
    const float bx2 = soa[2*stride+base+i], by2 = soa[3*stride+base+i];
    const float f0  = soa[5*stride+base+i], f1  = soa[6*stride+base+i];
    const float f2  = soa[7*stride+base+i], f3  = soa[8*stride+base+i];
    for (int k = 0; k < 8; ++k) {
        int j = k * BLOCK + t;
        bool s = false;
        if (j < N) {
            float iw = fminf(soa[2*stride+base+j], bx2) - fmaxf(soa[0*stride+base+j], bx1);
            float ih = fminf(soa[3*stride+base+j], by2) - fmaxf(soa[1*stride+base+j], by1);
            if (iw > 0.f && ih > 0.f) {
                float d0 = soa[5*stride+base+j]-f0, d1 = soa[6*stride+base+j]-f1;
                float d2 = soa[7*stride+base+j]-f2, d3 = soa[8*stride+base+j]-f3;
                float diff = 0.25f*(d0*d0 + d1*d1 + d2*d2 + d3*d3);
                s = diff < 0.1f;   // TAG_THR
            }
        }
        unsigned long long bb = __ballot(s);
        if ((t & 63) == 0) row[k*4 + (t>>6)] = bb;
    }
}

// K3: sequential NMS scan, one wave per image. Lane l<32 owns dead-mask word l.
// No reductions in the loop: per-step alive snapshots are fire-and-forget
// stores, resolved by nsteps_kernel.
__global__ __launch_bounds__(64) void scan_kernel(
    const unsigned long long* __restrict__ sup,
    const unsigned long long* __restrict__ init_dead,
    int* __restrict__ eff, int* __restrict__ sel,
    unsigned int* __restrict__ stepcnt, int* __restrict__ nsel)
{
    const int img = blockIdx.x, l = threadIdx.x;
    const unsigned long long* S = sup + (size_t)img * S2 * NW;
    unsigned long long dead = (l < NW) ? init_dead[(size_t)img*NW + l] : ~0ull;
    int r = 0;
    unsigned long long ring[8];
#pragma unroll
    for (int d = 0; d < 8; ++d) ring[d] = (l < NW) ? S[(size_t)d*NW + l] : 0ull;

    for (int base = 0; base < S2; base += 8) {
#pragma unroll
        for (int d = 0; d < 8; ++d) {
            const int i = base + d;
            unsigned long long row = ring[d];
            const int nx = i + 8;
            ring[d] = (nx < S2 && l < NW) ? S[(size_t)nx*NW + l] : 0ull;
            const int io = i >> 6;
            unsigned long long dw = __shfl(dead, io);
            if (!((dw >> (i & 63)) & 1ull)) {
                // i is alive -> selector with rank r
                if (l < NW)
                    stepcnt[((size_t)img*S2 + r)*NW + l] = (unsigned)__popcll(dead);
                unsigned long long newly = row & ~dead;
                if (l == io) newly &= ~(1ull << (i & 63));   // not self
                unsigned long long nb = newly;
                while (nb) {
                    int b = __ffsll((unsigned long long)nb) - 1;
                    nb &= nb - 1;
                    eff[(size_t)img*S2 + l*64 + b] = r + 1;  // suppressed at r -> contributes thru r
                }
                dead |= newly;
                if (l == io) {
                    dead |= (1ull << (i & 63));
                    eff[(size_t)img*S2 + i] = r;             // selector -> contributes thru r-1
                }
                if (l == 0) sel[(size_t)img*S2 + r] = i;
                ++r;
            }
        }
    }
    if (l == 0) nsel[img] = r;
}

// K4: exact alive<2 cutoff + zero the accumulators for K5.
__global__ __launch_bounds__(BLOCK) void nsteps_kernel(
    const unsigned int* __restrict__ stepcnt, const int* __restrict__ nsel,
    int* __restrict__ nsteps, float* __restrict__ acc)
{
    const int img = blockIdx.x, t = threadIdx.x;
    if (t < 4) acc[img*4 + t] = 0.f;
    const int S = nsel[img];
    int best = 0x7FFFFFFF;
    for (int r = t; r < S; r += BLOCK) {
        unsigned s = 0;
        const unsigned* p = stepcnt + ((size_t)img*S2 + r)*NW;
        for (int l = 0; l < NW; ++l) s += p[l];
        if ((int)(S2 - (int)s) < 2) best = min(best, r);
    }
    __shared__ int sm[NWAVES];
    for (int o = 32; o > 0; o >>= 1) best = min(best, __shfl_down(best, o));
    if ((t & 63) == 0) sm[t >> 6] = best;
    __syncthreads();
    if (t == 0) {
        int b = sm[0];
        for (int w = 1; w < NWAVES; ++w) b = min(b, sm[w]);
        nsteps[img] = min(b, S);
    }
}

// K5: fully parallel per-step pair sums. Block (r, img).
__global__ __launch_bounds__(BLOCK) void pairs_kernel(
    const float* __restrict__ soa, const int* __restrict__ sgt,
    const int* __restrict__ eff, const int* __restrict__ sel,
    const int* __restrict__ nsteps, float* __restrict__ acc,
    int N, int imgs)
{
    const int r = blockIdx.x, img = blockIdx.y, t = threadIdx.x;
    if (r >= nsteps[img]) return;
    const size_t stride = (size_t)imgs * S2, base = (size_t)img * S2;
    const int p = sel[(size_t)img*S2 + r];
    const float bx1 = soa[0*stride+base+p], by1 = soa[1*stride+base+p];
    const float bx2 = soa[2*stride+base+p], by2 = soa[3*stride+base+p];
    const float f0  = soa[5*stride+base+p], f1  = soa[6*stride+base+p];
    const float f2  = soa[7*stride+base+p], f3  = soa[8*stride+base+p];
    const int   bgt = sgt[base + p];

    float psum = 0.f, pn = 0.f, qsum = 0.f, qn = 0.f;
    for (int k = 0; k < 8; ++k) {
        int j = k * BLOCK + t;
        if (j >= N) continue;
        if (r >= eff[base + j]) continue;        // removed before/at selection (self: eff==r)
        float iw = fminf(soa[2*stride+base+j], bx2) - fmaxf(soa[0*stride+base+j], bx1);
        float ih = fminf(soa[3*stride+base+j], by2) - fmaxf(soa[1*stride+base+j], by1);
        if (iw > 0.f && ih > 0.f) {
            float d0 = soa[5*stride+base+j]-f0, d1 = soa[6*stride+base+j]-f1;
            float d2 = soa[7*stride+base+j]-f2, d3 = soa[8*stride+base+j]-f3;
            float diff = 0.25f*(d0*d0 + d1*d1 + d2*d2 + d3*d3);
            bool check = diff < 0.1f;
            bool same  = (sgt[base + j] == bgt);
            float sc   = soa[4*stride+base+j];
            if (same && !check)      { psum += diff * sc;       pn += 1.f; }
            else if (!same && check) { qsum += expf(-diff)*sc;  qn += 1.f; }
        }
    }
    for (int o = 32; o > 0; o >>= 1) {
        psum += __shfl_down(psum, o); pn += __shfl_down(pn, o);
        qsum += __shfl_down(qsum, o); qn += __shfl_down(qn, o);
    }
    __shared__ float sp[NWAVES][4];
    if ((t & 63) == 0) {
        int w = t >> 6;
        sp[w][0] = psum; sp[w][1] = pn; sp[w][2] = qsum; sp[w][3] = qn;
    }
    __syncthreads();
    if (t == 0) {
        float P = 0, Pn = 0, Q = 0, Qn = 0;
        for (int w = 0; w < NWAVES; ++w) {
            P += sp[w][0]; Pn += sp[w][1]; Q += sp[w][2]; Qn += sp[w][3];
        }
        if (Pn > 0.f) { atomicAdd(&acc[img*4+0], P / Pn); atomicAdd(&acc[img*4+1], 1.f); }
        if (Qn > 0.f) { atomicAdd(&acc[img*4+2], Q / Qn); atomicAdd(&acc[img*4+3], 1.f); }
    }
}

__global__ void finalize2_kernel(const float* __restrict__ acc,
                                 float* __restrict__ out, int imgs)
{
    if (threadIdx.x == 0 && blockIdx.x == 0) {
        float push = 0.f, pull = 0.f;
        for (int i = 0; i < imgs; ++i) {
            pull += acc[i*4+0] / (acc[i*4+1] + 1e-6f);
            push += acc[i*4+2] / (acc[i*4+3] + 1e-6f);
        }
        out[0] = push / (float)imgs;   // push_loss
        out[1] = pull / (float)imgs;   // pull_loss
    }
}

// =====================================================================
// FALLBACK PATH (R1 kernel) — used only if ws_size is too small / N>2048.
// =====================================================================
__global__ __launch_bounds__(BLOCK) void tagloss_kernel(
    const float* __restrict__ pred, const int* __restrict__ gt_inds,
    const float* __restrict__ proposals, float* __restrict__ ws, int N)
{
    const int img = blockIdx.x, t = threadIdx.x;
    const int lane = t & 63, wav = t >> 6;
    const float* P = proposals + (size_t)img * N * 5;
    const float* E = pred      + (size_t)img * N * 4;
    const int*   G = gt_inds   + (size_t)img * N;
    float x1[KMAX], y1[KMAX], x2[KMAX], y2[KMAX], sc[KMAX];
    float e0[KMAX], e1[KMAX], e2[KMAX], e3[KMAX];
    int gt[KMAX]; unsigned amask = 0u; int local_alive = 0;
#pragma unroll
    for (int k = 0; k < KMAX; ++k) {
        int j = k * BLOCK + t;
        if (j < N) {
            x1[k]=P[j*5+0]; y1[k]=P[j*5+1]; x2[k]=P[j*5+2]; y2[k]=P[j*5+3]; sc[k]=P[j*5+4];
            e0[k]=E[j*4+0]; e1[k]=E[j*4+1]; e2[k]=E[j*4+2]; e3[k]=E[j*4+3]; gt[k]=G[j];
            if (gt[k] >= 0 && (y2[k]-y1[k]) > 0.0f) { amask |= 1u<<k; local_alive++; }
        } else { x1[k]=y1[k]=x2[k]=y2[k]=0.f; sc[k]=0.f; e0[k]=e1[k]=e2[k]=e3[k]=0.f; gt[k]=-1; }
    }
    __shared__ unsigned long long s_key[NWAVES];
    __shared__ float s_b[9];
    __shared__ float s_part[NWAVES][5];
    int alive_count;
    {
        float v = (float)local_alive;
#pragma unroll
        for (int o = 32; o > 0; o >>= 1) v += __shfl_down(v, o);
        if (lane == 0) s_part[wav][0] = v;
        __syncthreads();
        float tot = 0.f;
        for (int w = 0; w < NWAVES; ++w) tot += s_part[w][0];
        alive_count = (int)tot;
    }
    float tot_pull=0.f, tot_push=0.f, pull_cnt=0.f, push_cnt=0.f;
    while (alive_count >= 2) {
        unsigned long long key = 0ull;
#pragma unroll
        for (int k = 0; k < KMAX; ++k)
            if (amask & (1u<<k)) {
                unsigned long long kk = ((unsigned long long)__float_as_uint(sc[k])<<32)
                                      | (unsigned long long)(0xFFFFFFFFu - (unsigned)(k*BLOCK+t));
                if (kk > key) key = kk;
            }
#pragma unroll
        for (int o = 32; o > 0; o >>= 1) {
            unsigned long long ok = __shfl_down(key, o);
            if (ok > key) key = ok;
        }
        if (lane == 0) s_key[wav] = key;
        __syncthreads();
        unsigned long long bk = s_key[0];
        for (int w = 1; w < NWAVES; ++w) if (s_key[w] > bk) bk = s_key[w];
        const int i = (int)(0xFFFFFFFFu - (unsigned)(bk & 0xFFFFFFFFull));
        if ((i & (BLOCK-1)) == t) {
            int k = i / BLOCK;
            s_b[0]=x1[k]; s_b[1]=y1[k]; s_b[2]=x2[k]; s_b[3]=y2[k];
            s_b[4]=e0[k]; s_b[5]=e1[k]; s_b[6]=e2[k]; s_b[7]=e3[k];
            s_b[8]=__int_as_float(gt[k]);
        }
        __syncthreads();
        const float bx1=s_b[0], by1=s_b[1], bx2=s_b[2], by2=s_b[3];
        const float f0=s_b[4], f1=s_b[5], f2=s_b[6], f3=s_b[7];
        const int bgt = __float_as_int(s_b[8]);
        const float areai = (bx2-bx1)*(by2-by1);
        float psum=0.f,qsum=0.f,pn=0.f,qn=0.f,scnt=0.f;
#pragma unroll
        for (int k = 0; k < KMAX; ++k) {
            if (!(amask & (1u<<k))) continue;
            int j = k*BLOCK+t;
            if (j == i) { amask &= ~(1u<<k); continue; }
            float iw = fmaxf(fminf(x2[k],bx2)-fmaxf(x1[k],bx1),0.f);
            float ih = fmaxf(fminf(y2[k],by2)-fmaxf(y1[k],by1),0.f);
            float inter = iw*ih;
            float uni = (x2[k]-x1[k])*(y2[k]-y1[k]) + areai - inter;
            float iou = inter / fmaxf(uni, 1e-12f);
            if (iou > 0.f) {
                float d0=e0[k]-f0,d1=e1[k]-f1,d2=e2[k]-f2,d3=e3[k]-f3;
                float diff = 0.25f*(d0*d0+d1*d1+d2*d2+d3*d3);
                bool check = diff < 0.1f;
                bool same = (gt[k]==bgt);
                if (same && !check) { psum += diff*sc[k]; pn += 1.f; }
                if (!same && check) { qsum += __expf(-diff)*sc[k]; qn += 1.f; }
                if (check)          { amask &= ~(1u<<k); scnt += 1.f; }
            }
        }
        float r0=psum,r1=pn,r2=qsum,r3=qn,r4=scnt;
#pragma unroll
        for (int o = 32; o > 0; o >>= 1) {
            r0+=__shfl_down(r0,o); r1+=__shfl_down(r1,o); r2+=__shfl_down(r2,o);
            r3+=__shfl_down(r3,o); r4+=__shfl_down(r4,o);
        }
        if (lane == 0) { s_part[wav][0]=r0;s_part[wav][1]=r1;s_part[wav][2]=r2;s_part[wav][3]=r3;s_part[wav][4]=r4; }
        __syncthreads();
        float T0=0,T1=0,T2=0,T3=0,T4=0;
        for (int w = 0; w < NWAVES; ++w) {
            T0+=s_part[w][0];T1+=s_part[w][1];T2+=s_part[w][2];T3+=s_part[w][3];T4+=s_part[w][4];
        }
        if (T1 > 0.f) { tot_pull += T0/T1; pull_cnt += 1.f; }
        if (T3 > 0.f) { tot_push += T2/T3; push_cnt += 1.f; }
        alive_count -= 1 + (int)T4;
    }
    if (t == 0) {
        ws[img*2+0] = tot_push / (push_cnt + 1e-6f);
        ws[img*2+1] = tot_pull / (pull_cnt + 1e-6f);
    }
}

__global__ void finalize_kernel(const float* __restrict__ ws,
                                float* __restrict__ out, int imgs)
{
    if (threadIdx.x == 0 && blockIdx.x == 0) {
        float push = 0.f, pull = 0.f;
        for (int k = 0; k < imgs; ++k) { push += ws[2*k]; pull += ws[2*k+1]; }
        out[0] = push / (float)imgs;
        out[1] = pull / (float)imgs;
    }
}

// =====================================================================
extern "C" void kernel_launch(void* const* d_in, const int* in_sizes, int n_in,
                              void* d_out, int out_size, void* d_ws, size_t ws_size,
                              hipStream_t stream) {
    const float* pred      = (const float*)d_in[0];
    const int*   gt_inds   = (const int*)  d_in[1];
    const float* proposals = (const float*)d_in[2];
    const int imgs = in_sizes[3] / 80;     // gt_bboxes (IMGS,20,4)
    const int N    = in_sizes[1] / imgs;   // gt_inds (IMGS,N)

    // ws layout for the parallel path
    size_t off = 0;
    auto alloc = [&](size_t b) { size_t o = off; off += (b + 255) & ~(size_t)255; return o; };
    const size_t soa_off   = alloc((size_t)9 * imgs * S2 * 4);
    const size_t sgt_off   = alloc((size_t)imgs * S2 * 4);
    const size_t eff_off   = alloc((size_t)imgs * S2 * 4);
    const size_t idead_off = alloc((size_t)imgs * NW * 8);
    const size_t sup_off   = alloc((size_t)imgs * S2 * NW * 8);
    const size_t scnt_off  = alloc((size_t)imgs * S2 * NW * 4);
    const size_t sel_off   = alloc((size_t)imgs * S2 * 4);
    const size_t nsel_off  = alloc((size_t)imgs * 4);
    const size_t nst_off   = alloc((size_t)imgs * 4);
    const size_t acc_off   = alloc((size_t)imgs * 16);
    const size_t need = off;

    if (N <= S2 && ws_size >= need) {
        char* w = (char*)d_ws;
        float*              soa  = (float*)(w + soa_off);
        int*                sgt  = (int*)(w + sgt_off);
        int*                eff  = (int*)(w + eff_off);
        unsigned long long* idd  = (unsigned long long*)(w + idead_off);
        unsigned long long* sup  = (unsigned long long*)(w + sup_off);
        unsigned int*       scnt = (unsigned int*)(w + scnt_off);
        int*                sel  = (int*)(w + sel_off);
        int*                nsel = (int*)(w + nsel_off);
        int*                nst  = (int*)(w + nst_off);
        float*              acc  = (float*)(w + acc_off);

        sort_kernel<<<imgs, BLOCK, 0, stream>>>(pred, gt_inds, proposals,
                                                soa, sgt, eff, idd, N, imgs);
        supmat_kernel<<<dim3(S2, imgs), BLOCK, 0, stream>>>(soa, sup, N, imgs);
        scan_kernel<<<imgs, 64, 0, stream>>>(sup, idd, eff, sel, scnt, nsel);
        nsteps_kernel<<<imgs, BLOCK, 0, stream>>>(scnt, nsel, nst, acc);
        pairs_kernel<<<dim3(S2, imgs), BLOCK, 0, stream>>>(soa, sgt, eff, sel,
                                                           nst, acc, N, imgs);
        finalize2_kernel<<<1, 64, 0, stream>>>(acc, (float*)d_out, imgs);
    } else {
        float* ws = (float*)d_ws;
        tagloss_kernel<<<imgs, BLOCK, 0, stream>>>(pred, gt_inds, proposals, ws, N);
        finalize_kernel<<<1, 64, 0, stream>>>(ws, (float*)d_out, imgs);
    }
}

// Round 3
// 383.562 us; speedup vs baseline: 12.5693x; 1.7458x over previous
//
#include <hip/hip_runtime.h>
#include <stdint.h>

#define BLOCK 256
#define KMAX 8
#define NWAVES (BLOCK / 64)
#define S2 2048          // padded N (pow2); N=2000 fits
#define NW 32            // 64-bit words per row (S2/64)
#define NCH 32           // 64-element chunks (S2/64)
#define EFF_INF 0x7FFFFFFF

// =====================================================================
// Pipeline: sort -> sup bitmatrix (symmetric) -> chunked greedy (only
// sequential part, ~32 steps) -> parallel eff/rank -> nsteps -> pairs.
// =====================================================================

// K1: per-image bitonic sort by (score desc, idx asc); emit sorted SoA + valid bits.
__global__ __launch_bounds__(BLOCK) void sort_kernel(
    const float* __restrict__ pred, const int* __restrict__ gt_inds,
    const float* __restrict__ proposals,
    float* __restrict__ soa, int* __restrict__ sgt,
    unsigned long long* __restrict__ validw,
    int N, int imgs)
{
    const int img = blockIdx.x, t = threadIdx.x;
    __shared__ unsigned long long key[S2];
    const float* P = proposals + (size_t)img * N * 5;
    const float* E = pred      + (size_t)img * N * 4;
    const int*   G = gt_inds   + (size_t)img * N;

    for (int k = 0; k < 8; ++k) {
        int p = k * BLOCK + t;
        float sc = (p < N) ? P[p*5 + 4] : 0.f;
        key[p] = ((unsigned long long)(~__float_as_uint(sc)) << 32) | (unsigned)p;
    }
    __syncthreads();
    for (int sz = 2; sz <= S2; sz <<= 1)
        for (int st = sz >> 1; st > 0; st >>= 1) {
            for (int m = 0; m < 8; ++m) {
                int i = m * BLOCK + t, l = i ^ st;
                if (l > i) {
                    bool up = ((i & sz) == 0);
                    unsigned long long a = key[i], b = key[l];
                    if ((a > b) == up) { key[i] = b; key[l] = a; }
                }
            }
            __syncthreads();
        }

    const size_t stride = (size_t)imgs * S2;
    const size_t base   = (size_t)img * S2;
    for (int k = 0; k < 8; ++k) {
        int p = k * BLOCK + t;
        int orig = (int)(key[p] & 0xFFFFFFFFull);
        bool real = (p < N);
        float x1=0,y1=0,x2=0,y2=0,sc=0,e0=0,e1=0,e2=0,e3=0; int g = -1;
        if (real) {
            x1 = P[orig*5+0]; y1 = P[orig*5+1];
            x2 = P[orig*5+2]; y2 = P[orig*5+3]; sc = P[orig*5+4];
            e0 = E[orig*4+0]; e1 = E[orig*4+1];
            e2 = E[orig*4+2]; e3 = E[orig*4+3]; g = G[orig];
        }
        soa[0*stride + base + p] = x1; soa[1*stride + base + p] = y1;
        soa[2*stride + base + p] = x2; soa[3*stride + base + p] = y2;
        soa[4*stride + base + p] = sc;
        soa[5*stride + base + p] = e0; soa[6*stride + base + p] = e1;
        soa[7*stride + base + p] = e2; soa[8*stride + base + p] = e3;
        sgt[base + p] = g;
        bool valid = real && (g >= 0) && ((y2 - y1) > 0.f);  // MIN_HEIGHT=0
        unsigned long long vb = __ballot(valid);
        if ((t & 63) == 0) validw[(size_t)img * NW + (k*4 + (t>>6))] = vb;
    }
}

// K2: symmetric suppression matrix, 64x64 tiles. sup(i,j)=inter>0 && diff<TAG_THR.
__global__ __launch_bounds__(BLOCK) void supmat_kernel(
    const float* __restrict__ soa, unsigned long long* __restrict__ sup,
    int N, int imgs)
{
    const int ic = blockIdx.x, jc = blockIdx.y, img = blockIdx.z;
    const int t = threadIdx.x, wave = t >> 6, lane = t & 63;
    const size_t stride = (size_t)imgs * S2, base = (size_t)img * S2;
    __shared__ float si[8][64];
    for (int idx = t; idx < 512; idx += BLOCK) {
        int f = idx >> 6, e = idx & 63;
        int a = (f < 4) ? f : f + 1;      // arrays {0,1,2,3,5,6,7,8}
        si[f][e] = soa[(size_t)a*stride + base + ic*64 + e];
    }
    __syncthreads();
    const int j = jc*64 + lane;
    const float jx1 = soa[0*stride+base+j], jy1 = soa[1*stride+base+j];
    const float jx2 = soa[2*stride+base+j], jy2 = soa[3*stride+base+j];
    const float j0  = soa[5*stride+base+j], j1  = soa[6*stride+base+j];
    const float j2  = soa[7*stride+base+j], j3  = soa[8*stride+base+j];
    const bool jin = (j < N);
    for (int ii = 0; ii < 16; ++ii) {
        int il = wave*16 + ii;
        int i  = ic*64 + il;
        float bx1 = si[0][il], by1 = si[1][il], bx2 = si[2][il], by2 = si[3][il];
        float f0  = si[4][il], f1  = si[5][il], f2  = si[6][il], f3  = si[7][il];
        bool s = false;
        if (jin && i < N) {
            float iw = fminf(jx2, bx2) - fmaxf(jx1, bx1);
            float ih = fminf(jy2, by2) - fmaxf(jy1, by1);
            if (iw > 0.f && ih > 0.f) {
                float d0 = j0-f0, d1 = j1-f1, d2 = j2-f2, d3 = j3-f3;
                float diff = 0.25f*(d0*d0 + d1*d1 + d2*d2 + d3*d3);
                s = diff < 0.1f;   // TAG_THR
            }
        }
        unsigned long long bb = __ballot(s);
        if (lane == 0) sup[((size_t)img*S2 + i)*NW + jc] = bb;
    }
}

// K3: THE sequential part — chunked Gauss-Seidel greedy, one wave per image.
// 32 chunks; per chunk: batched row loads + ballot-only bit-serial resolve.
__global__ __launch_bounds__(64) void greedy_kernel(
    const unsigned long long* __restrict__ sup,
    const unsigned long long* __restrict__ validw,
    unsigned long long* __restrict__ selw_out)
{
    const int img = blockIdx.x, l = threadIdx.x;
    const unsigned long long* S = sup + (size_t)img * S2 * NW;
    __shared__ unsigned long long ssel[NW];
    if (l < NW) ssel[l] = 0ull;
    __syncthreads();

    for (int c = 0; c < NCH; ++c) {
        const int j = c*64 + l;
        const unsigned long long* R = S + (size_t)j * NW;
        unsigned long long rw[NW];
#pragma unroll
        for (int w = 0; w < NW; ++w) rw[w] = R[w];      // one batched wait
        unsigned long long acc = 0ull;
#pragma unroll
        for (int w = 0; w < NW; ++w) acc |= rw[w] & ssel[w];  // ssel[w>=c]==0
        const unsigned long long vw = validw[(size_t)img*NW + c];
        bool aliveme = (((vw >> l) & 1ull) != 0ull) && (acc == 0ull);
        unsigned long long remaining = __ballot(aliveme);
        const unsigned long long local = rw[c];          // in-chunk suppressors of me
        unsigned long long sel = 0ull;
        while (remaining) {
            int i = __builtin_ctzll(remaining);          // lowest index alive -> greedy pick
            sel |= 1ull << i;
            unsigned long long row_i = __ballot(((local >> i) & 1ull) != 0ull);
            remaining &= ~row_i;                          // diag bit clears i itself
            remaining &= ~(1ull << i);
        }
        if (l == 0) {
            ssel[c] = sel;
            selw_out[(size_t)img*NW + c] = sel;
        }
        __syncthreads();
    }
}

// rank(j) = number of selected elements with sorted index < j
__device__ inline int rank_of(const unsigned long long* ss, int j) {
    int jw = j >> 6, jb = j & 63;
    int rk = __popcll(ss[jw] & (jb ? (~0ull >> (64 - jb)) : 0ull));
    for (int w = 0; w < jw; ++w) rk += __popcll(ss[w]);
    return rk;
}

// K4: fully parallel eff computation.
// eff: invalid->0; selected->rank; suppressed->rank(first selected suppressor)+1; survivor->INF
__global__ __launch_bounds__(BLOCK) void effrank_kernel(
    const unsigned long long* __restrict__ sup,
    const unsigned long long* __restrict__ validw,
    const unsigned long long* __restrict__ selw,
    int* __restrict__ eff)
{
    const int img = blockIdx.y;
    const int j = blockIdx.x * BLOCK + threadIdx.x;
    __shared__ unsigned long long ss[NW], vv[NW];
    if (threadIdx.x < NW) ss[threadIdx.x] = selw[(size_t)img*NW + threadIdx.x];
    else if (threadIdx.x < 2*NW) vv[threadIdx.x - NW] = validw[(size_t)img*NW + threadIdx.x - NW];
    __syncthreads();
    int jw = j >> 6, jb = j & 63;
    bool valid = (vv[jw] >> jb) & 1ull;
    bool selb  = (ss[jw] >> jb) & 1ull;
    int e;
    if (!valid) e = 0;
    else if (selb) e = rank_of(ss, j);
    else {
        const unsigned long long* R = sup + ((size_t)img*S2 + j)*NW;
        int istar = -1;
#pragma unroll
        for (int w = 0; w < NW; ++w) {
            unsigned long long f = R[w] & ss[w];
            if (istar < 0 && f) istar = w*64 + __builtin_ctzll(f);
        }
        e = (istar < 0) ? EFF_INF : (rank_of(ss, istar) + 1);
    }
    eff[(size_t)img*S2 + j] = e;
}

// K5: exact alive<2 cutoff via histogram + block prefix-sum; zero acc.
__global__ __launch_bounds__(BLOCK) void nsteps_kernel(
    const unsigned long long* __restrict__ validw,
    const unsigned long long* __restrict__ selw,
    const int* __restrict__ eff,
    int* __restrict__ nsteps, float* __restrict__ acc)
{
    const int img = blockIdx.x, t = threadIdx.x;
    const int lane = t & 63, wave = t >> 6;
    if (t < 4) acc[img*4 + t] = 0.f;
    __shared__ unsigned hist[S2];
    __shared__ unsigned long long ss[NW], vv[NW];
    __shared__ unsigned wsum[NWAVES];
    __shared__ int bm[NWAVES];
    if (t < NW) { ss[t] = selw[(size_t)img*NW + t]; vv[t] = validw[(size_t)img*NW + t]; }
    for (int x = t; x < S2; x += BLOCK) hist[x] = 0u;
    __syncthreads();
    int V = 0, Sc = 0;
    for (int w = 0; w < NW; ++w) { V += __popcll(vv[w]); Sc += __popcll(ss[w]); }
    for (int jj = t; jj < S2; jj += BLOCK) {
        int e = eff[(size_t)img*S2 + jj];
        int jw = jj >> 6, jb = jj & 63;
        bool valid = (vv[jw] >> jb) & 1ull, selb = (ss[jw] >> jb) & 1ull;
        if (valid && !selb && e != EFF_INF) atomicAdd(&hist[e - 1], 1u);
    }
    __syncthreads();
    // inclusive scan of hist[2048]: 8/thread local + wave scan + cross-wave
    unsigned loc[8]; unsigned s = 0;
#pragma unroll
    for (int k = 0; k < 8; ++k) { s += hist[t*8 + k]; loc[k] = s; }
    unsigned tot = s;
    for (int o = 1; o < 64; o <<= 1) {
        unsigned v = __shfl_up(tot, o);
        if (lane >= o) tot += v;
    }
    if (lane == 63) wsum[wave] = tot;
    __syncthreads();
    unsigned woff = 0;
    for (int w = 0; w < wave; ++w) woff += wsum[w];
    unsigned exclP = woff + tot - s;
    __syncthreads();
#pragma unroll
    for (int k = 0; k < 8; ++k) hist[t*8 + k] = exclP + loc[k];
    __syncthreads();
    int best = EFF_INF;
    for (int r = t; r < Sc; r += BLOCK) {
        unsigned rem = (r == 0) ? 0u : hist[r - 1];   // suppressed removed before step r
        int alive = V - r - (int)rem;
        if (alive < 2) best = min(best, r);
    }
    for (int o = 32; o > 0; o >>= 1) best = min(best, __shfl_down(best, o));
    if (lane == 0) bm[wave] = best;
    __syncthreads();
    if (t == 0) {
        int b = bm[0];
        for (int w = 1; w < NWAVES; ++w) b = min(b, bm[w]);
        nsteps[img] = min(b, Sc);
    }
}

// K6: pair sums, tiled: block = (selector chunk, img); wave handles 16 selectors.
__global__ __launch_bounds__(BLOCK) void pairs_kernel(
    const float* __restrict__ soa, const int* __restrict__ sgt,
    const int* __restrict__ eff, const unsigned long long* __restrict__ selw,
    const int* __restrict__ nsteps, float* __restrict__ acc,
    int N, int imgs)
{
    const int ic = blockIdx.x, img = blockIdx.y;
    const int t = threadIdx.x, wave = t >> 6, lane = t & 63;
    const int ns = nsteps[img];
    const size_t stride = (size_t)imgs * S2, base = (size_t)img * S2;
    __shared__ float sibf[8][64];
    __shared__ int sigt[64], sirk[64], siact[64];
    __shared__ unsigned long long ss[NW];
    if (t < NW) ss[t] = selw[(size_t)img*NW + t];
    __syncthreads();
    if (t < 64) {
        int i = ic*64 + t;
        int iw_ = i >> 6, ib = i & 63;
        bool selb = (ss[iw_] >> ib) & 1ull;
        int rk = rank_of(ss, i);
        sirk[t] = rk;
        siact[t] = (selb && rk < ns) ? 1 : 0;
        sigt[t] = sgt[base + i];
    }
    for (int idx = t; idx < 512; idx += BLOCK) {
        int f = idx >> 6, e = idx & 63;
        int a = (f < 4) ? f : f + 1;
        sibf[f][e] = soa[(size_t)a*stride + base + ic*64 + e];
    }
    __syncthreads();

    float ps[16], pn[16], qs[16], qn[16];
#pragma unroll
    for (int ii = 0; ii < 16; ++ii) { ps[ii]=0.f; pn[ii]=0.f; qs[ii]=0.f; qn[ii]=0.f; }

    for (int jt = 0; jt < NCH; ++jt) {
        const int j = jt*64 + lane;
        const float jx1 = soa[0*stride+base+j], jy1 = soa[1*stride+base+j];
        const float jx2 = soa[2*stride+base+j], jy2 = soa[3*stride+base+j];
        const float jsc = soa[4*stride+base+j];
        const float j0  = soa[5*stride+base+j], j1  = soa[6*stride+base+j];
        const float j2  = soa[7*stride+base+j], j3  = soa[8*stride+base+j];
        const int   jgt = sgt[base + j];
        const int   jef = eff[(size_t)img*S2 + j];
#pragma unroll
        for (int ii = 0; ii < 16; ++ii) {
            int il = wave*16 + ii;
            if (!siact[il]) continue;               // wave-uniform
            int r = sirk[il];
            float iw = fminf(jx2, sibf[2][il]) - fmaxf(jx1, sibf[0][il]);
            float ih = fminf(jy2, sibf[3][il]) - fmaxf(jy1, sibf[1][il]);
            if (r < jef && iw > 0.f && ih > 0.f) {   // alive (self: jef==r excluded)
                float d0 = j0 - sibf[4][il], d1 = j1 - sibf[5][il];
                float d2 = j2 - sibf[6][il], d3 = j3 - sibf[7][il];
                float diff = 0.25f*(d0*d0 + d1*d1 + d2*d2 + d3*d3);
                bool check = diff < 0.1f;
                bool same  = (jgt == sigt[il]);
                if (same && !check)      { ps[ii] += diff * jsc;       pn[ii] += 1.f; }
                else if (!same && check) { qs[ii] += expf(-diff)*jsc;  qn[ii] += 1.f; }
            }
        }
    }
#pragma unroll
    for (int ii = 0; ii < 16; ++ii) {
        int il = wave*16 + ii;
        if (!siact[il]) continue;                   // wave-uniform
        float a0 = ps[ii], a1 = pn[ii], a2 = qs[ii], a3 = qn[ii];
        for (int o = 32; o > 0; o >>= 1) {
            a0 += __shfl_down(a0, o); a1 += __shfl_down(a1, o);
            a2 += __shfl_down(a2, o); a3 += __shfl_down(a3, o);
        }
        if (lane == 0) {
            if (a1 > 0.f) { atomicAdd(&acc[img*4+0], a0 / a1); atomicAdd(&acc[img*4+1], 1.f); }
            if (a3 > 0.f) { atomicAdd(&acc[img*4+2], a2 / a3); atomicAdd(&acc[img*4+3], 1.f); }
        }
    }
}

__global__ void finalize2_kernel(const float* __restrict__ acc,
                                 float* __restrict__ out, int imgs)
{
    if (threadIdx.x == 0 && blockIdx.x == 0) {
        float push = 0.f, pull = 0.f;
        for (int i = 0; i < imgs; ++i) {
            pull += acc[i*4+0] / (acc[i*4+1] + 1e-6f);
            push += acc[i*4+2] / (acc[i*4+3] + 1e-6f);
        }
        out[0] = push / (float)imgs;   // push_loss
        out[1] = pull / (float)imgs;   // pull_loss
    }
}

// =====================================================================
// FALLBACK PATH (R1 kernel) — only if ws too small / N > 2048.
// =====================================================================
__global__ __launch_bounds__(BLOCK) void tagloss_kernel(
    const float* __restrict__ pred, const int* __restrict__ gt_inds,
    const float* __restrict__ proposals, float* __restrict__ ws, int N)
{
    const int img = blockIdx.x, t = threadIdx.x;
    const int lane = t & 63, wav = t >> 6;
    const float* P = proposals + (size_t)img * N * 5;
    const float* E = pred      + (size_t)img * N * 4;
    const int*   G = gt_inds   + (size_t)img * N;
    float x1[KMAX], y1[KMAX], x2[KMAX], y2[KMAX], sc[KMAX];
    float e0[KMAX], e1[KMAX], e2[KMAX], e3[KMAX];
    int gt[KMAX]; unsigned amask = 0u; int local_alive = 0;
#pragma unroll
    for (int k = 0; k < KMAX; ++k) {
        int j = k * BLOCK + t;
        if (j < N) {
            x1[k]=P[j*5+0]; y1[k]=P[j*5+1]; x2[k]=P[j*5+2]; y2[k]=P[j*5+3]; sc[k]=P[j*5+4];
            e0[k]=E[j*4+0]; e1[k]=E[j*4+1]; e2[k]=E[j*4+2]; e3[k]=E[j*4+3]; gt[k]=G[j];
            if (gt[k] >= 0 && (y2[k]-y1[k]) > 0.0f) { amask |= 1u<<k; local_alive++; }
        } else { x1[k]=y1[k]=x2[k]=y2[k]=0.f; sc[k]=0.f; e0[k]=e1[k]=e2[k]=e3[k]=0.f; gt[k]=-1; }
    }
    __shared__ unsigned long long s_key[NWAVES];
    __shared__ float s_b[9];
    __shared__ float s_part[NWAVES][5];
    int alive_count;
    {
        float v = (float)local_alive;
#pragma unroll
        for (int o = 32; o > 0; o >>= 1) v += __shfl_down(v, o);
        if (lane == 0) s_part[wav][0] = v;
        __syncthreads();
        float tot = 0.f;
        for (int w = 0; w < NWAVES; ++w) tot += s_part[w][0];
        alive_count = (int)tot;
    }
    float tot_pull=0.f, tot_push=0.f, pull_cnt=0.f, push_cnt=0.f;
    while (alive_count >= 2) {
        unsigned long long key = 0ull;
#pragma unroll
        for (int k = 0; k < KMAX; ++k)
            if (amask & (1u<<k)) {
                unsigned long long kk = ((unsigned long long)__float_as_uint(sc[k])<<32)
                                      | (unsigned long long)(0xFFFFFFFFu - (unsigned)(k*BLOCK+t));
                if (kk > key) key = kk;
            }
#pragma unroll
        for (int o = 32; o > 0; o >>= 1) {
            unsigned long long ok = __shfl_down(key, o);
            if (ok > key) key = ok;
        }
        if (lane == 0) s_key[wav] = key;
        __syncthreads();
        unsigned long long bk = s_key[0];
        for (int w = 1; w < NWAVES; ++w) if (s_key[w] > bk) bk = s_key[w];
        const int i = (int)(0xFFFFFFFFu - (unsigned)(bk & 0xFFFFFFFFull));
        if ((i & (BLOCK-1)) == t) {
            int k = i / BLOCK;
            s_b[0]=x1[k]; s_b[1]=y1[k]; s_b[2]=x2[k]; s_b[3]=y2[k];
            s_b[4]=e0[k]; s_b[5]=e1[k]; s_b[6]=e2[k]; s_b[7]=e3[k];
            s_b[8]=__int_as_float(gt[k]);
        }
        __syncthreads();
        const float bx1=s_b[0], by1=s_b[1], bx2=s_b[2], by2=s_b[3];
        const float f0=s_b[4], f1=s_b[5], f2=s_b[6], f3=s_b[7];
        const int bgt = __float_as_int(s_b[8]);
        const float areai = (bx2-bx1)*(by2-by1);
        float psum=0.f,qsum=0.f,pn=0.f,qn=0.f,scnt=0.f;
#pragma unroll
        for (int k = 0; k < KMAX; ++k) {
            if (!(amask & (1u<<k))) continue;
            int j = k*BLOCK+t;
            if (j == i) { amask &= ~(1u<<k); continue; }
            float iw = fmaxf(fminf(x2[k],bx2)-fmaxf(x1[k],bx1),0.f);
            float ih = fmaxf(fminf(y2[k],by2)-fmaxf(y1[k],by1),0.f);
            float inter = iw*ih;
            float uni = (x2[k]-x1[k])*(y2[k]-y1[k]) + areai - inter;
            float iou = inter / fmaxf(uni, 1e-12f);
            if (iou > 0.f) {
                float d0=e0[k]-f0,d1=e1[k]-f1,d2=e2[k]-f2,d3=e3[k]-f3;
                float diff = 0.25f*(d0*d0+d1*d1+d2*d2+d3*d3);
                bool check = diff < 0.1f;
                bool same = (gt[k]==bgt);
                if (same && !check) { psum += diff*sc[k]; pn += 1.f; }
                if (!same && check) { qsum += __expf(-diff)*sc[k]; qn += 1.f; }
                if (check)          { amask &= ~(1u<<k); scnt += 1.f; }
            }
        }
        float r0=psum,r1=pn,r2=qsum,r3=qn,r4=scnt;
#pragma unroll
        for (int o = 32; o > 0; o >>= 1) {
            r0+=__shfl_down(r0,o); r1+=__shfl_down(r1,o); r2+=__shfl_down(r2,o);
            r3+=__shfl_down(r3,o); r4+=__shfl_down(r4,o);
        }
        if (lane == 0) { s_part[wav][0]=r0;s_part[wav][1]=r1;s_part[wav][2]=r2;s_part[wav][3]=r3;s_part[wav][4]=r4; }
        __syncthreads();
        float T0=0,T1=0,T2=0,T3=0,T4=0;
        for (int w = 0; w < NWAVES; ++w) {
            T0+=s_part[w][0];T1+=s_part[w][1];T2+=s_part[w][2];T3+=s_part[w][3];T4+=s_part[w][4];
        }
        if (T1 > 0.f) { tot_pull += T0/T1; pull_cnt += 1.f; }
        if (T3 > 0.f) { tot_push += T2/T3; push_cnt += 1.f; }
        alive_count -= 1 + (int)T4;
    }
    if (t == 0) {
        ws[img*2+0] = tot_push / (push_cnt + 1e-6f);
        ws[img*2+1] = tot_pull / (pull_cnt + 1e-6f);
    }
}

__global__ void finalize_kernel(const float* __restrict__ ws,
                                float* __restrict__ out, int imgs)
{
    if (threadIdx.x == 0 && blockIdx.x == 0) {
        float push = 0.f, pull = 0.f;
        for (int k = 0; k < imgs; ++k) { push += ws[2*k]; pull += ws[2*k+1]; }
        out[0] = push / (float)imgs;
        out[1] = pull / (float)imgs;
    }
}

// =====================================================================
extern "C" void kernel_launch(void* const* d_in, const int* in_sizes, int n_in,
                              void* d_out, int out_size, void* d_ws, size_t ws_size,
                              hipStream_t stream) {
    const float* pred      = (const float*)d_in[0];
    const int*   gt_inds   = (const int*)  d_in[1];
    const float* proposals = (const float*)d_in[2];
    const int imgs = in_sizes[3] / 80;     // gt_bboxes (IMGS,20,4)
    const int N    = in_sizes[1] / imgs;   // gt_inds (IMGS,N)

    size_t off = 0;
    auto alloc = [&](size_t b) { size_t o = off; off += (b + 255) & ~(size_t)255; return o; };
    const size_t soa_off  = alloc((size_t)9 * imgs * S2 * 4);
    const size_t sgt_off  = alloc((size_t)imgs * S2 * 4);
    const size_t vld_off  = alloc((size_t)imgs * NW * 8);
    const size_t sel_off  = alloc((size_t)imgs * NW * 8);
    const size_t eff_off  = alloc((size_t)imgs * S2 * 4);
    const size_t sup_off  = alloc((size_t)imgs * S2 * NW * 8);
    const size_t nst_off  = alloc((size_t)imgs * 4);
    const size_t acc_off  = alloc((size_t)imgs * 16);
    const size_t need = off;

    if (N <= S2 && ws_size >= need) {
        char* w = (char*)d_ws;
        float*              soa  = (float*)(w + soa_off);
        int*                sgt  = (int*)(w + sgt_off);
        unsigned long long* vld  = (unsigned long long*)(w + vld_off);
        unsigned long long* sel  = (unsigned long long*)(w + sel_off);
        int*                eff  = (int*)(w + eff_off);
        unsigned long long* sup  = (unsigned long long*)(w + sup_off);
        int*                nst  = (int*)(w + nst_off);
        float*              acc  = (float*)(w + acc_off);

        sort_kernel<<<imgs, BLOCK, 0, stream>>>(pred, gt_inds, proposals,
                                                soa, sgt, vld, N, imgs);
        supmat_kernel<<<dim3(NCH, NCH, imgs), BLOCK, 0, stream>>>(soa, sup, N, imgs);
        greedy_kernel<<<imgs, 64, 0, stream>>>(sup, vld, sel);
        effrank_kernel<<<dim3(S2/BLOCK, imgs), BLOCK, 0, stream>>>(sup, vld, sel, eff);
        nsteps_kernel<<<imgs, BLOCK, 0, stream>>>(vld, sel, eff, nst, acc);
        pairs_kernel<<<dim3(NCH, imgs), BLOCK, 0, stream>>>(soa, sgt, eff, sel,
                                                            nst, acc, N, imgs);
        finalize2_kernel<<<1, 64, 0, stream>>>(acc, (float*)d_out, imgs);
    } else {
        float* ws = (float*)d_ws;
        tagloss_kernel<<<imgs, BLOCK, 0, stream>>>(pred, gt_inds, proposals, ws, N);
        finalize_kernel<<<1, 64, 0, stream>>>(ws, (float*)d_out, imgs);
    }
}

// Round 4
// 296.883 us; speedup vs baseline: 16.2391x; 1.2920x over previous
//
#include <hip/hip_runtime.h>
#include <stdint.h>

#define BLOCK 256
#define KMAX 8
#define NWAVES (BLOCK / 64)
#define S2 2048          // padded N (pow2); N=2000 fits
#define NW 32            // 64-bit words per row (S2/64)
#define NCH 32           // 64-element chunks (S2/64)
#define SPB 16           // selector slots per pairs-block
#define PB (S2 / SPB)    // pairs blocks per image (128)
#define EFF_INF 0x7FFFFFFF

// rank(j) = number of selected elements with sorted index < j
__device__ inline int rank_of(const unsigned long long* ss, int j) {
    int jw = j >> 6, jb = j & 63;
    int rk = __popcll(ss[jw] & (jb ? (~0ull >> (64 - jb)) : 0ull));
    for (int w = 0; w < jw; ++w) rk += __popcll(ss[w]);
    return rk;
}

// =====================================================================
// K1: rank-by-counting sort (O(N^2), fully parallel) + scatter to sorted SoA.
// position(i) = #{j<N : sc_j > sc_i || (sc_j == sc_i && j < i)}  == sort by
// (score desc, idx asc). Pad slots [N,S2) get zeros / gt=-1.
// =====================================================================
__global__ __launch_bounds__(BLOCK) void ranksort_kernel(
    const float* __restrict__ pred, const int* __restrict__ gt_inds,
    const float* __restrict__ proposals,
    float* __restrict__ soa, int* __restrict__ sgt,
    int N, int imgs)
{
    const int img = blockIdx.y, t = threadIdx.x;
    const int i = blockIdx.x * BLOCK + t;
    __shared__ unsigned sb[S2];
    const float* P = proposals + (size_t)img * N * 5;
    const float* E = pred      + (size_t)img * N * 4;
    const int*   G = gt_inds   + (size_t)img * N;

    for (int kk = t; kk < S2; kk += BLOCK)
        sb[kk] = (kk < N) ? __float_as_uint(P[kk*5 + 4]) : 0u;
    __syncthreads();

    const size_t stride = (size_t)imgs * S2;
    const size_t base   = (size_t)img * S2;

    if (i >= N) {
        if (i < S2) {
#pragma unroll
            for (int a = 0; a < 9; ++a) soa[(size_t)a*stride + base + i] = 0.f;
            sgt[base + i] = -1;
        }
        return;
    }

    const unsigned my = sb[i];
    int p = 0;
    const uint4* sb4 = (const uint4*)sb;
    const int n4 = N >> 2;
    for (int q = 0; q < n4; ++q) {
        uint4 v = sb4[q];
        int jj = q * 4;
        p += (int)((v.x > my) | ((v.x == my) & (jj + 0 < i)));
        p += (int)((v.y > my) | ((v.y == my) & (jj + 1 < i)));
        p += (int)((v.z > my) | ((v.z == my) & (jj + 2 < i)));
        p += (int)((v.w > my) | ((v.w == my) & (jj + 3 < i)));
    }
    for (int jj = n4*4; jj < N; ++jj) {
        unsigned v = sb[jj];
        p += (int)((v > my) | ((v == my) & (jj < i)));
    }

    soa[0*stride + base + p] = P[i*5+0];
    soa[1*stride + base + p] = P[i*5+1];
    soa[2*stride + base + p] = P[i*5+2];
    soa[3*stride + base + p] = P[i*5+3];
    soa[4*stride + base + p] = P[i*5+4];
    soa[5*stride + base + p] = E[i*4+0];
    soa[6*stride + base + p] = E[i*4+1];
    soa[7*stride + base + p] = E[i*4+2];
    soa[8*stride + base + p] = E[i*4+3];
    sgt[base + p] = G[i];
}

// =====================================================================
// K2: symmetric suppression matrix, 64x64 tiles. sup(i,j)=inter>0 && diff<TAG_THR.
// =====================================================================
__global__ __launch_bounds__(BLOCK) void supmat_kernel(
    const float* __restrict__ soa, unsigned long long* __restrict__ sup,
    int N, int imgs)
{
    const int ic = blockIdx.x, jc = blockIdx.y, img = blockIdx.z;
    const int t = threadIdx.x, wave = t >> 6, lane = t & 63;
    const size_t stride = (size_t)imgs * S2, base = (size_t)img * S2;
    __shared__ float si[8][64];
    for (int idx = t; idx < 512; idx += BLOCK) {
        int f = idx >> 6, e = idx & 63;
        int a = (f < 4) ? f : f + 1;      // arrays {0,1,2,3,5,6,7,8}
        si[f][e] = soa[(size_t)a*stride + base + ic*64 + e];
    }
    __syncthreads();
    const int j = jc*64 + lane;
    const float jx1 = soa[0*stride+base+j], jy1 = soa[1*stride+base+j];
    const float jx2 = soa[2*stride+base+j], jy2 = soa[3*stride+base+j];
    const float j0  = soa[5*stride+base+j], j1  = soa[6*stride+base+j];
    const float j2  = soa[7*stride+base+j], j3  = soa[8*stride+base+j];
    const bool jin = (j < N);
    for (int ii = 0; ii < 16; ++ii) {
        int il = wave*16 + ii;
        int i  = ic*64 + il;
        float bx1 = si[0][il], by1 = si[1][il], bx2 = si[2][il], by2 = si[3][il];
        float f0  = si[4][il], f1  = si[5][il], f2  = si[6][il], f3  = si[7][il];
        bool s = false;
        if (jin && i < N) {
            float iw = fminf(jx2, bx2) - fmaxf(jx1, bx1);
            float ih = fminf(jy2, by2) - fmaxf(jy1, by1);
            if (iw > 0.f && ih > 0.f) {
                float d0 = j0-f0, d1 = j1-f1, d2 = j2-f2, d3 = j3-f3;
                float diff = 0.25f*(d0*d0 + d1*d1 + d2*d2 + d3*d3);
                s = diff < 0.1f;   // TAG_THR
            }
        }
        unsigned long long bb = __ballot(s);
        if (lane == 0) sup[((size_t)img*S2 + i)*NW + jc] = bb;
    }
}

// =====================================================================
// K3: sequential chunked greedy, one wave per image. Prefetched rows, no
// dynamic register indexing (in-chunk word via dedicated load).
// =====================================================================
__global__ __launch_bounds__(64) void greedy_kernel(
    const unsigned long long* __restrict__ sup,
    const int* __restrict__ sgt, const float* __restrict__ soa,
    unsigned long long* __restrict__ selw_out, int imgs)
{
    const int img = blockIdx.x, l = threadIdx.x;
    const unsigned long long* S = sup + (size_t)img * S2 * NW;
    const size_t stride = (size_t)imgs * S2, base = (size_t)img * S2;
    __shared__ unsigned long long ssel[NW];
    if (l < NW) ssel[l] = 0ull;
    __syncthreads();

    unsigned long long rw[NW];
#pragma unroll
    for (int w = 0; w < NW; ++w) rw[w] = S[(size_t)l*NW + w];
    unsigned long long loc = S[(size_t)l*NW + 0];
    bool vme;
    {
        int g = sgt[base + l];
        float a = soa[1*stride+base+l], b = soa[3*stride+base+l];
        vme = (g >= 0) && ((b - a) > 0.f);
    }

    for (int c = 0; c < NCH; ++c) {
        unsigned long long nrw[NW]; unsigned long long nloc = 0ull; bool nv = false;
        if (c + 1 < NCH) {
            const int j2 = (c+1)*64 + l;
#pragma unroll
            for (int w = 0; w < NW; ++w) nrw[w] = S[(size_t)j2*NW + w];
            nloc = S[(size_t)j2*NW + (c+1)];
            int g = sgt[base + j2];
            float a = soa[1*stride+base+j2], b = soa[3*stride+base+j2];
            nv = (g >= 0) && ((b - a) > 0.f);
        } else {
#pragma unroll
            for (int w = 0; w < NW; ++w) nrw[w] = 0ull;
        }

        unsigned long long acc = 0ull;
#pragma unroll
        for (int w = 0; w < NW; ++w) acc |= rw[w] & ssel[w];  // ssel[w>=c]==0
        bool aliveme = vme && (acc == 0ull);
        unsigned long long remaining = __ballot(aliveme);
        unsigned long long sel = 0ull;
        while (remaining) {
            int i = __builtin_ctzll(remaining);      // lowest alive -> greedy pick
            sel |= 1ull << i;
            unsigned long long row_i = __ballot(((loc >> i) & 1ull) != 0ull);
            remaining &= ~row_i;
            remaining &= ~(1ull << i);
        }
        if (l == 0) {
            ssel[c] = sel;
            selw_out[(size_t)img*NW + c] = sel;
        }
        __syncthreads();
#pragma unroll
        for (int w = 0; w < NW; ++w) rw[w] = nrw[w];
        loc = nloc; vme = nv;
    }
}

// =====================================================================
// K4: merged eff + nsteps. One block per image.
// eff: invalid->0; selected->rank; suppressed->rank(first sel suppressor)+1;
// survivor->INF. Then histogram+scan gives exact alive<2 cutoff.
// =====================================================================
__global__ __launch_bounds__(BLOCK) void effsteps_kernel(
    const unsigned long long* __restrict__ sup,
    const unsigned long long* __restrict__ selw,
    const int* __restrict__ sgt, const float* __restrict__ soa,
    int* __restrict__ eff, int* __restrict__ nsteps, int imgs)
{
    const int img = blockIdx.x, t = threadIdx.x;
    const int lane = t & 63, wave = t >> 6;
    const size_t stride = (size_t)imgs * S2, base = (size_t)img * S2;
    __shared__ unsigned long long ss[NW];
    __shared__ unsigned hist[S2];
    __shared__ int ints[2*NWAVES];
    __shared__ unsigned wsum[NWAVES];
    __shared__ int bm[NWAVES];
    if (t < NW) ss[t] = selw[(size_t)img*NW + t];
    for (int x = t; x < S2; x += BLOCK) hist[x] = 0u;
    __syncthreads();

    int myV = 0, mySc = 0;
#pragma unroll
    for (int k = 0; k < 8; ++k) {
        const int j = k*BLOCK + t;
        int g = sgt[base + j];
        float a = soa[1*stride+base+j], b = soa[3*stride+base+j];
        bool valid = (g >= 0) && ((b - a) > 0.f);
        bool selb  = (ss[j>>6] >> (j & 63)) & 1ull;
        int e;
        if (!valid) e = 0;
        else if (selb) { e = rank_of(ss, j); ++myV; ++mySc; }
        else {
            ++myV;
            const unsigned long long* R = sup + ((size_t)img*S2 + j)*NW;
            int istar = -1;
#pragma unroll
            for (int w = 0; w < NW; ++w) {
                unsigned long long f = R[w] & ss[w];
                if (istar < 0 && f) istar = w*64 + __builtin_ctzll(f);
            }
            if (istar < 0) e = EFF_INF;
            else { e = rank_of(ss, istar) + 1; atomicAdd(&hist[e - 1], 1u); }
        }
        eff[(size_t)img*S2 + j] = e;
    }
    __syncthreads();

    // block-reduce V, Sc
    int v = myV, sc = mySc;
    for (int o = 32; o > 0; o >>= 1) { v += __shfl_down(v, o); sc += __shfl_down(sc, o); }
    if (lane == 0) { ints[wave] = v; ints[NWAVES + wave] = sc; }
    __syncthreads();
    int V = 0, Sc = 0;
    for (int w = 0; w < NWAVES; ++w) { V += ints[w]; Sc += ints[NWAVES + w]; }

    // inclusive scan of hist[2048]
    unsigned loc[8]; unsigned s = 0;
#pragma unroll
    for (int k = 0; k < 8; ++k) { s += hist[t*8 + k]; loc[k] = s; }
    unsigned tot = s;
    for (int o = 1; o < 64; o <<= 1) {
        unsigned u = __shfl_up(tot, o);
        if (lane >= o) tot += u;
    }
    if (lane == 63) wsum[wave] = tot;
    __syncthreads();
    unsigned woff = 0;
    for (int w = 0; w < wave; ++w) woff += wsum[w];
    unsigned exclP = woff + tot - s;
    __syncthreads();
#pragma unroll
    for (int k = 0; k < 8; ++k) hist[t*8 + k] = exclP + loc[k];
    __syncthreads();

    int best = EFF_INF;
    for (int r = t; r < Sc; r += BLOCK) {
        unsigned rem = (r == 0) ? 0u : hist[r - 1];   // suppressed removed before step r
        int alive = V - r - (int)rem;
        if (alive < 2) best = min(best, r);
    }
    for (int o = 32; o > 0; o >>= 1) best = min(best, __shfl_down(best, o));
    if (lane == 0) bm[wave] = best;
    __syncthreads();
    if (t == 0) {
        int b = bm[0];
        for (int w = 1; w < NWAVES; ++w) b = min(b, bm[w]);
        nsteps[img] = min(b, Sc);
    }
}

// =====================================================================
// K5: pair sums. Block = (16 selector slots, img); each wave owns 4 slots
// (data register-hoisted); j strided over lanes. No global atomics —
// per-block partials {sumPullRatio, cntPull, sumPushRatio, cntPush}.
// =====================================================================
__global__ __launch_bounds__(BLOCK) void pairs_kernel(
    const float* __restrict__ soa, const int* __restrict__ sgt,
    const int* __restrict__ eff, const unsigned long long* __restrict__ selw,
    const int* __restrict__ nsteps, float* __restrict__ partials, int imgs)
{
    const int ic = blockIdx.x, img = blockIdx.y;
    const int t = threadIdx.x, wave = t >> 6, lane = t & 63;
    const size_t stride = (size_t)imgs * S2, base = (size_t)img * S2;
    __shared__ unsigned long long ss[NW];
    __shared__ float pw[NWAVES][4];
    __shared__ int anyact;
    if (t < NW) ss[t] = selw[(size_t)img*NW + t];
    if (t == 0) anyact = 0;
    __syncthreads();
    const int ns = nsteps[img];

    float bx1[4], by1[4], bx2[4], by2[4], f0[4], f1[4], f2[4], f3[4];
    int bgt[4], rk[4]; bool act[4];
    bool any = false;
#pragma unroll
    for (int u = 0; u < 4; ++u) {
        const int i = ic*SPB + wave*4 + u;
        bool selb = (ss[i>>6] >> (i & 63)) & 1ull;
        int r = rank_of(ss, i);
        rk[u] = r;
        act[u] = selb && (r < ns);
        any |= act[u];
        if (act[u]) {
            bx1[u] = soa[0*stride+base+i]; by1[u] = soa[1*stride+base+i];
            bx2[u] = soa[2*stride+base+i]; by2[u] = soa[3*stride+base+i];
            f0[u]  = soa[5*stride+base+i]; f1[u]  = soa[6*stride+base+i];
            f2[u]  = soa[7*stride+base+i]; f3[u]  = soa[8*stride+base+i];
            bgt[u] = sgt[base + i];
        } else {
            bx1[u]=by1[u]=bx2[u]=by2[u]=0.f; f0[u]=f1[u]=f2[u]=f3[u]=0.f; bgt[u]=-2;
        }
    }
    if (any && lane == 0) anyact = 1;   // benign same-value race
    __syncthreads();
    if (!anyact) {
        if (t < 4) partials[((size_t)img*PB + ic)*4 + t] = 0.f;
        return;
    }

    float ps[4] = {0,0,0,0}, pn[4] = {0,0,0,0}, qs[4] = {0,0,0,0}, qn[4] = {0,0,0,0};
    for (int jt = 0; jt < NCH; ++jt) {
        const int j = jt*64 + lane;
        const float jx1 = soa[0*stride+base+j], jy1 = soa[1*stride+base+j];
        const float jx2 = soa[2*stride+base+j], jy2 = soa[3*stride+base+j];
        const float jsc = soa[4*stride+base+j];
        const float j0  = soa[5*stride+base+j], j1  = soa[6*stride+base+j];
        const float j2  = soa[7*stride+base+j], j3  = soa[8*stride+base+j];
        const int   jgt = sgt[base + j];
        const int   jef = eff[(size_t)img*S2 + j];
#pragma unroll
        for (int u = 0; u < 4; ++u) {
            if (!act[u]) continue;                    // wave-uniform
            if (rk[u] < jef) {                        // j alive at step rk (self: jef==rk)
                float iw = fminf(jx2, bx2[u]) - fmaxf(jx1, bx1[u]);
                float ih = fminf(jy2, by2[u]) - fmaxf(jy1, by1[u]);
                if (iw > 0.f && ih > 0.f) {
                    float d0 = j0 - f0[u], d1 = j1 - f1[u];
                    float d2 = j2 - f2[u], d3 = j3 - f3[u];
                    float diff = 0.25f*(d0*d0 + d1*d1 + d2*d2 + d3*d3);
                    bool check = diff < 0.1f;
                    bool same  = (jgt == bgt[u]);
                    if (same && !check)      { ps[u] += diff * jsc;       pn[u] += 1.f; }
                    else if (!same && check) { qs[u] += expf(-diff)*jsc;  qn[u] += 1.f; }
                }
            }
        }
    }

    float sPull = 0.f, cPull = 0.f, sPush = 0.f, cPush = 0.f;
#pragma unroll
    for (int u = 0; u < 4; ++u) {
        if (!act[u]) continue;                        // wave-uniform
        float a0 = ps[u], a1 = pn[u], a2 = qs[u], a3 = qn[u];
        for (int o = 32; o > 0; o >>= 1) {
            a0 += __shfl_down(a0, o); a1 += __shfl_down(a1, o);
            a2 += __shfl_down(a2, o); a3 += __shfl_down(a3, o);
        }
        if (lane == 0) {
            if (a1 > 0.f) { sPull += a0 / a1; cPull += 1.f; }
            if (a3 > 0.f) { sPush += a2 / a3; cPush += 1.f; }
        }
    }
    if (lane == 0) {
        pw[wave][0] = sPull; pw[wave][1] = cPull;
        pw[wave][2] = sPush; pw[wave][3] = cPush;
    }
    __syncthreads();
    if (t == 0) {
        float a = 0, b = 0, c = 0, d = 0;
        for (int w = 0; w < NWAVES; ++w) {
            a += pw[w][0]; b += pw[w][1]; c += pw[w][2]; d += pw[w][3];
        }
        float* p = partials + ((size_t)img*PB + ic)*4;
        p[0] = a; p[1] = b; p[2] = c; p[3] = d;
    }
}

// K6: sum per-block partials, form final losses.
__global__ __launch_bounds__(BLOCK) void finalize_kernel(
    const float* __restrict__ partials, float* __restrict__ out, int imgs)
{
    const int t = threadIdx.x;
    __shared__ float a[8][4];     // up to 8 images
    if (t < 32) ((float*)a)[t] = 0.f;
    __syncthreads();
    for (int e = t; e < imgs * PB; e += BLOCK) {
        int img = e / PB;
        const float* p = partials + (size_t)e * 4;
#pragma unroll
        for (int k = 0; k < 4; ++k) {
            float v = p[k];
            if (v != 0.f) atomicAdd(&a[img][k], v);
        }
    }
    __syncthreads();
    if (t == 0) {
        float push = 0.f, pull = 0.f;
        for (int i = 0; i < imgs; ++i) {
            pull += a[i][0] / (a[i][1] + 1e-6f);
            push += a[i][2] / (a[i][3] + 1e-6f);
        }
        out[0] = push / (float)imgs;   // push_loss
        out[1] = pull / (float)imgs;   // pull_loss
    }
}

// =====================================================================
// FALLBACK PATH (R1 kernel) — only if ws too small / N > 2048 / imgs > 8.
// =====================================================================
__global__ __launch_bounds__(BLOCK) void tagloss_kernel(
    const float* __restrict__ pred, const int* __restrict__ gt_inds,
    const float* __restrict__ proposals, float* __restrict__ ws, int N)
{
    const int img = blockIdx.x, t = threadIdx.x;
    const int lane = t & 63, wav = t >> 6;
    const float* P = proposals + (size_t)img * N * 5;
    const float* E = pred      + (size_t)img * N * 4;
    const int*   G = gt_inds   + (size_t)img * N;
    float x1[KMAX], y1[KMAX], x2[KMAX], y2[KMAX], sc[KMAX];
    float e0[KMAX], e1[KMAX], e2[KMAX], e3[KMAX];
    int gt[KMAX]; unsigned amask = 0u; int local_alive = 0;
#pragma unroll
    for (int k = 0; k < KMAX; ++k) {
        int j = k * BLOCK + t;
        if (j < N) {
            x1[k]=P[j*5+0]; y1[k]=P[j*5+1]; x2[k]=P[j*5+2]; y2[k]=P[j*5+3]; sc[k]=P[j*5+4];
            e0[k]=E[j*4+0]; e1[k]=E[j*4+1]; e2[k]=E[j*4+2]; e3[k]=E[j*4+3]; gt[k]=G[j];
            if (gt[k] >= 0 && (y2[k]-y1[k]) > 0.0f) { amask |= 1u<<k; local_alive++; }
        } else { x1[k]=y1[k]=x2[k]=y2[k]=0.f; sc[k]=0.f; e0[k]=e1[k]=e2[k]=e3[k]=0.f; gt[k]=-1; }
    }
    __shared__ unsigned long long s_key[NWAVES];
    __shared__ float s_b[9];
    __shared__ float s_part[NWAVES][5];
    int alive_count;
    {
        float v = (float)local_alive;
#pragma unroll
        for (int o = 32; o > 0; o >>= 1) v += __shfl_down(v, o);
        if (lane == 0) s_part[wav][0] = v;
        __syncthreads();
        float tot = 0.f;
        for (int w = 0; w < NWAVES; ++w) tot += s_part[w][0];
        alive_count = (int)tot;
    }
    float tot_pull=0.f, tot_push=0.f, pull_cnt=0.f, push_cnt=0.f;
    while (alive_count >= 2) {
        unsigned long long key = 0ull;
#pragma unroll
        for (int k = 0; k < KMAX; ++k)
            if (amask & (1u<<k)) {
                unsigned long long kk = ((unsigned long long)__float_as_uint(sc[k])<<32)
                                      | (unsigned long long)(0xFFFFFFFFu - (unsigned)(k*BLOCK+t));
                if (kk > key) key = kk;
            }
#pragma unroll
        for (int o = 32; o > 0; o >>= 1) {
            unsigned long long ok = __shfl_down(key, o);
            if (ok > key) key = ok;
        }
        if (lane == 0) s_key[wav] = key;
        __syncthreads();
        unsigned long long bk = s_key[0];
        for (int w = 1; w < NWAVES; ++w) if (s_key[w] > bk) bk = s_key[w];
        const int i = (int)(0xFFFFFFFFu - (unsigned)(bk & 0xFFFFFFFFull));
        if ((i & (BLOCK-1)) == t) {
            int k = i / BLOCK;
            s_b[0]=x1[k]; s_b[1]=y1[k]; s_b[2]=x2[k]; s_b[3]=y2[k];
            s_b[4]=e0[k]; s_b[5]=e1[k]; s_b[6]=e2[k]; s_b[7]=e3[k];
            s_b[8]=__int_as_float(gt[k]);
        }
        __syncthreads();
        const float bx1=s_b[0], by1=s_b[1], bx2=s_b[2], by2=s_b[3];
        const float f0=s_b[4], f1=s_b[5], f2=s_b[6], f3=s_b[7];
        const int bgt = __float_as_int(s_b[8]);
        const float areai = (bx2-bx1)*(by2-by1);
        float psum=0.f,qsum=0.f,pn=0.f,qn=0.f,scnt=0.f;
#pragma unroll
        for (int k = 0; k < KMAX; ++k) {
            if (!(amask & (1u<<k))) continue;
            int j = k*BLOCK+t;
            if (j == i) { amask &= ~(1u<<k); continue; }
            float iw = fmaxf(fminf(x2[k],bx2)-fmaxf(x1[k],bx1),0.f);
            float ih = fmaxf(fminf(y2[k],by2)-fmaxf(y1[k],by1),0.f);
            float inter = iw*ih;
            float uni = (x2[k]-x1[k])*(y2[k]-y1[k]) + areai - inter;
            float iou = inter / fmaxf(uni, 1e-12f);
            if (iou > 0.f) {
                float d0=e0[k]-f0,d1=e1[k]-f1,d2=e2[k]-f2,d3=e3[k]-f3;
                float diff = 0.25f*(d0*d0+d1*d1+d2*d2+d3*d3);
                bool check = diff < 0.1f;
                bool same = (gt[k]==bgt);
                if (same && !check) { psum += diff*sc[k]; pn += 1.f; }
                if (!same && check) { qsum += __expf(-diff)*sc[k]; qn += 1.f; }
                if (check)          { amask &= ~(1u<<k); scnt += 1.f; }
            }
        }
        float r0=psum,r1=pn,r2=qsum,r3=qn,r4=scnt;
#pragma unroll
        for (int o = 32; o > 0; o >>= 1) {
            r0+=__shfl_down(r0,o); r1+=__shfl_down(r1,o); r2+=__shfl_down(r2,o);
            r3+=__shfl_down(r3,o); r4+=__shfl_down(r4,o);
        }
        if (lane == 0) { s_part[wav][0]=r0;s_part[wav][1]=r1;s_part[wav][2]=r2;s_part[wav][3]=r3;s_part[wav][4]=r4; }
        __syncthreads();
        float T0=0,T1=0,T2=0,T3=0,T4=0;
        for (int w = 0; w < NWAVES; ++w) {
            T0+=s_part[w][0];T1+=s_part[w][1];T2+=s_part[w][2];T3+=s_part[w][3];T4+=s_part[w][4];
        }
        if (T1 > 0.f) { tot_pull += T0/T1; pull_cnt += 1.f; }
        if (T3 > 0.f) { tot_push += T2/T3; push_cnt += 1.f; }
        alive_count -= 1 + (int)T4;
    }
    if (t == 0) {
        ws[img*2+0] = tot_push / (push_cnt + 1e-6f);
        ws[img*2+1] = tot_pull / (pull_cnt + 1e-6f);
    }
}

__global__ void finalize_fb_kernel(const float* __restrict__ ws,
                                   float* __restrict__ out, int imgs)
{
    if (threadIdx.x == 0 && blockIdx.x == 0) {
        float push = 0.f, pull = 0.f;
        for (int k = 0; k < imgs; ++k) { push += ws[2*k]; pull += ws[2*k+1]; }
        out[0] = push / (float)imgs;
        out[1] = pull / (float)imgs;
    }
}

// =====================================================================
extern "C" void kernel_launch(void* const* d_in, const int* in_sizes, int n_in,
                              void* d_out, int out_size, void* d_ws, size_t ws_size,
                              hipStream_t stream) {
    const float* pred      = (const float*)d_in[0];
    const int*   gt_inds   = (const int*)  d_in[1];
    const float* proposals = (const float*)d_in[2];
    const int imgs = in_sizes[3] / 80;     // gt_bboxes (IMGS,20,4)
    const int N    = in_sizes[1] / imgs;   // gt_inds (IMGS,N)

    size_t off = 0;
    auto alloc = [&](size_t b) { size_t o = off; off += (b + 255) & ~(size_t)255; return o; };
    const size_t soa_off  = alloc((size_t)9 * imgs * S2 * 4);
    const size_t sgt_off  = alloc((size_t)imgs * S2 * 4);
    const size_t sel_off  = alloc((size_t)imgs * NW * 8);
    const size_t eff_off  = alloc((size_t)imgs * S2 * 4);
    const size_t sup_off  = alloc((size_t)imgs * S2 * NW * 8);
    const size_t nst_off  = alloc((size_t)imgs * 4);
    const size_t par_off  = alloc((size_t)imgs * PB * 16);
    const size_t need = off;

    if (N <= S2 && imgs <= 8 && ws_size >= need) {
        char* w = (char*)d_ws;
        float*              soa  = (float*)(w + soa_off);
        int*                sgt  = (int*)(w + sgt_off);
        unsigned long long* sel  = (unsigned long long*)(w + sel_off);
        int*                eff  = (int*)(w + eff_off);
        unsigned long long* sup  = (unsigned long long*)(w + sup_off);
        int*                nst  = (int*)(w + nst_off);
        float*              par  = (float*)(w + par_off);

        ranksort_kernel<<<dim3(S2/BLOCK, imgs), BLOCK, 0, stream>>>(
            pred, gt_inds, proposals, soa, sgt, N, imgs);
        supmat_kernel<<<dim3(NCH, NCH, imgs), BLOCK, 0, stream>>>(soa, sup, N, imgs);
        greedy_kernel<<<imgs, 64, 0, stream>>>(sup, sgt, soa, sel, imgs);
        effsteps_kernel<<<imgs, BLOCK, 0, stream>>>(sup, sel, sgt, soa, eff, nst, imgs);
        pairs_kernel<<<dim3(PB, imgs), BLOCK, 0, stream>>>(soa, sgt, eff, sel,
                                                           nst, par, imgs);
        finalize_kernel<<<1, BLOCK, 0, stream>>>(par, (float*)d_out, imgs);
    } else {
        float* ws = (float*)d_ws;
        tagloss_kernel<<<imgs, BLOCK, 0, stream>>>(pred, gt_inds, proposals, ws, N);
        finalize_fb_kernel<<<1, 64, 0, stream>>>(ws, (float*)d_out, imgs);
    }
}

// Round 5
// 247.331 us; speedup vs baseline: 19.4925x; 1.2003x over previous
//
#include <hip/hip_runtime.h>
#include <stdint.h>

#define BLOCK 256
#define KMAX 8
#define NWAVES (BLOCK / 64)
#define S2 2048          // padded N (pow2); N=2000 fits
#define NW 32            // 64-bit words per row (S2/64)
#define NCH 32           // 64-element chunks (S2/64)
#define SPB 16           // selector slots per pairs-block
#define PB (S2 / SPB)    // pairs blocks per image (128)
#define EFF_INF 0x7FFFFFFF

// rank(j) = number of selected elements with sorted index < j
__device__ inline int rank_of(const unsigned long long* ss, int j) {
    int jw = j >> 6, jb = j & 63;
    int rk = __popcll(ss[jw] & (jb ? (~0ull >> (64 - jb)) : 0ull));
    for (int w = 0; w < jw; ++w) rk += __popcll(ss[w]);
    return rk;
}

// =====================================================================
// K1: rank-by-counting sort (O(N^2), fully parallel) + scatter to sorted SoA.
// =====================================================================
__global__ __launch_bounds__(BLOCK) void ranksort_kernel(
    const float* __restrict__ pred, const int* __restrict__ gt_inds,
    const float* __restrict__ proposals,
    float* __restrict__ soa, int* __restrict__ sgt,
    int N, int imgs)
{
    const int img = blockIdx.y, t = threadIdx.x;
    const int i = blockIdx.x * BLOCK + t;
    __shared__ unsigned sb[S2];
    const float* P = proposals + (size_t)img * N * 5;
    const float* E = pred      + (size_t)img * N * 4;
    const int*   G = gt_inds   + (size_t)img * N;

    for (int kk = t; kk < S2; kk += BLOCK)
        sb[kk] = (kk < N) ? __float_as_uint(P[kk*5 + 4]) : 0u;
    __syncthreads();

    const size_t stride = (size_t)imgs * S2;
    const size_t base   = (size_t)img * S2;

    if (i >= N) {
        if (i < S2) {
#pragma unroll
            for (int a = 0; a < 9; ++a) soa[(size_t)a*stride + base + i] = 0.f;
            sgt[base + i] = -1;
        }
        return;
    }

    const unsigned my = sb[i];
    int p = 0;
    const uint4* sb4 = (const uint4*)sb;
    const int n4 = N >> 2;
    for (int q = 0; q < n4; ++q) {
        uint4 v = sb4[q];
        int jj = q * 4;
        p += (int)((v.x > my) | ((v.x == my) & (jj + 0 < i)));
        p += (int)((v.y > my) | ((v.y == my) & (jj + 1 < i)));
        p += (int)((v.z > my) | ((v.z == my) & (jj + 2 < i)));
        p += (int)((v.w > my) | ((v.w == my) & (jj + 3 < i)));
    }
    for (int jj = n4*4; jj < N; ++jj) {
        unsigned v = sb[jj];
        p += (int)((v > my) | ((v == my) & (jj < i)));
    }

    soa[0*stride + base + p] = P[i*5+0];
    soa[1*stride + base + p] = P[i*5+1];
    soa[2*stride + base + p] = P[i*5+2];
    soa[3*stride + base + p] = P[i*5+3];
    soa[4*stride + base + p] = P[i*5+4];
    soa[5*stride + base + p] = E[i*4+0];
    soa[6*stride + base + p] = E[i*4+1];
    soa[7*stride + base + p] = E[i*4+2];
    soa[8*stride + base + p] = E[i*4+3];
    sgt[base + p] = G[i];
}

// =====================================================================
// K2: suppression matrix in TRANSPOSED layout supT[img][w][j] (legal since
// sup is bitwise symmetric): supT[w][j] = bits over i in chunk w of sup(i,j)
// = word w of row j. Makes greedy/effsteps loads coalesced.
// =====================================================================
__global__ __launch_bounds__(BLOCK) void supmat_kernel(
    const float* __restrict__ soa, unsigned long long* __restrict__ supT,
    int N, int imgs)
{
    const int ic = blockIdx.x, jc = blockIdx.y, img = blockIdx.z;
    const int t = threadIdx.x, wave = t >> 6, lane = t & 63;
    const size_t stride = (size_t)imgs * S2, base = (size_t)img * S2;
    __shared__ float si[8][64];
    for (int idx = t; idx < 512; idx += BLOCK) {
        int f = idx >> 6, e = idx & 63;
        int a = (f < 4) ? f : f + 1;      // arrays {0,1,2,3,5,6,7,8}
        si[f][e] = soa[(size_t)a*stride + base + ic*64 + e];
    }
    __syncthreads();
    const int j = jc*64 + lane;
    const float jx1 = soa[0*stride+base+j], jy1 = soa[1*stride+base+j];
    const float jx2 = soa[2*stride+base+j], jy2 = soa[3*stride+base+j];
    const float j0  = soa[5*stride+base+j], j1  = soa[6*stride+base+j];
    const float j2  = soa[7*stride+base+j], j3  = soa[8*stride+base+j];
    const bool jin = (j < N);
    for (int ii = 0; ii < 16; ++ii) {
        int il = wave*16 + ii;
        int i  = ic*64 + il;
        float bx1 = si[0][il], by1 = si[1][il], bx2 = si[2][il], by2 = si[3][il];
        float f0  = si[4][il], f1  = si[5][il], f2  = si[6][il], f3  = si[7][il];
        bool s = false;
        if (jin && i < N) {
            float iw = fminf(jx2, bx2) - fmaxf(jx1, bx1);
            float ih = fminf(jy2, by2) - fmaxf(jy1, by1);
            if (iw > 0.f && ih > 0.f) {
                float d0 = j0-f0, d1 = j1-f1, d2 = j2-f2, d3 = j3-f3;
                float diff = 0.25f*(d0*d0 + d1*d1 + d2*d2 + d3*d3);
                s = diff < 0.1f;   // TAG_THR
            }
        }
        unsigned long long bb = __ballot(s);
        // word jc of row i -> transposed slot supT[img][jc][i]
        if (lane == 0) supT[((size_t)img*NW + jc)*S2 + i] = bb;
    }
}

// =====================================================================
// K3: sequential chunked greedy, one wave per image.
// Lane l owns dead-bits (32-bit mask) for elements j = m*64+l, m=0..31.
// Per chunk: batch round-based resolve (rounds = suppression chain depth,
// ~1-2 here) instead of per-pick serial; then coalesced lower-triangle
// updates of future dead bits. Exact greedy (sup symmetric => batch A is
// conflict-free and kills only go forward).
// =====================================================================
__global__ __launch_bounds__(64) void greedy_kernel(
    const unsigned long long* __restrict__ supT,
    const int* __restrict__ sgt, const float* __restrict__ soa,
    unsigned long long* __restrict__ selw_out, int imgs)
{
    const int img = blockIdx.x, l = threadIdx.x;
    const size_t matb = (size_t)img * NW * S2;
    const size_t stride = (size_t)imgs * S2, base = (size_t)img * S2;

    // per-lane validity: bit c = valid(j = c*64 + l)
    unsigned vmask = 0u;
#pragma unroll
    for (int c = 0; c < NCH; ++c) {
        const int j = c*64 + l;
        int g = sgt[base + j];
        float a = soa[1*stride + base + j];
        float b = soa[3*stride + base + j];
        if (g >= 0 && (b - a) > 0.f) vmask |= (1u << c);
    }

    const unsigned long long lowmask = (l == 0) ? 0ull : (~0ull >> (64 - l));
    unsigned dead32 = 0u;
    unsigned long long loc = supT[matb + (size_t)0*64 + l];   // word 0, row l

    for (int c = 0; c < NCH; ++c) {
        // prefetch next chunk's self word + first update group (addresses
        // independent of this chunk's resolve)
        unsigned long long nloc = 0ull;
        if (c + 1 < NCH)
            nloc = supT[matb + (size_t)(c+1)*S2 + (size_t)(c+1)*64 + l];
        int n0 = NCH - (c + 1); if (n0 > 8) n0 = 8;
        unsigned long long g0[8];
#pragma unroll
        for (int q = 0; q < 8; ++q)
            if (q < n0) g0[q] = supT[matb + (size_t)c*S2 + (size_t)(c+1+q)*64 + l];

        // ---- batch resolve over this chunk ----
        bool alive = ((vmask >> c) & 1u) && !((dead32 >> c) & 1u);
        unsigned long long U = __ballot(alive);
        unsigned long long sel = 0ull;
        while (U) {
            bool inU = (U >> l) & 1ull;
            unsigned long long A = __ballot(inU && ((loc & U & lowmask) == 0ull));
            sel |= A;
            bool kill = inU && !((A >> l) & 1ull) && ((loc & A) != 0ull);
            unsigned long long K = __ballot(kill);
            U &= ~(A | K);
        }
        if (l == 0) selw_out[(size_t)img*NW + c] = sel;

        // ---- update future dead bits (only if anything selected) ----
        if (sel != 0ull) {
            int m0 = c + 1;
            while (m0 < NCH) {
                int mn = m0 + 8;
                int n1 = NCH - mn; if (n1 > 8) n1 = 8; if (n1 < 0) n1 = 0;
                unsigned long long g1[8];
#pragma unroll
                for (int q = 0; q < 8; ++q)
                    if (q < n1) g1[q] = supT[matb + (size_t)c*S2 + (size_t)(mn+q)*64 + l];
#pragma unroll
                for (int q = 0; q < 8; ++q)
                    if (q < n0) dead32 |= ((g0[q] & sel) != 0ull) ? (1u << (m0 + q)) : 0u;
#pragma unroll
                for (int q = 0; q < 8; ++q) g0[q] = g1[q];
                m0 = mn; n0 = n1;
            }
        }
        loc = nloc;
    }
}

// =====================================================================
// K4: merged eff + nsteps. One block per image. Transposed (coalesced) reads.
// =====================================================================
__global__ __launch_bounds__(BLOCK) void effsteps_kernel(
    const unsigned long long* __restrict__ supT,
    const unsigned long long* __restrict__ selw,
    const int* __restrict__ sgt, const float* __restrict__ soa,
    int* __restrict__ eff, int* __restrict__ nsteps, int imgs)
{
    const int img = blockIdx.x, t = threadIdx.x;
    const int lane = t & 63, wave = t >> 6;
    const size_t stride = (size_t)imgs * S2, base = (size_t)img * S2;
    const unsigned long long* M = supT + (size_t)img * NW * S2;
    __shared__ unsigned long long ss[NW];
    __shared__ unsigned hist[S2];
    __shared__ int ints[2*NWAVES];
    __shared__ unsigned wsum[NWAVES];
    __shared__ int bm[NWAVES];
    if (t < NW) ss[t] = selw[(size_t)img*NW + t];
    for (int x = t; x < S2; x += BLOCK) hist[x] = 0u;
    __syncthreads();

    int myV = 0, mySc = 0;
#pragma unroll
    for (int k = 0; k < 8; ++k) {
        const int j = k*BLOCK + t;
        int g = sgt[base + j];
        float a = soa[1*stride+base+j], b = soa[3*stride+base+j];
        bool valid = (g >= 0) && ((b - a) > 0.f);
        bool selb  = (ss[j>>6] >> (j & 63)) & 1ull;
        int e;
        if (!valid) e = 0;
        else if (selb) { e = rank_of(ss, j); ++myV; ++mySc; }
        else {
            ++myV;
            int istar = -1;
#pragma unroll
            for (int w = 0; w < NW; ++w) {
                unsigned long long f = M[(size_t)w*S2 + j] & ss[w];
                if (istar < 0 && f) istar = w*64 + __builtin_ctzll(f);
            }
            if (istar < 0) e = EFF_INF;
            else { e = rank_of(ss, istar) + 1; atomicAdd(&hist[e - 1], 1u); }
        }
        eff[(size_t)img*S2 + j] = e;
    }
    __syncthreads();

    int v = myV, sc = mySc;
    for (int o = 32; o > 0; o >>= 1) { v += __shfl_down(v, o); sc += __shfl_down(sc, o); }
    if (lane == 0) { ints[wave] = v; ints[NWAVES + wave] = sc; }
    __syncthreads();
    int V = 0, Sc = 0;
    for (int w = 0; w < NWAVES; ++w) { V += ints[w]; Sc += ints[NWAVES + w]; }

    unsigned loc[8]; unsigned s = 0;
#pragma unroll
    for (int k = 0; k < 8; ++k) { s += hist[t*8 + k]; loc[k] = s; }
    unsigned tot = s;
    for (int o = 1; o < 64; o <<= 1) {
        unsigned u = __shfl_up(tot, o);
        if (lane >= o) tot += u;
    }
    if (lane == 63) wsum[wave] = tot;
    __syncthreads();
    unsigned woff = 0;
    for (int w = 0; w < wave; ++w) woff += wsum[w];
    unsigned exclP = woff + tot - s;
    __syncthreads();
#pragma unroll
    for (int k = 0; k < 8; ++k) hist[t*8 + k] = exclP + loc[k];
    __syncthreads();

    int best = EFF_INF;
    for (int r = t; r < Sc; r += BLOCK) {
        unsigned rem = (r == 0) ? 0u : hist[r - 1];
        int alive = V - r - (int)rem;
        if (alive < 2) best = min(best, r);
    }
    for (int o = 32; o > 0; o >>= 1) best = min(best, __shfl_down(best, o));
    if (lane == 0) bm[wave] = best;
    __syncthreads();
    if (t == 0) {
        int b = bm[0];
        for (int w = 1; w < NWAVES; ++w) b = min(b, bm[w]);
        nsteps[img] = min(b, Sc);
    }
}

// =====================================================================
// K5: pair sums. Block = (16 selector slots, img); wave owns 4 slots in
// registers; per-block partials, no global atomics.
// =====================================================================
__global__ __launch_bounds__(BLOCK) void pairs_kernel(
    const float* __restrict__ soa, const int* __restrict__ sgt,
    const int* __restrict__ eff, const unsigned long long* __restrict__ selw,
    const int* __restrict__ nsteps, float* __restrict__ partials, int imgs)
{
    const int ic = blockIdx.x, img = blockIdx.y;
    const int t = threadIdx.x, wave = t >> 6, lane = t & 63;
    const size_t stride = (size_t)imgs * S2, base = (size_t)img * S2;
    __shared__ unsigned long long ss[NW];
    __shared__ float pw[NWAVES][4];
    __shared__ int anyact;
    if (t < NW) ss[t] = selw[(size_t)img*NW + t];
    if (t == 0) anyact = 0;
    __syncthreads();
    const int ns = nsteps[img];

    float bx1[4], by1[4], bx2[4], by2[4], f0[4], f1[4], f2[4], f3[4];
    int bgt[4], rk[4]; bool act[4];
    bool any = false;
#pragma unroll
    for (int u = 0; u < 4; ++u) {
        const int i = ic*SPB + wave*4 + u;
        bool selb = (ss[i>>6] >> (i & 63)) & 1ull;
        int r = rank_of(ss, i);
        rk[u] = r;
        act[u] = selb && (r < ns);
        any |= act[u];
        if (act[u]) {
            bx1[u] = soa[0*stride+base+i]; by1[u] = soa[1*stride+base+i];
            bx2[u] = soa[2*stride+base+i]; by2[u] = soa[3*stride+base+i];
            f0[u]  = soa[5*stride+base+i]; f1[u]  = soa[6*stride+base+i];
            f2[u]  = soa[7*stride+base+i]; f3[u]  = soa[8*stride+base+i];
            bgt[u] = sgt[base + i];
        } else {
            bx1[u]=by1[u]=bx2[u]=by2[u]=0.f; f0[u]=f1[u]=f2[u]=f3[u]=0.f; bgt[u]=-2;
        }
    }
    if (any && lane == 0) anyact = 1;   // benign same-value race
    __syncthreads();
    if (!anyact) {
        if (t < 4) partials[((size_t)img*PB + ic)*4 + t] = 0.f;
        return;
    }

    float ps[4] = {0,0,0,0}, pn[4] = {0,0,0,0}, qs[4] = {0,0,0,0}, qn[4] = {0,0,0,0};
    for (int jt = 0; jt < NCH; ++jt) {
        const int j = jt*64 + lane;
        const float jx1 = soa[0*stride+base+j], jy1 = soa[1*stride+base+j];
        const float jx2 = soa[2*stride+base+j], jy2 = soa[3*stride+base+j];
        const float jsc = soa[4*stride+base+j];
        const float j0  = soa[5*stride+base+j], j1  = soa[6*stride+base+j];
        const float j2  = soa[7*stride+base+j], j3  = soa[8*stride+base+j];
        const int   jgt = sgt[base + j];
        const int   jef = eff[(size_t)img*S2 + j];
#pragma unroll
        for (int u = 0; u < 4; ++u) {
            if (!act[u]) continue;                    // wave-uniform
            if (rk[u] < jef) {
                float iw = fminf(jx2, bx2[u]) - fmaxf(jx1, bx1[u]);
                float ih = fminf(jy2, by2[u]) - fmaxf(jy1, by1[u]);
                if (iw > 0.f && ih > 0.f) {
                    float d0 = j0 - f0[u], d1 = j1 - f1[u];
                    float d2 = j2 - f2[u], d3 = j3 - f3[u];
                    float diff = 0.25f*(d0*d0 + d1*d1 + d2*d2 + d3*d3);
                    bool check = diff < 0.1f;
                    bool same  = (jgt == bgt[u]);
                    if (same && !check)      { ps[u] += diff * jsc;       pn[u] += 1.f; }
                    else if (!same && check) { qs[u] += expf(-diff)*jsc;  qn[u] += 1.f; }
                }
            }
        }
    }

    float sPull = 0.f, cPull = 0.f, sPush = 0.f, cPush = 0.f;
#pragma unroll
    for (int u = 0; u < 4; ++u) {
        if (!act[u]) continue;                        // wave-uniform
        float a0 = ps[u], a1 = pn[u], a2 = qs[u], a3 = qn[u];
        for (int o = 32; o > 0; o >>= 1) {
            a0 += __shfl_down(a0, o); a1 += __shfl_down(a1, o);
            a2 += __shfl_down(a2, o); a3 += __shfl_down(a3, o);
        }
        if (lane == 0) {
            if (a1 > 0.f) { sPull += a0 / a1; cPull += 1.f; }
            if (a3 > 0.f) { sPush += a2 / a3; cPush += 1.f; }
        }
    }
    if (lane == 0) {
        pw[wave][0] = sPull; pw[wave][1] = cPull;
        pw[wave][2] = sPush; pw[wave][3] = cPush;
    }
    __syncthreads();
    if (t == 0) {
        float a = 0, b = 0, c = 0, d = 0;
        for (int w = 0; w < NWAVES; ++w) {
            a += pw[w][0]; b += pw[w][1]; c += pw[w][2]; d += pw[w][3];
        }
        float* p = partials + ((size_t)img*PB + ic)*4;
        p[0] = a; p[1] = b; p[2] = c; p[3] = d;
    }
}

// K6: sum per-block partials, form final losses.
__global__ __launch_bounds__(BLOCK) void finalize_kernel(
    const float* __restrict__ partials, float* __restrict__ out, int imgs)
{
    const int t = threadIdx.x;
    __shared__ float a[8][4];     // up to 8 images
    if (t < 32) ((float*)a)[t] = 0.f;
    __syncthreads();
    for (int e = t; e < imgs * PB; e += BLOCK) {
        int img = e / PB;
        const float* p = partials + (size_t)e * 4;
#pragma unroll
        for (int k = 0; k < 4; ++k) {
            float v = p[k];
            if (v != 0.f) atomicAdd(&a[img][k], v);
        }
    }
    __syncthreads();
    if (t == 0) {
        float push = 0.f, pull = 0.f;
        for (int i = 0; i < imgs; ++i) {
            pull += a[i][0] / (a[i][1] + 1e-6f);
            push += a[i][2] / (a[i][3] + 1e-6f);
        }
        out[0] = push / (float)imgs;   // push_loss
        out[1] = pull / (float)imgs;   // pull_loss
    }
}

// =====================================================================
// FALLBACK PATH (R1 kernel) — only if ws too small / N > 2048 / imgs > 8.
// =====================================================================
__global__ __launch_bounds__(BLOCK) void tagloss_kernel(
    const float* __restrict__ pred, const int* __restrict__ gt_inds,
    const float* __restrict__ proposals, float* __restrict__ ws, int N)
{
    const int img = blockIdx.x, t = threadIdx.x;
    const int lane = t & 63, wav = t >> 6;
    const float* P = proposals + (size_t)img * N * 5;
    const float* E = pred      + (size_t)img * N * 4;
    const int*   G = gt_inds   + (size_t)img * N;
    float x1[KMAX], y1[KMAX], x2[KMAX], y2[KMAX], sc[KMAX];
    float e0[KMAX], e1[KMAX], e2[KMAX], e3[KMAX];
    int gt[KMAX]; unsigned amask = 0u; int local_alive = 0;
#pragma unroll
    for (int k = 0; k < KMAX; ++k) {
        int j = k * BLOCK + t;
        if (j < N) {
            x1[k]=P[j*5+0]; y1[k]=P[j*5+1]; x2[k]=P[j*5+2]; y2[k]=P[j*5+3]; sc[k]=P[j*5+4];
            e0[k]=E[j*4+0]; e1[k]=E[j*4+1]; e2[k]=E[j*4+2]; e3[k]=E[j*4+3]; gt[k]=G[j];
            if (gt[k] >= 0 && (y2[k]-y1[k]) > 0.0f) { amask |= 1u<<k; local_alive++; }
        } else { x1[k]=y1[k]=x2[k]=y2[k]=0.f; sc[k]=0.f; e0[k]=e1[k]=e2[k]=e3[k]=0.f; gt[k]=-1; }
    }
    __shared__ unsigned long long s_key[NWAVES];
    __shared__ float s_b[9];
    __shared__ float s_part[NWAVES][5];
    int alive_count;
    {
        float v = (float)local_alive;
#pragma unroll
        for (int o = 32; o > 0; o >>= 1) v += __shfl_down(v, o);
        if (lane == 0) s_part[wav][0] = v;
        __syncthreads();
        float tot = 0.f;
        for (int w = 0; w < NWAVES; ++w) tot += s_part[w][0];
        alive_count = (int)tot;
    }
    float tot_pull=0.f, tot_push=0.f, pull_cnt=0.f, push_cnt=0.f;
    while (alive_count >= 2) {
        unsigned long long key = 0ull;
#pragma unroll
        for (int k = 0; k < KMAX; ++k)
            if (amask & (1u<<k)) {
                unsigned long long kk = ((unsigned long long)__float_as_uint(sc[k])<<32)
                                      | (unsigned long long)(0xFFFFFFFFu - (unsigned)(k*BLOCK+t));
                if (kk > key) key = kk;
            }
#pragma unroll
        for (int o = 32; o > 0; o >>= 1) {
            unsigned long long ok = __shfl_down(key, o);
            if (ok > key) key = ok;
        }
        if (lane == 0) s_key[wav] = key;
        __syncthreads();
        unsigned long long bk = s_key[0];
        for (int w = 1; w < NWAVES; ++w) if (s_key[w] > bk) bk = s_key[w];
        const int i = (int)(0xFFFFFFFFu - (unsigned)(bk & 0xFFFFFFFFull));
        if ((i & (BLOCK-1)) == t) {
            int k = i / BLOCK;
            s_b[0]=x1[k]; s_b[1]=y1[k]; s_b[2]=x2[k]; s_b[3]=y2[k];
            s_b[4]=e0[k]; s_b[5]=e1[k]; s_b[6]=e2[k]; s_b[7]=e3[k];
            s_b[8]=__int_as_float(gt[k]);
        }
        __syncthreads();
        const float bx1=s_b[0], by1=s_b[1], bx2=s_b[2], by2=s_b[3];
        const float f0=s_b[4], f1=s_b[5], f2=s_b[6], f3=s_b[7];
        const int bgt = __float_as_int(s_b[8]);
        const float areai = (bx2-bx1)*(by2-by1);
        float psum=0.f,qsum=0.f,pn=0.f,qn=0.f,scnt=0.f;
#pragma unroll
        for (int k = 0; k < KMAX; ++k) {
            if (!(amask & (1u<<k))) continue;
            int j = k*BLOCK+t;
            if (j == i) { amask &= ~(1u<<k); continue; }
            float iw = fmaxf(fminf(x2[k],bx2)-fmaxf(x1[k],bx1),0.f);
            float ih = fmaxf(fminf(y2[k],by2)-fmaxf(y1[k],by1),0.f);
            float inter = iw*ih;
            float uni = (x2[k]-x1[k])*(y2[k]-y1[k]) + areai - inter;
            float iou = inter / fmaxf(uni, 1e-12f);
            if (iou > 0.f) {
                float d0=e0[k]-f0,d1=e1[k]-f1,d2=e2[k]-f2,d3=e3[k]-f3;
                float diff = 0.25f*(d0*d0+d1*d1+d2*d2+d3*d3);
                bool check = diff < 0.1f;
                bool same = (gt[k]==bgt);
                if (same && !check) { psum += diff*sc[k]; pn += 1.f; }
                if (!same && check) { qsum += __expf(-diff)*sc[k]; qn += 1.f; }
                if (check)          { amask &= ~(1u<<k); scnt += 1.f; }
            }
        }
        float r0=psum,r1=pn,r2=qsum,r3=qn,r4=scnt;
#pragma unroll
        for (int o = 32; o > 0; o >>= 1) {
            r0+=__shfl_down(r0,o); r1+=__shfl_down(r1,o); r2+=__shfl_down(r2,o);
            r3+=__shfl_down(r3,o); r4+=__shfl_down(r4,o);
        }
        if (lane == 0) { s_part[wav][0]=r0;s_part[wav][1]=r1;s_part[wav][2]=r2;s_part[wav][3]=r3;s_part[wav][4]=r4; }
        __syncthreads();
        float T0=0,T1=0,T2=0,T3=0,T4=0;
        for (int w = 0; w < NWAVES; ++w) {
            T0+=s_part[w][0];T1+=s_part[w][1];T2+=s_part[w][2];T3+=s_part[w][3];T4+=s_part[w][4];
        }
        if (T1 > 0.f) { tot_pull += T0/T1; pull_cnt += 1.f; }
        if (T3 > 0.f) { tot_push += T2/T3; push_cnt += 1.f; }
        alive_count -= 1 + (int)T4;
    }
    if (t == 0) {
        ws[img*2+0] = tot_push / (push_cnt + 1e-6f);
        ws[img*2+1] = tot_pull / (pull_cnt + 1e-6f);
    }
}

__global__ void finalize_fb_kernel(const float* __restrict__ ws,
                                   float* __restrict__ out, int imgs)
{
    if (threadIdx.x == 0 && blockIdx.x == 0) {
        float push = 0.f, pull = 0.f;
        for (int k = 0; k < imgs; ++k) { push += ws[2*k]; pull += ws[2*k+1]; }
        out[0] = push / (float)imgs;
        out[1] = pull / (float)imgs;
    }
}

// =====================================================================
extern "C" void kernel_launch(void* const* d_in, const int* in_sizes, int n_in,
                              void* d_out, int out_size, void* d_ws, size_t ws_size,
                              hipStream_t stream) {
    const float* pred      = (const float*)d_in[0];
    const int*   gt_inds   = (const int*)  d_in[1];
    const float* proposals = (const float*)d_in[2];
    const int imgs = in_sizes[3] / 80;     // gt_bboxes (IMGS,20,4)
    const int N    = in_sizes[1] / imgs;   // gt_inds (IMGS,N)

    size_t off = 0;
    auto alloc = [&](size_t b) { size_t o = off; off += (b + 255) & ~(size_t)255; return o; };
    const size_t soa_off  = alloc((size_t)9 * imgs * S2 * 4);
    const size_t sgt_off  = alloc((size_t)imgs * S2 * 4);
    const size_t sel_off  = alloc((size_t)imgs * NW * 8);
    const size_t eff_off  = alloc((size_t)imgs * S2 * 4);
    const size_t sup_off  = alloc((size_t)imgs * S2 * NW * 8);
    const size_t nst_off  = alloc((size_t)imgs * 4);
    const size_t par_off  = alloc((size_t)imgs * PB * 16);
    const size_t need = off;

    if (N <= S2 && imgs <= 8 && ws_size >= need) {
        char* w = (char*)d_ws;
        float*              soa  = (float*)(w + soa_off);
        int*                sgt  = (int*)(w + sgt_off);
        unsigned long long* sel  = (unsigned long long*)(w + sel_off);
        int*                eff  = (int*)(w + eff_off);
        unsigned long long* supT = (unsigned long long*)(w + sup_off);
        int*                nst  = (int*)(w + nst_off);
        float*              par  = (float*)(w + par_off);

        ranksort_kernel<<<dim3(S2/BLOCK, imgs), BLOCK, 0, stream>>>(
            pred, gt_inds, proposals, soa, sgt, N, imgs);
        supmat_kernel<<<dim3(NCH, NCH, imgs), BLOCK, 0, stream>>>(soa, supT, N, imgs);
        greedy_kernel<<<imgs, 64, 0, stream>>>(supT, sgt, soa, sel, imgs);
        effsteps_kernel<<<imgs, BLOCK, 0, stream>>>(supT, sel, sgt, soa, eff, nst, imgs);
        pairs_kernel<<<dim3(PB, imgs), BLOCK, 0, stream>>>(soa, sgt, eff, sel,
                                                           nst, par, imgs);
        finalize_kernel<<<1, BLOCK, 0, stream>>>(par, (float*)d_out, imgs);
    } else {
        float* ws = (float*)d_ws;
        tagloss_kernel<<<imgs, BLOCK, 0, stream>>>(pred, gt_inds, proposals, ws, N);
        finalize_fb_kernel<<<1, 64, 0, stream>>>(ws, (float*)d_out, imgs);
    }
}

// Round 7
// 246.026 us; speedup vs baseline: 19.5959x; 1.0053x over previous
//
#include <hip/hip_runtime.h>
#include <stdint.h>

#define BLOCK 256
#define KMAX 8
#define NWAVES (BLOCK / 64)
#define S2 2048          // padded N (pow2); N=2000 fits
#define NW 32            // 64-bit words per row (S2/64)
#define NCH 32           // 64-element chunks (S2/64)
#define SPB 16           // selector slots per pairs-block
#define PB (S2 / SPB)    // pairs blocks per image (128)
#define EFF_INF 0x7FFFFFFF

// rank(j) = number of selected elements with sorted index < j
__device__ inline int rank_of(const unsigned long long* ss, int j) {
    int jw = j >> 6, jb = j & 63;
    int rk = __popcll(ss[jw] & (jb ? (~0ull >> (64 - jb)) : 0ull));
    for (int w = 0; w < jw; ++w) rk += __popcll(ss[w]);
    return rk;
}

// =====================================================================
// K1: rank-by-counting sort (O(N^2), fully parallel) + scatter to sorted SoA.
// =====================================================================
__global__ __launch_bounds__(BLOCK) void ranksort_kernel(
    const float* __restrict__ pred, const int* __restrict__ gt_inds,
    const float* __restrict__ proposals,
    float* __restrict__ soa, int* __restrict__ sgt,
    int N, int imgs)
{
    const int img = blockIdx.y, t = threadIdx.x;
    const int i = blockIdx.x * BLOCK + t;
    __shared__ unsigned sb[S2];
    const float* P = proposals + (size_t)img * N * 5;
    const float* E = pred      + (size_t)img * N * 4;
    const int*   G = gt_inds   + (size_t)img * N;

    for (int kk = t; kk < S2; kk += BLOCK)
        sb[kk] = (kk < N) ? __float_as_uint(P[kk*5 + 4]) : 0u;
    __syncthreads();

    const size_t stride = (size_t)imgs * S2;
    const size_t base   = (size_t)img * S2;

    if (i >= N) {
        if (i < S2) {
#pragma unroll
            for (int a = 0; a < 9; ++a) soa[(size_t)a*stride + base + i] = 0.f;
            sgt[base + i] = -1;
        }
        return;
    }

    const unsigned my = sb[i];
    int p = 0;
    const uint4* sb4 = (const uint4*)sb;
    const int n4 = N >> 2;
    for (int q = 0; q < n4; ++q) {
        uint4 v = sb4[q];
        int jj = q * 4;
        p += (int)((v.x > my) | ((v.x == my) & (jj + 0 < i)));
        p += (int)((v.y > my) | ((v.y == my) & (jj + 1 < i)));
        p += (int)((v.z > my) | ((v.z == my) & (jj + 2 < i)));
        p += (int)((v.w > my) | ((v.w == my) & (jj + 3 < i)));
    }
    for (int jj = n4*4; jj < N; ++jj) {
        unsigned v = sb[jj];
        p += (int)((v > my) | ((v == my) & (jj < i)));
    }

    soa[0*stride + base + p] = P[i*5+0];
    soa[1*stride + base + p] = P[i*5+1];
    soa[2*stride + base + p] = P[i*5+2];
    soa[3*stride + base + p] = P[i*5+3];
    soa[4*stride + base + p] = P[i*5+4];
    soa[5*stride + base + p] = E[i*4+0];
    soa[6*stride + base + p] = E[i*4+1];
    soa[7*stride + base + p] = E[i*4+2];
    soa[8*stride + base + p] = E[i*4+3];
    sgt[base + p] = G[i];
}

// =====================================================================
// K2: suppression matrix, transposed layout supT[img][w][i] = bits over
// chunk-w elements j of sup(i,j) (valid by symmetry). The ballot bb runs
// over the 64 j-lanes for fixed i -> word jc of row i -> store at
// supT[jc][i]. Consumers only read supT[w][pos] for w <= pos>>6, so only
// blocks with jc <= ic are needed (lower triangle + diagonal).
// =====================================================================
__global__ __launch_bounds__(BLOCK) void supmat_kernel(
    const float* __restrict__ soa, unsigned long long* __restrict__ supT,
    int N, int imgs)
{
    const int ic = blockIdx.x, jc = blockIdx.y, img = blockIdx.z;
    if (ic < jc) return;   // only words w=jc <= ic = pos>>6 are ever read
    const int t = threadIdx.x, wave = t >> 6, lane = t & 63;
    const size_t stride = (size_t)imgs * S2, base = (size_t)img * S2;
    __shared__ float si[8][64];
    for (int idx = t; idx < 512; idx += BLOCK) {
        int f = idx >> 6, e = idx & 63;
        int a = (f < 4) ? f : f + 1;      // arrays {0,1,2,3,5,6,7,8}
        si[f][e] = soa[(size_t)a*stride + base + ic*64 + e];
    }
    __syncthreads();
    const int j = jc*64 + lane;
    const float jx1 = soa[0*stride+base+j], jy1 = soa[1*stride+base+j];
    const float jx2 = soa[2*stride+base+j], jy2 = soa[3*stride+base+j];
    const float j0  = soa[5*stride+base+j], j1  = soa[6*stride+base+j];
    const float j2  = soa[7*stride+base+j], j3  = soa[8*stride+base+j];
    const bool jin = (j < N);
    for (int ii = 0; ii < 16; ++ii) {
        int il = wave*16 + ii;
        int i  = ic*64 + il;
        float bx1 = si[0][il], by1 = si[1][il], bx2 = si[2][il], by2 = si[3][il];
        float f0  = si[4][il], f1  = si[5][il], f2  = si[6][il], f3  = si[7][il];
        bool s = false;
        if (jin && i < N) {
            float iw = fminf(jx2, bx2) - fmaxf(jx1, bx1);
            float ih = fminf(jy2, by2) - fmaxf(jy1, by1);
            if (iw > 0.f && ih > 0.f) {
                float d0 = j0-f0, d1 = j1-f1, d2 = j2-f2, d3 = j3-f3;
                float diff = 0.25f*(d0*d0 + d1*d1 + d2*d2 + d3*d3);
                s = diff < 0.1f;   // TAG_THR
            }
        }
        unsigned long long bb = __ballot(s);   // bits over j-lanes, fixed i
        if (lane == 0) supT[((size_t)img*NW + jc)*S2 + i] = bb;
    }
}

// =====================================================================
// K3: sequential chunked greedy, one wave per image. Per chunk: ONE batched
// vmcnt wait — fully-unrolled predicated gather of row words 0..c-1 plus
// the diag word (no dynamic register indexing). Dead test via AND with
// ssel (LDS, broadcast). Batch round-based resolve (exact: sup symmetric =>
// batch of lowest-alive-unsuppressed picks is conflict-free).
// =====================================================================
__global__ __launch_bounds__(64) void greedy_kernel(
    const unsigned long long* __restrict__ supT,
    const int* __restrict__ sgt, const float* __restrict__ soa,
    unsigned long long* __restrict__ selw_out, int imgs)
{
    const int img = blockIdx.x, l = threadIdx.x;
    const size_t matb = (size_t)img * NW * S2;
    const size_t stride = (size_t)imgs * S2, base = (size_t)img * S2;
    __shared__ unsigned long long ssel[NW];

    // per-lane validity: bit c = valid(j = c*64 + l)   (coalesced loads)
    unsigned vmask = 0u;
#pragma unroll
    for (int c = 0; c < NCH; ++c) {
        const int j = c*64 + l;
        int g = sgt[base + j];
        float a = soa[1*stride + base + j];
        float b = soa[3*stride + base + j];
        if (g >= 0 && (b - a) > 0.f) vmask |= (1u << c);
    }

    const unsigned long long lowmask = (l == 0) ? 0ull : (~0ull >> (64 - l));

    for (int c = 0; c < NCH; ++c) {
        const int j = c*64 + l;
        // ---- batched gather: words 0..c-1 of row j + diag word c ----
        unsigned long long rowv[NW];
        const unsigned long long loc = supT[matb + (size_t)c*S2 + j];
#pragma unroll
        for (int w = 0; w < NW; ++w)
            rowv[w] = (w < c) ? supT[matb + (size_t)w*S2 + j] : 0ull;
        unsigned long long acc = 0ull;
#pragma unroll
        for (int w = 0; w < NW; ++w)
            if (w < c) acc |= rowv[w] & ssel[w];

        // ---- batch resolve over this chunk ----
        bool alive = ((vmask >> c) & 1u) && (acc == 0ull);
        unsigned long long U = __ballot(alive);
        unsigned long long sel = 0ull;
        while (U) {
            bool inU = (U >> l) & 1ull;
            unsigned long long A = __ballot(inU && ((loc & U & lowmask) == 0ull));
            sel |= A;
            bool kill = inU && !((A >> l) & 1ull) && ((loc & A) != 0ull);
            unsigned long long K = __ballot(kill);
            U &= ~(A | K);
        }
        if (l == 0) {
            ssel[c] = sel;
            selw_out[(size_t)img*NW + c] = sel;
        }
        __syncthreads();   // single wave: cheap; orders LDS write->reads
    }
}

// =====================================================================
// K4: merged eff + nsteps. One block per image. Scans only w <= j>>6
// (a non-selected valid j's first selected suppressor always has idx < j).
// =====================================================================
__global__ __launch_bounds__(BLOCK) void effsteps_kernel(
    const unsigned long long* __restrict__ supT,
    const unsigned long long* __restrict__ selw,
    const int* __restrict__ sgt, const float* __restrict__ soa,
    int* __restrict__ eff, int* __restrict__ nsteps, int imgs)
{
    const int img = blockIdx.x, t = threadIdx.x;
    const int lane = t & 63, wave = t >> 6;
    const size_t stride = (size_t)imgs * S2, base = (size_t)img * S2;
    const unsigned long long* M = supT + (size_t)img * NW * S2;
    __shared__ unsigned long long ss[NW];
    __shared__ unsigned hist[S2];
    __shared__ int ints[2*NWAVES];
    __shared__ unsigned wsum[NWAVES];
    __shared__ int bm[NWAVES];
    if (t < NW) ss[t] = selw[(size_t)img*NW + t];
    for (int x = t; x < S2; x += BLOCK) hist[x] = 0u;
    __syncthreads();

    int myV = 0, mySc = 0;
#pragma unroll
    for (int k = 0; k < 8; ++k) {
        const int j = k*BLOCK + t;
        const int jw_ = j >> 6;
        int g = sgt[base + j];
        float a = soa[1*stride+base+j], b = soa[3*stride+base+j];
        bool valid = (g >= 0) && ((b - a) > 0.f);
        bool selb  = (ss[jw_] >> (j & 63)) & 1ull;
        int e;
        if (!valid) e = 0;
        else if (selb) { e = rank_of(ss, j); ++myV; ++mySc; }
        else {
            ++myV;
            int istar = -1;
#pragma unroll
            for (int w = 0; w < NW; ++w) {
                if (w <= jw_) {
                    unsigned long long f = M[(size_t)w*S2 + j] & ss[w];
                    if (istar < 0 && f) istar = w*64 + __builtin_ctzll(f);
                }
            }
            if (istar < 0) e = EFF_INF;
            else { e = rank_of(ss, istar) + 1; atomicAdd(&hist[e - 1], 1u); }
        }
        eff[(size_t)img*S2 + j] = e;
    }
    __syncthreads();

    int v = myV, sc = mySc;
    for (int o = 32; o > 0; o >>= 1) { v += __shfl_down(v, o); sc += __shfl_down(sc, o); }
    if (lane == 0) { ints[wave] = v; ints[NWAVES + wave] = sc; }
    __syncthreads();
    int V = 0, Sc = 0;
    for (int w = 0; w < NWAVES; ++w) { V += ints[w]; Sc += ints[NWAVES + w]; }

    unsigned loc[8]; unsigned s = 0;
#pragma unroll
    for (int k = 0; k < 8; ++k) { s += hist[t*8 + k]; loc[k] = s; }
    unsigned tot = s;
    for (int o = 1; o < 64; o <<= 1) {
        unsigned u = __shfl_up(tot, o);
        if (lane >= o) tot += u;
    }
    if (lane == 63) wsum[wave] = tot;
    __syncthreads();
    unsigned woff = 0;
    for (int w = 0; w < wave; ++w) woff += wsum[w];
    unsigned exclP = woff + tot - s;
    __syncthreads();
#pragma unroll
    for (int k = 0; k < 8; ++k) hist[t*8 + k] = exclP + loc[k];
    __syncthreads();

    int best = EFF_INF;
    for (int r = t; r < Sc; r += BLOCK) {
        unsigned rem = (r == 0) ? 0u : hist[r - 1];
        int alive = V - r - (int)rem;
        if (alive < 2) best = min(best, r);
    }
    for (int o = 32; o > 0; o >>= 1) best = min(best, __shfl_down(best, o));
    if (lane == 0) bm[wave] = best;
    __syncthreads();
    if (t == 0) {
        int b = bm[0];
        for (int w = 1; w < NWAVES; ++w) b = min(b, bm[w]);
        nsteps[img] = min(b, Sc);
    }
}

// =====================================================================
// K5: pair sums. Block = (16 selector slots, img); wave owns 4 slots in
// registers; per-block partials, no global atomics.
// =====================================================================
__global__ __launch_bounds__(BLOCK) void pairs_kernel(
    const float* __restrict__ soa, const int* __restrict__ sgt,
    const int* __restrict__ eff, const unsigned long long* __restrict__ selw,
    const int* __restrict__ nsteps, float* __restrict__ partials, int imgs)
{
    const int ic = blockIdx.x, img = blockIdx.y;
    const int t = threadIdx.x, wave = t >> 6, lane = t & 63;
    const size_t stride = (size_t)imgs * S2, base = (size_t)img * S2;
    __shared__ unsigned long long ss[NW];
    __shared__ float pw[NWAVES][4];
    __shared__ int anyact;
    if (t < NW) ss[t] = selw[(size_t)img*NW + t];
    if (t == 0) anyact = 0;
    __syncthreads();
    const int ns = nsteps[img];

    float bx1[4], by1[4], bx2[4], by2[4], f0[4], f1[4], f2[4], f3[4];
    int bgt[4], rk[4]; bool act[4];
    bool any = false;
#pragma unroll
    for (int u = 0; u < 4; ++u) {
        const int i = ic*SPB + wave*4 + u;
        bool selb = (ss[i>>6] >> (i & 63)) & 1ull;
        int r = rank_of(ss, i);
        rk[u] = r;
        act[u] = selb && (r < ns);
        any |= act[u];
        if (act[u]) {
            bx1[u] = soa[0*stride+base+i]; by1[u] = soa[1*stride+base+i];
            bx2[u] = soa[2*stride+base+i]; by2[u] = soa[3*stride+base+i];
            f0[u]  = soa[5*stride+base+i]; f1[u]  = soa[6*stride+base+i];
            f2[u]  = soa[7*stride+base+i]; f3[u]  = soa[8*stride+base+i];
            bgt[u] = sgt[base + i];
        } else {
            bx1[u]=by1[u]=bx2[u]=by2[u]=0.f; f0[u]=f1[u]=f2[u]=f3[u]=0.f; bgt[u]=-2;
        }
    }
    if (any && lane == 0) anyact = 1;   // benign same-value race
    __syncthreads();
    if (!anyact) {
        if (t < 4) partials[((size_t)img*PB + ic)*4 + t] = 0.f;
        return;
    }

    float ps[4] = {0,0,0,0}, pn[4] = {0,0,0,0}, qs[4] = {0,0,0,0}, qn[4] = {0,0,0,0};
    for (int jt = 0; jt < NCH; ++jt) {
        const int j = jt*64 + lane;
        const float jx1 = soa[0*stride+base+j], jy1 = soa[1*stride+base+j];
        const float jx2 = soa[2*stride+base+j], jy2 = soa[3*stride+base+j];
        const float jsc = soa[4*stride+base+j];
        const float j0  = soa[5*stride+base+j], j1  = soa[6*stride+base+j];
        const float j2  = soa[7*stride+base+j], j3  = soa[8*stride+base+j];
        const int   jgt = sgt[base + j];
        const int   jef = eff[(size_t)img*S2 + j];
#pragma unroll
        for (int u = 0; u < 4; ++u) {
            if (!act[u]) continue;                    // wave-uniform
            if (rk[u] < jef) {
                float iw = fminf(jx2, bx2[u]) - fmaxf(jx1, bx1[u]);
                float ih = fminf(jy2, by2[u]) - fmaxf(jy1, by1[u]);
                if (iw > 0.f && ih > 0.f) {
                    float d0 = j0 - f0[u], d1 = j1 - f1[u];
                    float d2 = j2 - f2[u], d3 = j3 - f3[u];
                    float diff = 0.25f*(d0*d0 + d1*d1 + d2*d2 + d3*d3);
                    bool check = diff < 0.1f;
                    bool same  = (jgt == bgt[u]);
                    if (same && !check)      { ps[u] += diff * jsc;       pn[u] += 1.f; }
                    else if (!same && check) { qs[u] += expf(-diff)*jsc;  qn[u] += 1.f; }
                }
            }
        }
    }

    float sPull = 0.f, cPull = 0.f, sPush = 0.f, cPush = 0.f;
#pragma unroll
    for (int u = 0; u < 4; ++u) {
        if (!act[u]) continue;                        // wave-uniform
        float a0 = ps[u], a1 = pn[u], a2 = qs[u], a3 = qn[u];
        for (int o = 32; o > 0; o >>= 1) {
            a0 += __shfl_down(a0, o); a1 += __shfl_down(a1, o);
            a2 += __shfl_down(a2, o); a3 += __shfl_down(a3, o);
        }
        if (lane == 0) {
            if (a1 > 0.f) { sPull += a0 / a1; cPull += 1.f; }
            if (a3 > 0.f) { sPush += a2 / a3; cPush += 1.f; }
        }
    }
    if (lane == 0) {
        pw[wave][0] = sPull; pw[wave][1] = cPull;
        pw[wave][2] = sPush; pw[wave][3] = cPush;
    }
    __syncthreads();
    if (t == 0) {
        float a = 0, b = 0, c = 0, d = 0;
        for (int w = 0; w < NWAVES; ++w) {
            a += pw[w][0]; b += pw[w][1]; c += pw[w][2]; d += pw[w][3];
        }
        float* p = partials + ((size_t)img*PB + ic)*4;
        p[0] = a; p[1] = b; p[2] = c; p[3] = d;
    }
}

// K6: sum per-block partials, form final losses.
__global__ __launch_bounds__(BLOCK) void finalize_kernel(
    const float* __restrict__ partials, float* __restrict__ out, int imgs)
{
    const int t = threadIdx.x;
    __shared__ float a[8][4];     // up to 8 images
    if (t < 32) ((float*)a)[t] = 0.f;
    __syncthreads();
    for (int e = t; e < imgs * PB; e += BLOCK) {
        int img = e / PB;
        const float* p = partials + (size_t)e * 4;
#pragma unroll
        for (int k = 0; k < 4; ++k) {
            float v = p[k];
            if (v != 0.f) atomicAdd(&a[img][k], v);
        }
    }
    __syncthreads();
    if (t == 0) {
        float push = 0.f, pull = 0.f;
        for (int i = 0; i < imgs; ++i) {
            pull += a[i][0] / (a[i][1] + 1e-6f);
            push += a[i][2] / (a[i][3] + 1e-6f);
        }
        out[0] = push / (float)imgs;   // push_loss
        out[1] = pull / (float)imgs;   // pull_loss
    }
}

// =====================================================================
// FALLBACK PATH (R1 kernel) — only if ws too small / N > 2048 / imgs > 8.
// =====================================================================
__global__ __launch_bounds__(BLOCK) void tagloss_kernel(
    const float* __restrict__ pred, const int* __restrict__ gt_inds,
    const float* __restrict__ proposals, float* __restrict__ ws, int N)
{
    const int img = blockIdx.x, t = threadIdx.x;
    const int lane = t & 63, wav = t >> 6;
    const float* P = proposals + (size_t)img * N * 5;
    const float* E = pred      + (size_t)img * N * 4;
    const int*   G = gt_inds   + (size_t)img * N;
    float x1[KMAX], y1[KMAX], x2[KMAX], y2[KMAX], sc[KMAX];
    float e0[KMAX], e1[KMAX], e2[KMAX], e3[KMAX];
    int gt[KMAX]; unsigned amask = 0u; int local_alive = 0;
#pragma unroll
    for (int k = 0; k < KMAX; ++k) {
        int j = k * BLOCK + t;
        if (j < N) {
            x1[k]=P[j*5+0]; y1[k]=P[j*5+1]; x2[k]=P[j*5+2]; y2[k]=P[j*5+3]; sc[k]=P[j*5+4];
            e0[k]=E[j*4+0]; e1[k]=E[j*4+1]; e2[k]=E[j*4+2]; e3[k]=E[j*4+3]; gt[k]=G[j];
            if (gt[k] >= 0 && (y2[k]-y1[k]) > 0.0f) { amask |= 1u<<k; local_alive++; }
        } else { x1[k]=y1[k]=x2[k]=y2[k]=0.f; sc[k]=0.f; e0[k]=e1[k]=e2[k]=e3[k]=0.f; gt[k]=-1; }
    }
    __shared__ unsigned long long s_key[NWAVES];
    __shared__ float s_b[9];
    __shared__ float s_part[NWAVES][5];
    int alive_count;
    {
        float v = (float)local_alive;
#pragma unroll
        for (int o = 32; o > 0; o >>= 1) v += __shfl_down(v, o);
        if (lane == 0) s_part[wav][0] = v;
        __syncthreads();
        float tot = 0.f;
        for (int w = 0; w < NWAVES; ++w) tot += s_part[w][0];
        alive_count = (int)tot;
    }
    float tot_pull=0.f, tot_push=0.f, pull_cnt=0.f, push_cnt=0.f;
    while (alive_count >= 2) {
        unsigned long long key = 0ull;
#pragma unroll
        for (int k = 0; k < KMAX; ++k)
            if (amask & (1u<<k)) {
                unsigned long long kk = ((unsigned long long)__float_as_uint(sc[k])<<32)
                                      | (unsigned long long)(0xFFFFFFFFu - (unsigned)(k*BLOCK+t));
                if (kk > key) key = kk;
            }
#pragma unroll
        for (int o = 32; o > 0; o >>= 1) {
            unsigned long long ok = __shfl_down(key, o);
            if (ok > key) key = ok;
        }
        if (lane == 0) s_key[wav] = key;
        __syncthreads();
        unsigned long long bk = s_key[0];
        for (int w = 1; w < NWAVES; ++w) if (s_key[w] > bk) bk = s_key[w];
        const int i = (int)(0xFFFFFFFFu - (unsigned)(bk & 0xFFFFFFFFull));
        if ((i & (BLOCK-1)) == t) {
            int k = i / BLOCK;
            s_b[0]=x1[k]; s_b[1]=y1[k]; s_b[2]=x2[k]; s_b[3]=y2[k];
            s_b[4]=e0[k]; s_b[5]=e1[k]; s_b[6]=e2[k]; s_b[7]=e3[k];
            s_b[8]=__int_as_float(gt[k]);
        }
        __syncthreads();
        const float bx1=s_b[0], by1=s_b[1], bx2=s_b[2], by2=s_b[3];
        const float f0=s_b[4], f1=s_b[5], f2=s_b[6], f3=s_b[7];
        const int bgt = __float_as_int(s_b[8]);
        const float areai = (bx2-bx1)*(by2-by1);
        float psum=0.f,qsum=0.f,pn=0.f,qn=0.f,scnt=0.f;
#pragma unroll
        for (int k = 0; k < KMAX; ++k) {
            if (!(amask & (1u<<k))) continue;
            int j = k*BLOCK+t;
            if (j == i) { amask &= ~(1u<<k); continue; }
            float iw = fmaxf(fminf(x2[k],bx2)-fmaxf(x1[k],bx1),0.f);
            float ih = fmaxf(fminf(y2[k],by2)-fmaxf(y1[k],by1),0.f);
            float inter = iw*ih;
            float uni = (x2[k]-x1[k])*(y2[k]-y1[k]) + areai - inter;
            float iou = inter / fmaxf(uni, 1e-12f);
            if (iou > 0.f) {
                float d0=e0[k]-f0,d1=e1[k]-f1,d2=e2[k]-f2,d3=e3[k]-f3;
                float diff = 0.25f*(d0*d0+d1*d1+d2*d2+d3*d3);
                bool check = diff < 0.1f;
                bool same = (gt[k]==bgt);
                if (same && !check) { psum += diff*sc[k]; pn += 1.f; }
                if (!same && check) { qsum += __expf(-diff)*sc[k]; qn += 1.f; }
                if (check)          { amask &= ~(1u<<k); scnt += 1.f; }
            }
        }
        float r0=psum,r1=pn,r2=qsum,r3=qn,r4=scnt;
#pragma unroll
        for (int o = 32; o > 0; o >>= 1) {
            r0+=__shfl_down(r0,o); r1+=__shfl_down(r1,o); r2+=__shfl_down(r2,o);
            r3+=__shfl_down(r3,o); r4+=__shfl_down(r4,o);
        }
        if (lane == 0) { s_part[wav][0]=r0;s_part[wav][1]=r1;s_part[wav][2]=r2;s_part[wav][3]=r3;s_part[wav][4]=r4; }
        __syncthreads();
        float T0=0,T1=0,T2=0,T3=0,T4=0;
        for (int w = 0; w < NWAVES; ++w) {
            T0+=s_part[w][0];T1+=s_part[w][1];T2+=s_part[w][2];T3+=s_part[w][3];T4+=s_part[w][4];
        }
        if (T1 > 0.f) { tot_pull += T0/T1; pull_cnt += 1.f; }
        if (T3 > 0.f) { tot_push += T2/T3; push_cnt += 1.f; }
        alive_count -= 1 + (int)T4;
    }
    if (t == 0) {
        ws[img*2+0] = tot_push / (push_cnt + 1e-6f);
        ws[img*2+1] = tot_pull / (pull_cnt + 1e-6f);
    }
}

__global__ void finalize_fb_kernel(const float* __restrict__ ws,
                                   float* __restrict__ out, int imgs)
{
    if (threadIdx.x == 0 && blockIdx.x == 0) {
        float push = 0.f, pull = 0.f;
        for (int k = 0; k < imgs; ++k) { push += ws[2*k]; pull += ws[2*k+1]; }
        out[0] = push / (float)imgs;
        out[1] = pull / (float)imgs;
    }
}

// =====================================================================
extern "C" void kernel_launch(void* const* d_in, const int* in_sizes, int n_in,
                              void* d_out, int out_size, void* d_ws, size_t ws_size,
                              hipStream_t stream) {
    const float* pred      = (const float*)d_in[0];
    const int*   gt_inds   = (const int*)  d_in[1];
    const float* proposals = (const float*)d_in[2];
    const int imgs = in_sizes[3] / 80;     // gt_bboxes (IMGS,20,4)
    const int N    = in_sizes[1] / imgs;   // gt_inds (IMGS,N)

    size_t off = 0;
    auto alloc = [&](size_t b) { size_t o = off; off += (b + 255) & ~(size_t)255; return o; };
    const size_t soa_off  = alloc((size_t)9 * imgs * S2 * 4);
    const size_t sgt_off  = alloc((size_t)imgs * S2 * 4);
    const size_t sel_off  = alloc((size_t)imgs * NW * 8);
    const size_t eff_off  = alloc((size_t)imgs * S2 * 4);
    const size_t sup_off  = alloc((size_t)imgs * S2 * NW * 8);
    const size_t nst_off  = alloc((size_t)imgs * 4);
    const size_t par_off  = alloc((size_t)imgs * PB * 16);
    const size_t need = off;

    if (N <= S2 && imgs <= 8 && ws_size >= need) {
        char* w = (char*)d_ws;
        float*              soa  = (float*)(w + soa_off);
        int*                sgt  = (int*)(w + sgt_off);
        unsigned long long* sel  = (unsigned long long*)(w + sel_off);
        int*                eff  = (int*)(w + eff_off);
        unsigned long long* supT = (unsigned long long*)(w + sup_off);
        int*                nst  = (int*)(w + nst_off);
        float*              par  = (float*)(w + par_off);

        ranksort_kernel<<<dim3(S2/BLOCK, imgs), BLOCK, 0, stream>>>(
            pred, gt_inds, proposals, soa, sgt, N, imgs);
        supmat_kernel<<<dim3(NCH, NCH, imgs), BLOCK, 0, stream>>>(soa, supT, N, imgs);
        greedy_kernel<<<imgs, 64, 0, stream>>>(supT, sgt, soa, sel, imgs);
        effsteps_kernel<<<imgs, BLOCK, 0, stream>>>(supT, sel, sgt, soa, eff, nst, imgs);
        pairs_kernel<<<dim3(PB, imgs), BLOCK, 0, stream>>>(soa, sgt, eff, sel,
                                                           nst, par, imgs);
        finalize_kernel<<<1, BLOCK, 0, stream>>>(par, (float*)d_out, imgs);
    } else {
        float* ws = (float*)d_ws;
        tagloss_kernel<<<imgs, BLOCK, 0, stream>>>(pred, gt_inds, proposals, ws, N);
        finalize_fb_kernel<<<1, 64, 0, stream>>>(ws, (float*)d_out, imgs);
    }
}

// Round 8
// 243.408 us; speedup vs baseline: 19.8067x; 1.0108x over previous
//
#include <hip/hip_runtime.h>
#include <stdint.h>

#define BLOCK 256
#define KMAX 8
#define NWAVES (BLOCK / 64)
#define S2 2048          // padded N (pow2); N=2000 fits
#define NW 32            // 64-bit words per row (S2/64)
#define NCH 32           // 64-element chunks (S2/64)
#define SPB 16           // selector slots per pairs-block
#define PB (S2 / SPB)    // pairs blocks per image (128)
#define EFF_INF 0x7FFFFFFF

// rank(j) = number of selected elements with sorted index < j
__device__ inline int rank_of(const unsigned long long* ss, int j) {
    int jw = j >> 6, jb = j & 63;
    int rk = __popcll(ss[jw] & (jb ? (~0ull >> (64 - jb)) : 0ull));
    for (int w = 0; w < jw; ++w) rk += __popcll(ss[w]);
    return rk;
}

// =====================================================================
// K1: rank-by-counting sort (O(N^2), fully parallel) + scatter to sorted SoA.
// =====================================================================
__global__ __launch_bounds__(BLOCK) void ranksort_kernel(
    const float* __restrict__ pred, const int* __restrict__ gt_inds,
    const float* __restrict__ proposals,
    float* __restrict__ soa, int* __restrict__ sgt,
    int N, int imgs)
{
    const int img = blockIdx.y, t = threadIdx.x;
    const int i = blockIdx.x * BLOCK + t;
    __shared__ unsigned sb[S2];
    const float* P = proposals + (size_t)img * N * 5;
    const float* E = pred      + (size_t)img * N * 4;
    const int*   G = gt_inds   + (size_t)img * N;

    for (int kk = t; kk < S2; kk += BLOCK)
        sb[kk] = (kk < N) ? __float_as_uint(P[kk*5 + 4]) : 0u;
    __syncthreads();

    const size_t stride = (size_t)imgs * S2;
    const size_t base   = (size_t)img * S2;

    if (i >= N) {
        if (i < S2) {
#pragma unroll
            for (int a = 0; a < 9; ++a) soa[(size_t)a*stride + base + i] = 0.f;
            sgt[base + i] = -1;
        }
        return;
    }

    const unsigned my = sb[i];
    int p = 0;
    const uint4* sb4 = (const uint4*)sb;
    const int n4 = N >> 2;
    for (int q = 0; q < n4; ++q) {
        uint4 v = sb4[q];
        int jj = q * 4;
        p += (int)((v.x > my) | ((v.x == my) & (jj + 0 < i)));
        p += (int)((v.y > my) | ((v.y == my) & (jj + 1 < i)));
        p += (int)((v.z > my) | ((v.z == my) & (jj + 2 < i)));
        p += (int)((v.w > my) | ((v.w == my) & (jj + 3 < i)));
    }
    for (int jj = n4*4; jj < N; ++jj) {
        unsigned v = sb[jj];
        p += (int)((v > my) | ((v == my) & (jj < i)));
    }

    soa[0*stride + base + p] = P[i*5+0];
    soa[1*stride + base + p] = P[i*5+1];
    soa[2*stride + base + p] = P[i*5+2];
    soa[3*stride + base + p] = P[i*5+3];
    soa[4*stride + base + p] = P[i*5+4];
    soa[5*stride + base + p] = E[i*4+0];
    soa[6*stride + base + p] = E[i*4+1];
    soa[7*stride + base + p] = E[i*4+2];
    soa[8*stride + base + p] = E[i*4+3];
    sgt[base + p] = G[i];
}

// =====================================================================
// K2: suppression matrix, transposed layout supT[img][w][i] = bits over
// chunk-w elements j of sup(i,j) (valid by symmetry). Ballot runs over the
// 64 j-lanes for fixed i -> word jc of row i -> store supT[jc][i].
// Consumers only read supT[w][pos] for w <= pos>>6 -> only jc <= ic blocks.
// =====================================================================
__global__ __launch_bounds__(BLOCK) void supmat_kernel(
    const float* __restrict__ soa, unsigned long long* __restrict__ supT,
    int N, int imgs)
{
    const int ic = blockIdx.x, jc = blockIdx.y, img = blockIdx.z;
    if (ic < jc) return;   // only words w=jc <= ic = pos>>6 are ever read
    const int t = threadIdx.x, wave = t >> 6, lane = t & 63;
    const size_t stride = (size_t)imgs * S2, base = (size_t)img * S2;
    __shared__ float si[8][64];
    for (int idx = t; idx < 512; idx += BLOCK) {
        int f = idx >> 6, e = idx & 63;
        int a = (f < 4) ? f : f + 1;      // arrays {0,1,2,3,5,6,7,8}
        si[f][e] = soa[(size_t)a*stride + base + ic*64 + e];
    }
    __syncthreads();
    const int j = jc*64 + lane;
    const float jx1 = soa[0*stride+base+j], jy1 = soa[1*stride+base+j];
    const float jx2 = soa[2*stride+base+j], jy2 = soa[3*stride+base+j];
    const float j0  = soa[5*stride+base+j], j1  = soa[6*stride+base+j];
    const float j2  = soa[7*stride+base+j], j3  = soa[8*stride+base+j];
    const bool jin = (j < N);
    for (int ii = 0; ii < 16; ++ii) {
        int il = wave*16 + ii;
        int i  = ic*64 + il;
        float bx1 = si[0][il], by1 = si[1][il], bx2 = si[2][il], by2 = si[3][il];
        float f0  = si[4][il], f1  = si[5][il], f2  = si[6][il], f3  = si[7][il];
        bool s = false;
        if (jin && i < N) {
            float iw = fminf(jx2, bx2) - fmaxf(jx1, bx1);
            float ih = fminf(jy2, by2) - fmaxf(jy1, by1);
            if (iw > 0.f && ih > 0.f) {
                float d0 = j0-f0, d1 = j1-f1, d2 = j2-f2, d3 = j3-f3;
                float diff = 0.25f*(d0*d0 + d1*d1 + d2*d2 + d3*d3);
                s = diff < 0.1f;   // TAG_THR
            }
        }
        unsigned long long bb = __ballot(s);   // bits over j-lanes, fixed i
        if (lane == 0) supT[((size_t)img*NW + jc)*S2 + i] = bb;
    }
}

// =====================================================================
// K3: sequential chunked greedy, 256 threads per image.
// - dead bits in LDS (sdead[NW]); diag words preloaded to LDS (16 KB).
// - per chunk: wave 0 resolves chunk c entirely from LDS (batch ballot
//   rounds; exact since sup is symmetric); then ALL 4 waves mark future
//   dead bits with one coalesced load batch of word c (disjoint groups ->
//   no LDS write conflicts).
// =====================================================================
__global__ __launch_bounds__(BLOCK) void greedy_kernel(
    const unsigned long long* __restrict__ supT,
    const int* __restrict__ sgt, const float* __restrict__ soa,
    unsigned long long* __restrict__ selw_out, int imgs)
{
    const int img = blockIdx.x, t = threadIdx.x;
    const int lane = t & 63, wave = t >> 6;
    const size_t matb = (size_t)img * NW * S2;
    const size_t stride = (size_t)imgs * S2, base = (size_t)img * S2;
    __shared__ unsigned long long sdiag[S2];     // [c*64+l] = supT[c][c*64+l]
    __shared__ unsigned long long sdead[NW];
    __shared__ unsigned long long ssel_c;

    // preload all diagonal-block words (coalesced; one batched wait)
    for (int e = t; e < S2; e += BLOCK) {
        int c = e >> 6, l = e & 63;
        sdiag[e] = supT[matb + (size_t)c*S2 + c*64 + l];
    }
    // init dead = invalid (group-major so each wave's ballot covers a group)
    for (int g = wave; g < NW; g += NWAVES) {
        int j = g*64 + lane;
        int gg = sgt[base + j];
        float a = soa[1*stride + base + j];
        float b = soa[3*stride + base + j];
        bool invalid = !(gg >= 0 && (b - a) > 0.f);
        unsigned long long bb = __ballot(invalid);
        if (lane == 0) sdead[g] = bb;
    }
    __syncthreads();

    const unsigned long long lowmask = (lane == 0) ? 0ull : (~0ull >> (64 - lane));

    for (int c = 0; c < NCH; ++c) {
        // ---- wave 0: resolve chunk c from LDS ----
        if (wave == 0) {
            const unsigned long long loc = sdiag[c*64 + lane];
            unsigned long long U = ~sdead[c];          // alive in chunk c
            unsigned long long sel = 0ull;
            while (U) {
                bool inU = (U >> lane) & 1ull;
                unsigned long long A = __ballot(inU && ((loc & U & lowmask) == 0ull));
                sel |= A;
                bool kill = inU && !((A >> lane) & 1ull) && ((loc & A) != 0ull);
                unsigned long long K = __ballot(kill);
                U &= ~(A | K);
            }
            if (lane == 0) {
                ssel_c = sel;
                selw_out[(size_t)img*NW + c] = sel;
            }
        }
        __syncthreads();
        const unsigned long long sel = ssel_c;
        // ---- all waves: mark future dead bits (word c, groups g > c) ----
        if (sel != 0ull) {
            for (int g = c + 1 + wave; g < NW; g += NWAVES) {
                int j = g*64 + lane;
                unsigned long long w_ = supT[matb + (size_t)c*S2 + j];
                bool d = (w_ & sel) != 0ull;
                unsigned long long bb = __ballot(d);
                if (lane == 0 && bb) sdead[g] |= bb;   // disjoint g per wave
            }
        }
        __syncthreads();
    }
}

// =====================================================================
// K4: merged eff + nsteps. One block per image. Scans only w <= j>>6
// (a non-selected valid j's first selected suppressor always has idx < j).
// =====================================================================
__global__ __launch_bounds__(BLOCK) void effsteps_kernel(
    const unsigned long long* __restrict__ supT,
    const unsigned long long* __restrict__ selw,
    const int* __restrict__ sgt, const float* __restrict__ soa,
    int* __restrict__ eff, int* __restrict__ nsteps, int imgs)
{
    const int img = blockIdx.x, t = threadIdx.x;
    const int lane = t & 63, wave = t >> 6;
    const size_t stride = (size_t)imgs * S2, base = (size_t)img * S2;
    const unsigned long long* M = supT + (size_t)img * NW * S2;
    __shared__ unsigned long long ss[NW];
    __shared__ unsigned hist[S2];
    __shared__ int ints[2*NWAVES];
    __shared__ unsigned wsum[NWAVES];
    __shared__ int bm[NWAVES];
    if (t < NW) ss[t] = selw[(size_t)img*NW + t];
    for (int x = t; x < S2; x += BLOCK) hist[x] = 0u;
    __syncthreads();

    int myV = 0, mySc = 0;
#pragma unroll
    for (int k = 0; k < 8; ++k) {
        const int j = k*BLOCK + t;
        const int jw_ = j >> 6;
        int g = sgt[base + j];
        float a = soa[1*stride+base+j], b = soa[3*stride+base+j];
        bool valid = (g >= 0) && ((b - a) > 0.f);
        bool selb  = (ss[jw_] >> (j & 63)) & 1ull;
        int e;
        if (!valid) e = 0;
        else if (selb) { e = rank_of(ss, j); ++myV; ++mySc; }
        else {
            ++myV;
            int istar = -1;
#pragma unroll
            for (int w = 0; w < NW; ++w) {
                if (w <= jw_) {
                    unsigned long long f = M[(size_t)w*S2 + j] & ss[w];
                    if (istar < 0 && f) istar = w*64 + __builtin_ctzll(f);
                }
            }
            if (istar < 0) e = EFF_INF;
            else { e = rank_of(ss, istar) + 1; atomicAdd(&hist[e - 1], 1u); }
        }
        eff[(size_t)img*S2 + j] = e;
    }
    __syncthreads();

    int v = myV, sc = mySc;
    for (int o = 32; o > 0; o >>= 1) { v += __shfl_down(v, o); sc += __shfl_down(sc, o); }
    if (lane == 0) { ints[wave] = v; ints[NWAVES + wave] = sc; }
    __syncthreads();
    int V = 0, Sc = 0;
    for (int w = 0; w < NWAVES; ++w) { V += ints[w]; Sc += ints[NWAVES + w]; }

    unsigned loc[8]; unsigned s = 0;
#pragma unroll
    for (int k = 0; k < 8; ++k) { s += hist[t*8 + k]; loc[k] = s; }
    unsigned tot = s;
    for (int o = 1; o < 64; o <<= 1) {
        unsigned u = __shfl_up(tot, o);
        if (lane >= o) tot += u;
    }
    if (lane == 63) wsum[wave] = tot;
    __syncthreads();
    unsigned woff = 0;
    for (int w = 0; w < wave; ++w) woff += wsum[w];
    unsigned exclP = woff + tot - s;
    __syncthreads();
#pragma unroll
    for (int k = 0; k < 8; ++k) hist[t*8 + k] = exclP + loc[k];
    __syncthreads();

    int best = EFF_INF;
    for (int r = t; r < Sc; r += BLOCK) {
        unsigned rem = (r == 0) ? 0u : hist[r - 1];
        int alive = V - r - (int)rem;
        if (alive < 2) best = min(best, r);
    }
    for (int o = 32; o > 0; o >>= 1) best = min(best, __shfl_down(best, o));
    if (lane == 0) bm[wave] = best;
    __syncthreads();
    if (t == 0) {
        int b = bm[0];
        for (int w = 1; w < NWAVES; ++w) b = min(b, bm[w]);
        nsteps[img] = min(b, Sc);
    }
}

// =====================================================================
// K5: pair sums. Block = (16 selector slots, img); wave owns 4 slots in
// registers; per-block partials, no global atomics.
// =====================================================================
__global__ __launch_bounds__(BLOCK) void pairs_kernel(
    const float* __restrict__ soa, const int* __restrict__ sgt,
    const int* __restrict__ eff, const unsigned long long* __restrict__ selw,
    const int* __restrict__ nsteps, float* __restrict__ partials, int imgs)
{
    const int ic = blockIdx.x, img = blockIdx.y;
    const int t = threadIdx.x, wave = t >> 6, lane = t & 63;
    const size_t stride = (size_t)imgs * S2, base = (size_t)img * S2;
    __shared__ unsigned long long ss[NW];
    __shared__ float pw[NWAVES][4];
    __shared__ int anyact;
    if (t < NW) ss[t] = selw[(size_t)img*NW + t];
    if (t == 0) anyact = 0;
    __syncthreads();
    const int ns = nsteps[img];

    float bx1[4], by1[4], bx2[4], by2[4], f0[4], f1[4], f2[4], f3[4];
    int bgt[4], rk[4]; bool act[4];
    bool any = false;
#pragma unroll
    for (int u = 0; u < 4; ++u) {
        const int i = ic*SPB + wave*4 + u;
        bool selb = (ss[i>>6] >> (i & 63)) & 1ull;
        int r = rank_of(ss, i);
        rk[u] = r;
        act[u] = selb && (r < ns);
        any |= act[u];
        if (act[u]) {
            bx1[u] = soa[0*stride+base+i]; by1[u] = soa[1*stride+base+i];
            bx2[u] = soa[2*stride+base+i]; by2[u] = soa[3*stride+base+i];
            f0[u]  = soa[5*stride+base+i]; f1[u]  = soa[6*stride+base+i];
            f2[u]  = soa[7*stride+base+i]; f3[u]  = soa[8*stride+base+i];
            bgt[u] = sgt[base + i];
        } else {
            bx1[u]=by1[u]=bx2[u]=by2[u]=0.f; f0[u]=f1[u]=f2[u]=f3[u]=0.f; bgt[u]=-2;
        }
    }
    if (any && lane == 0) anyact = 1;   // benign same-value race
    __syncthreads();
    if (!anyact) {
        if (t < 4) partials[((size_t)img*PB + ic)*4 + t] = 0.f;
        return;
    }

    float ps[4] = {0,0,0,0}, pn[4] = {0,0,0,0}, qs[4] = {0,0,0,0}, qn[4] = {0,0,0,0};
    for (int jt = 0; jt < NCH; ++jt) {
        const int j = jt*64 + lane;
        const float jx1 = soa[0*stride+base+j], jy1 = soa[1*stride+base+j];
        const float jx2 = soa[2*stride+base+j], jy2 = soa[3*stride+base+j];
        const float jsc = soa[4*stride+base+j];
        const float j0  = soa[5*stride+base+j], j1  = soa[6*stride+base+j];
        const float j2  = soa[7*stride+base+j], j3  = soa[8*stride+base+j];
        const int   jgt = sgt[base + j];
        const int   jef = eff[(size_t)img*S2 + j];
#pragma unroll
        for (int u = 0; u < 4; ++u) {
            if (!act[u]) continue;                    // wave-uniform
            if (rk[u] < jef) {
                float iw = fminf(jx2, bx2[u]) - fmaxf(jx1, bx1[u]);
                float ih = fminf(jy2, by2[u]) - fmaxf(jy1, by1[u]);
                if (iw > 0.f && ih > 0.f) {
                    float d0 = j0 - f0[u], d1 = j1 - f1[u];
                    float d2 = j2 - f2[u], d3 = j3 - f3[u];
                    float diff = 0.25f*(d0*d0 + d1*d1 + d2*d2 + d3*d3);
                    bool check = diff < 0.1f;
                    bool same  = (jgt == bgt[u]);
                    if (same && !check)      { ps[u] += diff * jsc;       pn[u] += 1.f; }
                    else if (!same && check) { qs[u] += expf(-diff)*jsc;  qn[u] += 1.f; }
                }
            }
        }
    }

    float sPull = 0.f, cPull = 0.f, sPush = 0.f, cPush = 0.f;
#pragma unroll
    for (int u = 0; u < 4; ++u) {
        if (!act[u]) continue;                        // wave-uniform
        float a0 = ps[u], a1 = pn[u], a2 = qs[u], a3 = qn[u];
        for (int o = 32; o > 0; o >>= 1) {
            a0 += __shfl_down(a0, o); a1 += __shfl_down(a1, o);
            a2 += __shfl_down(a2, o); a3 += __shfl_down(a3, o);
        }
        if (lane == 0) {
            if (a1 > 0.f) { sPull += a0 / a1; cPull += 1.f; }
            if (a3 > 0.f) { sPush += a2 / a3; cPush += 1.f; }
        }
    }
    if (lane == 0) {
        pw[wave][0] = sPull; pw[wave][1] = cPull;
        pw[wave][2] = sPush; pw[wave][3] = cPush;
    }
    __syncthreads();
    if (t == 0) {
        float a = 0, b = 0, c = 0, d = 0;
        for (int w = 0; w < NWAVES; ++w) {
            a += pw[w][0]; b += pw[w][1]; c += pw[w][2]; d += pw[w][3];
        }
        float* p = partials + ((size_t)img*PB + ic)*4;
        p[0] = a; p[1] = b; p[2] = c; p[3] = d;
    }
}

// K6: sum per-block partials, form final losses.
__global__ __launch_bounds__(BLOCK) void finalize_kernel(
    const float* __restrict__ partials, float* __restrict__ out, int imgs)
{
    const int t = threadIdx.x;
    __shared__ float a[8][4];     // up to 8 images
    if (t < 32) ((float*)a)[t] = 0.f;
    __syncthreads();
    for (int e = t; e < imgs * PB; e += BLOCK) {
        int img = e / PB;
        const float* p = partials + (size_t)e * 4;
#pragma unroll
        for (int k = 0; k < 4; ++k) {
            float v = p[k];
            if (v != 0.f) atomicAdd(&a[img][k], v);
        }
    }
    __syncthreads();
    if (t == 0) {
        float push = 0.f, pull = 0.f;
        for (int i = 0; i < imgs; ++i) {
            pull += a[i][0] / (a[i][1] + 1e-6f);
            push += a[i][2] / (a[i][3] + 1e-6f);
        }
        out[0] = push / (float)imgs;   // push_loss
        out[1] = pull / (float)imgs;   // pull_loss
    }
}

// =====================================================================
// FALLBACK PATH (R1 kernel) — only if ws too small / N > 2048 / imgs > 8.
// =====================================================================
__global__ __launch_bounds__(BLOCK) void tagloss_kernel(
    const float* __restrict__ pred, const int* __restrict__ gt_inds,
    const float* __restrict__ proposals, float* __restrict__ ws, int N)
{
    const int img = blockIdx.x, t = threadIdx.x;
    const int lane = t & 63, wav = t >> 6;
    const float* P = proposals + (size_t)img * N * 5;
    const float* E = pred      + (size_t)img * N * 4;
    const int*   G = gt_inds   + (size_t)img * N;
    float x1[KMAX], y1[KMAX], x2[KMAX], y2[KMAX], sc[KMAX];
    float e0[KMAX], e1[KMAX], e2[KMAX], e3[KMAX];
    int gt[KMAX]; unsigned amask = 0u; int local_alive = 0;
#pragma unroll
    for (int k = 0; k < KMAX; ++k) {
        int j = k * BLOCK + t;
        if (j < N) {
            x1[k]=P[j*5+0]; y1[k]=P[j*5+1]; x2[k]=P[j*5+2]; y2[k]=P[j*5+3]; sc[k]=P[j*5+4];
            e0[k]=E[j*4+0]; e1[k]=E[j*4+1]; e2[k]=E[j*4+2]; e3[k]=E[j*4+3]; gt[k]=G[j];
            if (gt[k] >= 0 && (y2[k]-y1[k]) > 0.0f) { amask |= 1u<<k; local_alive++; }
        } else { x1[k]=y1[k]=x2[k]=y2[k]=0.f; sc[k]=0.f; e0[k]=e1[k]=e2[k]=e3[k]=0.f; gt[k]=-1; }
    }
    __shared__ unsigned long long s_key[NWAVES];
    __shared__ float s_b[9];
    __shared__ float s_part[NWAVES][5];
    int alive_count;
    {
        float v = (float)local_alive;
#pragma unroll
        for (int o = 32; o > 0; o >>= 1) v += __shfl_down(v, o);
        if (lane == 0) s_part[wav][0] = v;
        __syncthreads();
        float tot = 0.f;
        for (int w = 0; w < NWAVES; ++w) tot += s_part[w][0];
        alive_count = (int)tot;
    }
    float tot_pull=0.f, tot_push=0.f, pull_cnt=0.f, push_cnt=0.f;
    while (alive_count >= 2) {
        unsigned long long key = 0ull;
#pragma unroll
        for (int k = 0; k < KMAX; ++k)
            if (amask & (1u<<k)) {
                unsigned long long kk = ((unsigned long long)__float_as_uint(sc[k])<<32)
                                      | (unsigned long long)(0xFFFFFFFFu - (unsigned)(k*BLOCK+t));
                if (kk > key) key = kk;
            }
#pragma unroll
        for (int o = 32; o > 0; o >>= 1) {
            unsigned long long ok = __shfl_down(key, o);
            if (ok > key) key = ok;
        }
        if (lane == 0) s_key[wav] = key;
        __syncthreads();
        unsigned long long bk = s_key[0];
        for (int w = 1; w < NWAVES; ++w) if (s_key[w] > bk) bk = s_key[w];
        const int i = (int)(0xFFFFFFFFu - (unsigned)(bk & 0xFFFFFFFFull));
        if ((i & (BLOCK-1)) == t) {
            int k = i / BLOCK;
            s_b[0]=x1[k]; s_b[1]=y1[k]; s_b[2]=x2[k]; s_b[3]=y2[k];
            s_b[4]=e0[k]; s_b[5]=e1[k]; s_b[6]=e2[k]; s_b[7]=e3[k];
            s_b[8]=__int_as_float(gt[k]);
        }
        __syncthreads();
        const float bx1=s_b[0], by1=s_b[1], bx2=s_b[2], by2=s_b[3];
        const float f0=s_b[4], f1=s_b[5], f2=s_b[6], f3=s_b[7];
        const int bgt = __float_as_int(s_b[8]);
        const float areai = (bx2-bx1)*(by2-by1);
        float psum=0.f,qsum=0.f,pn=0.f,qn=0.f,scnt=0.f;
#pragma unroll
        for (int k = 0; k < KMAX; ++k) {
            if (!(amask & (1u<<k))) continue;
            int j = k*BLOCK+t;
            if (j == i) { amask &= ~(1u<<k); continue; }
            float iw = fmaxf(fminf(x2[k],bx2)-fmaxf(x1[k],bx1),0.f);
            float ih = fmaxf(fminf(y2[k],by2)-fmaxf(y1[k],by1),0.f);
            float inter = iw*ih;
            float uni = (x2[k]-x1[k])*(y2[k]-y1[k]) + areai - inter;
            float iou = inter / fmaxf(uni, 1e-12f);
            if (iou > 0.f) {
                float d0=e0[k]-f0,d1=e1[k]-f1,d2=e2[k]-f2,d3=e3[k]-f3;
                float diff = 0.25f*(d0*d0+d1*d1+d2*d2+d3*d3);
                bool check = diff < 0.1f;
                bool same = (gt[k]==bgt);
                if (same && !check) { psum += diff*sc[k]; pn += 1.f; }
                if (!same && check) { qsum += __expf(-diff)*sc[k]; qn += 1.f; }
                if (check)          { amask &= ~(1u<<k); scnt += 1.f; }
            }
        }
        float r0=psum,r1=pn,r2=qsum,r3=qn,r4=scnt;
#pragma unroll
        for (int o = 32; o > 0; o >>= 1) {
            r0+=__shfl_down(r0,o); r1+=__shfl_down(r1,o); r2+=__shfl_down(r2,o);
            r3+=__shfl_down(r3,o); r4+=__shfl_down(r4,o);
        }
        if (lane == 0) { s_part[wav][0]=r0;s_part[wav][1]=r1;s_part[wav][2]=r2;s_part[wav][3]=r3;s_part[wav][4]=r4; }
        __syncthreads();
        float T0=0,T1=0,T2=0,T3=0,T4=0;
        for (int w = 0; w < NWAVES; ++w) {
            T0+=s_part[w][0];T1+=s_part[w][1];T2+=s_part[w][2];T3+=s_part[w][3];T4+=s_part[w][4];
        }
        if (T1 > 0.f) { tot_pull += T0/T1; pull_cnt += 1.f; }
        if (T3 > 0.f) { tot_push += T2/T3; push_cnt += 1.f; }
        alive_count -= 1 + (int)T4;
    }
    if (t == 0) {
        ws[img*2+0] = tot_push / (push_cnt + 1e-6f);
        ws[img*2+1] = tot_pull / (pull_cnt + 1e-6f);
    }
}

__global__ void finalize_fb_kernel(const float* __restrict__ ws,
                                   float* __restrict__ out, int imgs)
{
    if (threadIdx.x == 0 && blockIdx.x == 0) {
        float push = 0.f, pull = 0.f;
        for (int k = 0; k < imgs; ++k) { push += ws[2*k]; pull += ws[2*k+1]; }
        out[0] = push / (float)imgs;
        out[1] = pull / (float)imgs;
    }
}

// =====================================================================
extern "C" void kernel_launch(void* const* d_in, const int* in_sizes, int n_in,
                              void* d_out, int out_size, void* d_ws, size_t ws_size,
                              hipStream_t stream) {
    const float* pred      = (const float*)d_in[0];
    const int*   gt_inds   = (const int*)  d_in[1];
    const float* proposals = (const float*)d_in[2];
    const int imgs = in_sizes[3] / 80;     // gt_bboxes (IMGS,20,4)
    const int N    = in_sizes[1] / imgs;   // gt_inds (IMGS,N)

    size_t off = 0;
    auto alloc = [&](size_t b) { size_t o = off; off += (b + 255) & ~(size_t)255; return o; };
    const size_t soa_off  = alloc((size_t)9 * imgs * S2 * 4);
    const size_t sgt_off  = alloc((size_t)imgs * S2 * 4);
    const size_t sel_off  = alloc((size_t)imgs * NW * 8);
    const size_t eff_off  = alloc((size_t)imgs * S2 * 4);
    const size_t sup_off  = alloc((size_t)imgs * S2 * NW * 8);
    const size_t nst_off  = alloc((size_t)imgs * 4);
    const size_t par_off  = alloc((size_t)imgs * PB * 16);
    const size_t need = off;

    if (N <= S2 && imgs <= 8 && ws_size >= need) {
        char* w = (char*)d_ws;
        float*              soa  = (float*)(w + soa_off);
        int*                sgt  = (int*)(w + sgt_off);
        unsigned long long* sel  = (unsigned long long*)(w + sel_off);
        int*                eff  = (int*)(w + eff_off);
        unsigned long long* supT = (unsigned long long*)(w + sup_off);
        int*                nst  = (int*)(w + nst_off);
        float*              par  = (float*)(w + par_off);

        ranksort_kernel<<<dim3(S2/BLOCK, imgs), BLOCK, 0, stream>>>(
            pred, gt_inds, proposals, soa, sgt, N, imgs);
        supmat_kernel<<<dim3(NCH, NCH, imgs), BLOCK, 0, stream>>>(soa, supT, N, imgs);
        greedy_kernel<<<imgs, BLOCK, 0, stream>>>(supT, sgt, soa, sel, imgs);
        effsteps_kernel<<<imgs, BLOCK, 0, stream>>>(supT, sel, sgt, soa, eff, nst, imgs);
        pairs_kernel<<<dim3(PB, imgs), BLOCK, 0, stream>>>(soa, sgt, eff, sel,
                                                           nst, par, imgs);
        finalize_kernel<<<1, BLOCK, 0, stream>>>(par, (float*)d_out, imgs);
    } else {
        float* ws = (float*)d_ws;
        tagloss_kernel<<<imgs, BLOCK, 0, stream>>>(pred, gt_inds, proposals, ws, N);
        finalize_fb_kernel<<<1, 64, 0, stream>>>(ws, (float*)d_out, imgs);
    }
}

// Round 9
// 207.937 us; speedup vs baseline: 23.1854x; 1.1706x over previous
//
#include <hip/hip_runtime.h>
#include <stdint.h>

#define BLOCK 256
#define KMAX 8
#define NWAVES (BLOCK / 64)
#define S2 2048          // padded N (pow2); N=2000 fits
#define NW 32            // 64-bit words per row (S2/64)
#define NCH 32           // 64-element chunks (S2/64)
#define SPB 16           // selector slots per pairs-block
#define PB (S2 / SPB)    // pairs blocks per image (128)
#define EFF_INF 0x7FFFFFFF

// rank(j) = number of selected elements with sorted index < j
__device__ inline int rank_of(const unsigned long long* ss, int j) {
    int jw = j >> 6, jb = j & 63;
    int rk = __popcll(ss[jw] & (jb ? (~0ull >> (64 - jb)) : 0ull));
    for (int w = 0; w < jw; ++w) rk += __popcll(ss[w]);
    return rk;
}

// =====================================================================
// K1: rank-by-counting sort (O(N^2), fully parallel) + scatter to sorted SoA.
// 4x-unrolled LDS count loop (independent b128 reads -> ILP hides LDS
// latency); payload global loads hoisted above the loop.
// =====================================================================
__global__ __launch_bounds__(BLOCK) void ranksort_kernel(
    const float* __restrict__ pred, const int* __restrict__ gt_inds,
    const float* __restrict__ proposals,
    float* __restrict__ soa, int* __restrict__ sgt,
    int N, int imgs)
{
    const int img = blockIdx.y, t = threadIdx.x;
    const int i = blockIdx.x * BLOCK + t;
    __shared__ unsigned sb[S2];
    const float* P = proposals + (size_t)img * N * 5;
    const float* E = pred      + (size_t)img * N * 4;
    const int*   G = gt_inds   + (size_t)img * N;

    for (int kk = t; kk < S2; kk += BLOCK)
        sb[kk] = (kk < N) ? __float_as_uint(P[kk*5 + 4]) : 0u;
    __syncthreads();

    const size_t stride = (size_t)imgs * S2;
    const size_t base   = (size_t)img * S2;

    if (i >= N) {
        if (i < S2) {
#pragma unroll
            for (int a = 0; a < 9; ++a) soa[(size_t)a*stride + base + i] = 0.f;
            sgt[base + i] = -1;
        }
        return;
    }

    // hoist payload loads: latency hides under the count loop
    const float p0 = P[i*5+0], p1 = P[i*5+1], p2 = P[i*5+2],
                p3 = P[i*5+3], p4 = P[i*5+4];
    const float q0 = E[i*4+0], q1 = E[i*4+1], q2 = E[i*4+2], q3 = E[i*4+3];
    const int   gg = G[i];

    const unsigned my = sb[i];
    int p = 0;
    const uint4* sb4 = (const uint4*)sb;
    const int n4 = N >> 2;
    int q = 0;
    for (; q + 4 <= n4; q += 4) {
        uint4 v0 = sb4[q], v1 = sb4[q+1], v2 = sb4[q+2], v3 = sb4[q+3];
        int jj = q * 4;
        p += (int)((v0.x > my) | ((v0.x == my) & (jj + 0  < i)));
        p += (int)((v0.y > my) | ((v0.y == my) & (jj + 1  < i)));
        p += (int)((v0.z > my) | ((v0.z == my) & (jj + 2  < i)));
        p += (int)((v0.w > my) | ((v0.w == my) & (jj + 3  < i)));
        p += (int)((v1.x > my) | ((v1.x == my) & (jj + 4  < i)));
        p += (int)((v1.y > my) | ((v1.y == my) & (jj + 5  < i)));
        p += (int)((v1.z > my) | ((v1.z == my) & (jj + 6  < i)));
        p += (int)((v1.w > my) | ((v1.w == my) & (jj + 7  < i)));
        p += (int)((v2.x > my) | ((v2.x == my) & (jj + 8  < i)));
        p += (int)((v2.y > my) | ((v2.y == my) & (jj + 9  < i)));
        p += (int)((v2.z > my) | ((v2.z == my) & (jj + 10 < i)));
        p += (int)((v2.w > my) | ((v2.w == my) & (jj + 11 < i)));
        p += (int)((v3.x > my) | ((v3.x == my) & (jj + 12 < i)));
        p += (int)((v3.y > my) | ((v3.y == my) & (jj + 13 < i)));
        p += (int)((v3.z > my) | ((v3.z == my) & (jj + 14 < i)));
        p += (int)((v3.w > my) | ((v3.w == my) & (jj + 15 < i)));
    }
    for (; q < n4; ++q) {
        uint4 v = sb4[q];
        int jj = q * 4;
        p += (int)((v.x > my) | ((v.x == my) & (jj + 0 < i)));
        p += (int)((v.y > my) | ((v.y == my) & (jj + 1 < i)));
        p += (int)((v.z > my) | ((v.z == my) & (jj + 2 < i)));
        p += (int)((v.w > my) | ((v.w == my) & (jj + 3 < i)));
    }
    for (int jj = n4*4; jj < N; ++jj) {
        unsigned v = sb[jj];
        p += (int)((v > my) | ((v == my) & (jj < i)));
    }

    soa[0*stride + base + p] = p0;
    soa[1*stride + base + p] = p1;
    soa[2*stride + base + p] = p2;
    soa[3*stride + base + p] = p3;
    soa[4*stride + base + p] = p4;
    soa[5*stride + base + p] = q0;
    soa[6*stride + base + p] = q1;
    soa[7*stride + base + p] = q2;
    soa[8*stride + base + p] = q3;
    sgt[base + p] = gg;
}

// =====================================================================
// K2: suppression matrix, transposed layout supT[img][w][i] = bits over
// chunk-w elements j of sup(i,j) (valid by symmetry). Ballot runs over the
// 64 j-lanes for fixed i -> word jc of row i -> store supT[jc][i].
// Consumers only read supT[w][pos] for w <= pos>>6 -> only jc <= ic blocks.
// =====================================================================
__global__ __launch_bounds__(BLOCK) void supmat_kernel(
    const float* __restrict__ soa, unsigned long long* __restrict__ supT,
    int N, int imgs)
{
    const int ic = blockIdx.x, jc = blockIdx.y, img = blockIdx.z;
    if (ic < jc) return;   // only words w=jc <= ic = pos>>6 are ever read
    const int t = threadIdx.x, wave = t >> 6, lane = t & 63;
    const size_t stride = (size_t)imgs * S2, base = (size_t)img * S2;
    __shared__ float si[8][64];
    for (int idx = t; idx < 512; idx += BLOCK) {
        int f = idx >> 6, e = idx & 63;
        int a = (f < 4) ? f : f + 1;      // arrays {0,1,2,3,5,6,7,8}
        si[f][e] = soa[(size_t)a*stride + base + ic*64 + e];
    }
    __syncthreads();
    const int j = jc*64 + lane;
    const float jx1 = soa[0*stride+base+j], jy1 = soa[1*stride+base+j];
    const float jx2 = soa[2*stride+base+j], jy2 = soa[3*stride+base+j];
    const float j0  = soa[5*stride+base+j], j1  = soa[6*stride+base+j];
    const float j2  = soa[7*stride+base+j], j3  = soa[8*stride+base+j];
    const bool jin = (j < N);
    for (int ii = 0; ii < 16; ++ii) {
        int il = wave*16 + ii;
        int i  = ic*64 + il;
        float bx1 = si[0][il], by1 = si[1][il], bx2 = si[2][il], by2 = si[3][il];
        float f0  = si[4][il], f1  = si[5][il], f2  = si[6][il], f3  = si[7][il];
        bool s = false;
        if (jin && i < N) {
            float iw = fminf(jx2, bx2) - fmaxf(jx1, bx1);
            float ih = fminf(jy2, by2) - fmaxf(jy1, by1);
            if (iw > 0.f && ih > 0.f) {
                float d0 = j0-f0, d1 = j1-f1, d2 = j2-f2, d3 = j3-f3;
                float diff = 0.25f*(d0*d0 + d1*d1 + d2*d2 + d3*d3);
                s = diff < 0.1f;   // TAG_THR
            }
        }
        unsigned long long bb = __ballot(s);   // bits over j-lanes, fixed i
        if (lane == 0) supT[((size_t)img*NW + jc)*S2 + i] = bb;
    }
}

// =====================================================================
// K3: sequential chunked greedy, 256 threads per image, software-pipelined.
// Update-word addresses depend only on c -> prefetch chunk c+1's words
// (double-buffered pfA/pfB, compile-time indexed via 2x-unrolled loop)
// while consuming chunk c's. Resolve runs on wave 0 from LDS.
// =====================================================================
#define GREEDY_ISSUE(c, dst)                                                   \
    _Pragma("unroll")                                                          \
    for (int q = 0; q < 8; ++q) {                                              \
        int g = (c) + 1 + wave + 4*q;                                          \
        dst[q] = (g < NW) ? supT[matb + (size_t)(c)*S2 + g*64 + lane] : 0ull;  \
    }

#define GREEDY_STEP(c, cur, nxt)                                               \
    {                                                                          \
        if (wave == 0) {                                                       \
            const unsigned long long loc = sdiag[(c)*64 + lane];               \
            unsigned long long U = ~sdead[(c)];                                \
            unsigned long long sel = 0ull;                                     \
            while (U) {                                                        \
                bool inU = (U >> lane) & 1ull;                                 \
                unsigned long long A = __ballot(inU && ((loc & U & lowmask) == 0ull)); \
                sel |= A;                                                      \
                bool kill = inU && !((A >> lane) & 1ull) && ((loc & A) != 0ull); \
                unsigned long long K = __ballot(kill);                         \
                U &= ~(A | K);                                                 \
            }                                                                  \
            if (lane == 0) {                                                   \
                ssel_c = sel;                                                  \
                selw_out[(size_t)img*NW + (c)] = sel;                          \
            }                                                                  \
        }                                                                      \
        __syncthreads();                                                       \
        const unsigned long long sel = ssel_c;                                 \
        if ((c) + 1 < NCH) { GREEDY_ISSUE((c)+1, nxt) }                        \
        if (sel != 0ull) {                                                     \
            _Pragma("unroll")                                                  \
            for (int q = 0; q < 8; ++q) {                                      \
                int g = (c) + 1 + wave + 4*q;                                  \
                if (g < NW) {                                                  \
                    bool d = (cur[q] & sel) != 0ull;                           \
                    unsigned long long bb = __ballot(d);                       \
                    if (lane == 0 && bb) sdead[g] |= bb;                       \
                }                                                              \
            }                                                                  \
        }                                                                      \
        __syncthreads();                                                       \
    }

__global__ __launch_bounds__(BLOCK) void greedy_kernel(
    const unsigned long long* __restrict__ supT,
    const int* __restrict__ sgt, const float* __restrict__ soa,
    unsigned long long* __restrict__ selw_out, int imgs)
{
    const int img = blockIdx.x, t = threadIdx.x;
    const int lane = t & 63, wave = t >> 6;
    const size_t matb = (size_t)img * NW * S2;
    const size_t stride = (size_t)imgs * S2, base = (size_t)img * S2;
    __shared__ unsigned long long sdiag[S2];     // [c*64+l] = supT[c][c*64+l]
    __shared__ unsigned long long sdead[NW];
    __shared__ unsigned long long ssel_c;

    // preload all diagonal-block words (coalesced; one batched wait)
    for (int e = t; e < S2; e += BLOCK) {
        int c = e >> 6, l = e & 63;
        sdiag[e] = supT[matb + (size_t)c*S2 + c*64 + l];
    }
    // init dead = invalid (group-major so each wave's ballot covers a group)
    for (int g = wave; g < NW; g += NWAVES) {
        int j = g*64 + lane;
        int gg = sgt[base + j];
        float a = soa[1*stride + base + j];
        float b = soa[3*stride + base + j];
        bool invalid = !(gg >= 0 && (b - a) > 0.f);
        unsigned long long bb = __ballot(invalid);
        if (lane == 0) sdead[g] = bb;
    }
    __syncthreads();

    const unsigned long long lowmask = (lane == 0) ? 0ull : (~0ull >> (64 - lane));

    unsigned long long pfA[8], pfB[8];
    GREEDY_ISSUE(0, pfA)
    for (int cc = 0; cc < NCH; cc += 2) {
        GREEDY_STEP(cc,     pfA, pfB)
        GREEDY_STEP(cc + 1, pfB, pfA)
    }
}

// =====================================================================
// K4: merged eff + nsteps. One block per image. Scans only w <= j>>6
// (a non-selected valid j's first selected suppressor always has idx < j).
// =====================================================================
__global__ __launch_bounds__(BLOCK) void effsteps_kernel(
    const unsigned long long* __restrict__ supT,
    const unsigned long long* __restrict__ selw,
    const int* __restrict__ sgt, const float* __restrict__ soa,
    int* __restrict__ eff, int* __restrict__ nsteps, int imgs)
{
    const int img = blockIdx.x, t = threadIdx.x;
    const int lane = t & 63, wave = t >> 6;
    const size_t stride = (size_t)imgs * S2, base = (size_t)img * S2;
    const unsigned long long* M = supT + (size_t)img * NW * S2;
    __shared__ unsigned long long ss[NW];
    __shared__ unsigned hist[S2];
    __shared__ int ints[2*NWAVES];
    __shared__ unsigned wsum[NWAVES];
    __shared__ int bm[NWAVES];
    if (t < NW) ss[t] = selw[(size_t)img*NW + t];
    for (int x = t; x < S2; x += BLOCK) hist[x] = 0u;
    __syncthreads();

    int myV = 0, mySc = 0;
#pragma unroll
    for (int k = 0; k < 8; ++k) {
        const int j = k*BLOCK + t;
        const int jw_ = j >> 6;
        int g = sgt[base + j];
        float a = soa[1*stride+base+j], b = soa[3*stride+base+j];
        bool valid = (g >= 0) && ((b - a) > 0.f);
        bool selb  = (ss[jw_] >> (j & 63)) & 1ull;
        int e;
        if (!valid) e = 0;
        else if (selb) { e = rank_of(ss, j); ++myV; ++mySc; }
        else {
            ++myV;
            int istar = -1;
#pragma unroll
            for (int w = 0; w < NW; ++w) {
                if (w <= jw_) {
                    unsigned long long f = M[(size_t)w*S2 + j] & ss[w];
                    if (istar < 0 && f) istar = w*64 + __builtin_ctzll(f);
                }
            }
            if (istar < 0) e = EFF_INF;
            else { e = rank_of(ss, istar) + 1; atomicAdd(&hist[e - 1], 1u); }
        }
        eff[(size_t)img*S2 + j] = e;
    }
    __syncthreads();

    int v = myV, sc = mySc;
    for (int o = 32; o > 0; o >>= 1) { v += __shfl_down(v, o); sc += __shfl_down(sc, o); }
    if (lane == 0) { ints[wave] = v; ints[NWAVES + wave] = sc; }
    __syncthreads();
    int V = 0, Sc = 0;
    for (int w = 0; w < NWAVES; ++w) { V += ints[w]; Sc += ints[NWAVES + w]; }

    unsigned loc[8]; unsigned s = 0;
#pragma unroll
    for (int k = 0; k < 8; ++k) { s += hist[t*8 + k]; loc[k] = s; }
    unsigned tot = s;
    for (int o = 1; o < 64; o <<= 1) {
        unsigned u = __shfl_up(tot, o);
        if (lane >= o) tot += u;
    }
    if (lane == 63) wsum[wave] = tot;
    __syncthreads();
    unsigned woff = 0;
    for (int w = 0; w < wave; ++w) woff += wsum[w];
    unsigned exclP = woff + tot - s;
    __syncthreads();
#pragma unroll
    for (int k = 0; k < 8; ++k) hist[t*8 + k] = exclP + loc[k];
    __syncthreads();

    int best = EFF_INF;
    for (int r = t; r < Sc; r += BLOCK) {
        unsigned rem = (r == 0) ? 0u : hist[r - 1];
        int alive = V - r - (int)rem;
        if (alive < 2) best = min(best, r);
    }
    for (int o = 32; o > 0; o >>= 1) best = min(best, __shfl_down(best, o));
    if (lane == 0) bm[wave] = best;
    __syncthreads();
    if (t == 0) {
        int b = bm[0];
        for (int w = 1; w < NWAVES; ++w) b = min(b, bm[w]);
        nsteps[img] = min(b, Sc);
    }
}

// =====================================================================
// K5: pair sums. Block = (16 selector slots, img); wave owns 4 slots in
// registers; per-block partials, no global atomics.
// =====================================================================
__global__ __launch_bounds__(BLOCK) void pairs_kernel(
    const float* __restrict__ soa, const int* __restrict__ sgt,
    const int* __restrict__ eff, const unsigned long long* __restrict__ selw,
    const int* __restrict__ nsteps, float* __restrict__ partials, int imgs)
{
    const int ic = blockIdx.x, img = blockIdx.y;
    const int t = threadIdx.x, wave = t >> 6, lane = t & 63;
    const size_t stride = (size_t)imgs * S2, base = (size_t)img * S2;
    __shared__ unsigned long long ss[NW];
    __shared__ float pw[NWAVES][4];
    __shared__ int anyact;
    if (t < NW) ss[t] = selw[(size_t)img*NW + t];
    if (t == 0) anyact = 0;
    __syncthreads();
    const int ns = nsteps[img];

    float bx1[4], by1[4], bx2[4], by2[4], f0[4], f1[4], f2[4], f3[4];
    int bgt[4], rk[4]; bool act[4];
    bool any = false;
#pragma unroll
    for (int u = 0; u < 4; ++u) {
        const int i = ic*SPB + wave*4 + u;
        bool selb = (ss[i>>6] >> (i & 63)) & 1ull;
        int r = rank_of(ss, i);
        rk[u] = r;
        act[u] = selb && (r < ns);
        any |= act[u];
        if (act[u]) {
            bx1[u] = soa[0*stride+base+i]; by1[u] = soa[1*stride+base+i];
            bx2[u] = soa[2*stride+base+i]; by2[u] = soa[3*stride+base+i];
            f0[u]  = soa[5*stride+base+i]; f1[u]  = soa[6*stride+base+i];
            f2[u]  = soa[7*stride+base+i]; f3[u]  = soa[8*stride+base+i];
            bgt[u] = sgt[base + i];
        } else {
            bx1[u]=by1[u]=bx2[u]=by2[u]=0.f; f0[u]=f1[u]=f2[u]=f3[u]=0.f; bgt[u]=-2;
        }
    }
    if (any && lane == 0) anyact = 1;   // benign same-value race
    __syncthreads();
    if (!anyact) {
        if (t < 4) partials[((size_t)img*PB + ic)*4 + t] = 0.f;
        return;
    }

    float ps[4] = {0,0,0,0}, pn[4] = {0,0,0,0}, qs[4] = {0,0,0,0}, qn[4] = {0,0,0,0};
    for (int jt = 0; jt < NCH; ++jt) {
        const int j = jt*64 + lane;
        const float jx1 = soa[0*stride+base+j], jy1 = soa[1*stride+base+j];
        const float jx2 = soa[2*stride+base+j], jy2 = soa[3*stride+base+j];
        const float jsc = soa[4*stride+base+j];
        const float j0  = soa[5*stride+base+j], j1  = soa[6*stride+base+j];
        const float j2  = soa[7*stride+base+j], j3  = soa[8*stride+base+j];
        const int   jgt = sgt[base + j];
        const int   jef = eff[(size_t)img*S2 + j];
#pragma unroll
        for (int u = 0; u < 4; ++u) {
            if (!act[u]) continue;                    // wave-uniform
            if (rk[u] < jef) {
                float iw = fminf(jx2, bx2[u]) - fmaxf(jx1, bx1[u]);
                float ih = fminf(jy2, by2[u]) - fmaxf(jy1, by1[u]);
                if (iw > 0.f && ih > 0.f) {
                    float d0 = j0 - f0[u], d1 = j1 - f1[u];
                    float d2 = j2 - f2[u], d3 = j3 - f3[u];
                    float diff = 0.25f*(d0*d0 + d1*d1 + d2*d2 + d3*d3);
                    bool check = diff < 0.1f;
                    bool same  = (jgt == bgt[u]);
                    if (same && !check)      { ps[u] += diff * jsc;       pn[u] += 1.f; }
                    else if (!same && check) { qs[u] += expf(-diff)*jsc;  qn[u] += 1.f; }
                }
            }
        }
    }

    float sPull = 0.f, cPull = 0.f, sPush = 0.f, cPush = 0.f;
#pragma unroll
    for (int u = 0; u < 4; ++u) {
        if (!act[u]) continue;                        // wave-uniform
        float a0 = ps[u], a1 = pn[u], a2 = qs[u], a3 = qn[u];
        for (int o = 32; o > 0; o >>= 1) {
            a0 += __shfl_down(a0, o); a1 += __shfl_down(a1, o);
            a2 += __shfl_down(a2, o); a3 += __shfl_down(a3, o);
        }
        if (lane == 0) {
            if (a1 > 0.f) { sPull += a0 / a1; cPull += 1.f; }
            if (a3 > 0.f) { sPush += a2 / a3; cPush += 1.f; }
        }
    }
    if (lane == 0) {
        pw[wave][0] = sPull; pw[wave][1] = cPull;
        pw[wave][2] = sPush; pw[wave][3] = cPush;
    }
    __syncthreads();
    if (t == 0) {
        float a = 0, b = 0, c = 0, d = 0;
        for (int w = 0; w < NWAVES; ++w) {
            a += pw[w][0]; b += pw[w][1]; c += pw[w][2]; d += pw[w][3];
        }
        float* p = partials + ((size_t)img*PB + ic)*4;
        p[0] = a; p[1] = b; p[2] = c; p[3] = d;
    }
}

// K6: sum per-block partials, form final losses.
__global__ __launch_bounds__(BLOCK) void finalize_kernel(
    const float* __restrict__ partials, float* __restrict__ out, int imgs)
{
    const int t = threadIdx.x;
    __shared__ float a[8][4];     // up to 8 images
    if (t < 32) ((float*)a)[t] = 0.f;
    __syncthreads();
    for (int e = t; e < imgs * PB; e += BLOCK) {
        int img = e / PB;
        const float* p = partials + (size_t)e * 4;
#pragma unroll
        for (int k = 0; k < 4; ++k) {
            float v = p[k];
            if (v != 0.f) atomicAdd(&a[img][k], v);
        }
    }
    __syncthreads();
    if (t == 0) {
        float push = 0.f, pull = 0.f;
        for (int i = 0; i < imgs; ++i) {
            pull += a[i][0] / (a[i][1] + 1e-6f);
            push += a[i][2] / (a[i][3] + 1e-6f);
        }
        out[0] = push / (float)imgs;   // push_loss
        out[1] = pull / (float)imgs;   // pull_loss
    }
}

// =====================================================================
// FALLBACK PATH (R1 kernel) — only if ws too small / N > 2048 / imgs > 8.
// =====================================================================
__global__ __launch_bounds__(BLOCK) void tagloss_kernel(
    const float* __restrict__ pred, const int* __restrict__ gt_inds,
    const float* __restrict__ proposals, float* __restrict__ ws, int N)
{
    const int img = blockIdx.x, t = threadIdx.x;
    const int lane = t & 63, wav = t >> 6;
    const float* P = proposals + (size_t)img * N * 5;
    const float* E = pred      + (size_t)img * N * 4;
    const int*   G = gt_inds   + (size_t)img * N;
    float x1[KMAX], y1[KMAX], x2[KMAX], y2[KMAX], sc[KMAX];
    float e0[KMAX], e1[KMAX], e2[KMAX], e3[KMAX];
    int gt[KMAX]; unsigned amask = 0u; int local_alive = 0;
#pragma unroll
    for (int k = 0; k < KMAX; ++k) {
        int j = k * BLOCK + t;
        if (j < N) {
            x1[k]=P[j*5+0]; y1[k]=P[j*5+1]; x2[k]=P[j*5+2]; y2[k]=P[j*5+3]; sc[k]=P[j*5+4];
            e0[k]=E[j*4+0]; e1[k]=E[j*4+1]; e2[k]=E[j*4+2]; e3[k]=E[j*4+3]; gt[k]=G[j];
            if (gt[k] >= 0 && (y2[k]-y1[k]) > 0.0f) { amask |= 1u<<k; local_alive++; }
        } else { x1[k]=y1[k]=x2[k]=y2[k]=0.f; sc[k]=0.f; e0[k]=e1[k]=e2[k]=e3[k]=0.f; gt[k]=-1; }
    }
    __shared__ unsigned long long s_key[NWAVES];
    __shared__ float s_b[9];
    __shared__ float s_part[NWAVES][5];
    int alive_count;
    {
        float v = (float)local_alive;
#pragma unroll
        for (int o = 32; o > 0; o >>= 1) v += __shfl_down(v, o);
        if (lane == 0) s_part[wav][0] = v;
        __syncthreads();
        float tot = 0.f;
        for (int w = 0; w < NWAVES; ++w) tot += s_part[w][0];
        alive_count = (int)tot;
    }
    float tot_pull=0.f, tot_push=0.f, pull_cnt=0.f, push_cnt=0.f;
    while (alive_count >= 2) {
        unsigned long long key = 0ull;
#pragma unroll
        for (int k = 0; k < KMAX; ++k)
            if (amask & (1u<<k)) {
                unsigned long long kk = ((unsigned long long)__float_as_uint(sc[k])<<32)
                                      | (unsigned long long)(0xFFFFFFFFu - (unsigned)(k*BLOCK+t));
                if (kk > key) key = kk;
            }
#pragma unroll
        for (int o = 32; o > 0; o >>= 1) {
            unsigned long long ok = __shfl_down(key, o);
            if (ok > key) key = ok;
        }
        if (lane == 0) s_key[wav] = key;
        __syncthreads();
        unsigned long long bk = s_key[0];
        for (int w = 1; w < NWAVES; ++w) if (s_key[w] > bk) bk = s_key[w];
        const int i = (int)(0xFFFFFFFFu - (unsigned)(bk & 0xFFFFFFFFull));
        if ((i & (BLOCK-1)) == t) {
            int k = i / BLOCK;
            s_b[0]=x1[k]; s_b[1]=y1[k]; s_b[2]=x2[k]; s_b[3]=y2[k];
            s_b[4]=e0[k]; s_b[5]=e1[k]; s_b[6]=e2[k]; s_b[7]=e3[k];
            s_b[8]=__int_as_float(gt[k]);
        }
        __syncthreads();
        const float bx1=s_b[0], by1=s_b[1], bx2=s_b[2], by2=s_b[3];
        const float f0=s_b[4], f1=s_b[5], f2=s_b[6], f3=s_b[7];
        const int bgt = __float_as_int(s_b[8]);
        const float areai = (bx2-bx1)*(by2-by1);
        float psum=0.f,qsum=0.f,pn=0.f,qn=0.f,scnt=0.f;
#pragma unroll
        for (int k = 0; k < KMAX; ++k) {
            if (!(amask & (1u<<k))) continue;
            int j = k*BLOCK+t;
            if (j == i) { amask &= ~(1u<<k); continue; }
            float iw = fmaxf(fminf(x2[k],bx2)-fmaxf(x1[k],bx1),0.f);
            float ih = fmaxf(fminf(y2[k],by2)-fmaxf(y1[k],by1),0.f);
            float inter = iw*ih;
            float uni = (x2[k]-x1[k])*(y2[k]-y1[k]) + areai - inter;
            float iou = inter / fmaxf(uni, 1e-12f);
            if (iou > 0.f) {
                float d0=e0[k]-f0,d1=e1[k]-f1,d2=e2[k]-f2,d3=e3[k]-f3;
                float diff = 0.25f*(d0*d0+d1*d1+d2*d2+d3*d3);
                bool check = diff < 0.1f;
                bool same = (gt[k]==bgt);
                if (same && !check) { psum += diff*sc[k]; pn += 1.f; }
                if (!same && check) { qsum += __expf(-diff)*sc[k]; qn += 1.f; }
                if (check)          { amask &= ~(1u<<k); scnt += 1.f; }
            }
        }
        float r0=psum,r1=pn,r2=qsum,r3=qn,r4=scnt;
#pragma unroll
        for (int o = 32; o > 0; o >>= 1) {
            r0+=__shfl_down(r0,o); r1+=__shfl_down(r1,o); r2+=__shfl_down(r2,o);
            r3+=__shfl_down(r3,o); r4+=__shfl_down(r4,o);
        }
        if (lane == 0) { s_part[wav][0]=r0;s_part[wav][1]=r1;s_part[wav][2]=r2;s_part[wav][3]=r3;s_part[wav][4]=r4; }
        __syncthreads();
        float T0=0,T1=0,T2=0,T3=0,T4=0;
        for (int w = 0; w < NWAVES; ++w) {
            T0+=s_part[w][0];T1+=s_part[w][1];T2+=s_part[w][2];T3+=s_part[w][3];T4+=s_part[w][4];
        }
        if (T1 > 0.f) { tot_pull += T0/T1; pull_cnt += 1.f; }
        if (T3 > 0.f) { tot_push += T2/T3; push_cnt += 1.f; }
        alive_count -= 1 + (int)T4;
    }
    if (t == 0) {
        ws[img*2+0] = tot_push / (push_cnt + 1e-6f);
        ws[img*2+1] = tot_pull / (pull_cnt + 1e-6f);
    }
}

__global__ void finalize_fb_kernel(const float* __restrict__ ws,
                                   float* __restrict__ out, int imgs)
{
    if (threadIdx.x == 0 && blockIdx.x == 0) {
        float push = 0.f, pull = 0.f;
        for (int k = 0; k < imgs; ++k) { push += ws[2*k]; pull += ws[2*k+1]; }
        out[0] = push / (float)imgs;
        out[1] = pull / (float)imgs;
    }
}

// =====================================================================
extern "C" void kernel_launch(void* const* d_in, const int* in_sizes, int n_in,
                              void* d_out, int out_size, void* d_ws, size_t ws_size,
                              hipStream_t stream) {
    const float* pred      = (const float*)d_in[0];
    const int*   gt_inds   = (const int*)  d_in[1];
    const float* proposals = (const float*)d_in[2];
    const int imgs = in_sizes[3] / 80;     // gt_bboxes (IMGS,20,4)
    const int N    = in_sizes[1] / imgs;   // gt_inds (IMGS,N)

    size_t off = 0;
    auto alloc = [&](size_t b) { size_t o = off; off += (b + 255) & ~(size_t)255; return o; };
    const size_t soa_off  = alloc((size_t)9 * imgs * S2 * 4);
    const size_t sgt_off  = alloc((size_t)imgs * S2 * 4);
    const size_t sel_off  = alloc((size_t)imgs * NW * 8);
    const size_t eff_off  = alloc((size_t)imgs * S2 * 4);
    const size_t sup_off  = alloc((size_t)imgs * S2 * NW * 8);
    const size_t nst_off  = alloc((size_t)imgs * 4);
    const size_t par_off  = alloc((size_t)imgs * PB * 16);
    const size_t need = off;

    if (N <= S2 && imgs <= 8 && ws_size >= need) {
        char* w = (char*)d_ws;
        float*              soa  = (float*)(w + soa_off);
        int*                sgt  = (int*)(w + sgt_off);
        unsigned long long* sel  = (unsigned long long*)(w + sel_off);
        int*                eff  = (int*)(w + eff_off);
        unsigned long long* supT = (unsigned long long*)(w + sup_off);
        int*                nst  = (int*)(w + nst_off);
        float*              par  = (float*)(w + par_off);

        ranksort_kernel<<<dim3(S2/BLOCK, imgs), BLOCK, 0, stream>>>(
            pred, gt_inds, proposals, soa, sgt, N, imgs);
        supmat_kernel<<<dim3(NCH, NCH, imgs), BLOCK, 0, stream>>>(soa, supT, N, imgs);
        greedy_kernel<<<imgs, BLOCK, 0, stream>>>(supT, sgt, soa, sel, imgs);
        effsteps_kernel<<<imgs, BLOCK, 0, stream>>>(supT, sel, sgt, soa, eff, nst, imgs);
        pairs_kernel<<<dim3(PB, imgs), BLOCK, 0, stream>>>(soa, sgt, eff, sel,
                                                           nst, par, imgs);
        finalize_kernel<<<1, BLOCK, 0, stream>>>(par, (float*)d_out, imgs);
    } else {
        float* ws = (float*)d_ws;
        tagloss_kernel<<<imgs, BLOCK, 0, stream>>>(pred, gt_inds, proposals, ws, N);
        finalize_fb_kernel<<<1, 64, 0, stream>>>(ws, (float*)d_out, imgs);
    }
}

// Round 10
// 178.488 us; speedup vs baseline: 27.0108x; 1.1650x over previous
//
#include <hip/hip_runtime.h>
#include <stdint.h>

#define BLOCK 256
#define KMAX 8
#define NWAVES (BLOCK / 64)
#define S2 2048          // padded N (pow2); N=2000 fits
#define NW 32            // 64-bit words per row (S2/64)
#define NCH 32           // 64-element chunks (S2/64)
#define SPB 16           // selector slots per pairs-block
#define PB (S2 / SPB)    // pairs blocks per image (128)
#define RB (S2 / BLOCK)  // rank blocks / j-slices (8)
#define EFF_INF 0x7FFFFFFF

// rank(j) = number of selected elements with sorted index < j
__device__ inline int rank_of(const unsigned long long* ss, int j) {
    int jw = j >> 6, jb = j & 63;
    int rk = __popcll(ss[jw] & (jb ? (~0ull >> (64 - jb)) : 0ull));
    for (int w = 0; w < jw; ++w) rk += __popcll(ss[w]);
    return rk;
}

// =====================================================================
// K1a: rank counting, split over j-slices for parallelism.
// grid (RB i-blocks, RB j-slices, imgs) = 256 blocks. Partial counts to ws
// (coalesced in i), no atomics. Pads (score 0, j>=N) contribute 0 since
// scores >= 0 and j >= N > i.
// =====================================================================
__global__ __launch_bounds__(BLOCK) void rankcount_kernel(
    const float* __restrict__ proposals,
    int* __restrict__ partial, int N, int imgs)
{
    const int bi = blockIdx.x, bj = blockIdx.y, img = blockIdx.z;
    const int t = threadIdx.x;
    const float* P = proposals + (size_t)img * N * 5;
    __shared__ unsigned sj[BLOCK];
    const int jbase = bj * BLOCK;
    {
        int j = jbase + t;
        sj[t] = (j < N) ? __float_as_uint(P[j*5 + 4]) : 0u;
    }
    __syncthreads();
    const int i = bi * BLOCK + t;
    if (i >= N) return;
    const unsigned my = __float_as_uint(P[i*5 + 4]);   // hides under count loop
    int p = 0;
    const uint4* s4 = (const uint4*)sj;
#pragma unroll
    for (int q = 0; q < BLOCK/4; ++q) {
        uint4 v = s4[q];
        int jj = jbase + q*4;
        p += (int)((v.x > my) | ((v.x == my) & (jj + 0 < i)));
        p += (int)((v.y > my) | ((v.y == my) & (jj + 1 < i)));
        p += (int)((v.z > my) | ((v.z == my) & (jj + 2 < i)));
        p += (int)((v.w > my) | ((v.w == my) & (jj + 3 < i)));
    }
    partial[((size_t)(img*RB + bj))*S2 + i] = p;
}

// =====================================================================
// K1b: sum partials -> position; gather payload; scatter to sorted SoA.
// =====================================================================
__global__ __launch_bounds__(BLOCK) void rankscatter_kernel(
    const float* __restrict__ pred, const int* __restrict__ gt_inds,
    const float* __restrict__ proposals, const int* __restrict__ partial,
    float* __restrict__ soa, int* __restrict__ sgt, int N, int imgs)
{
    const int img = blockIdx.y, t = threadIdx.x;
    const int i = blockIdx.x * BLOCK + t;
    const size_t stride = (size_t)imgs * S2;
    const size_t base   = (size_t)img * S2;

    if (i >= N) {
        if (i < S2) {
#pragma unroll
            for (int a = 0; a < 9; ++a) soa[(size_t)a*stride + base + i] = 0.f;
            sgt[base + i] = -1;
        }
        return;
    }

    const float* P = proposals + (size_t)img * N * 5;
    const float* E = pred      + (size_t)img * N * 4;
    const int*   G = gt_inds   + (size_t)img * N;

    // payload loads issue first; latency hides under the partial sum
    const float p0 = P[i*5+0], p1 = P[i*5+1], p2 = P[i*5+2],
                p3 = P[i*5+3], p4 = P[i*5+4];
    const float q0 = E[i*4+0], q1 = E[i*4+1], q2 = E[i*4+2], q3 = E[i*4+3];
    const int   gg = G[i];

    int p = 0;
#pragma unroll
    for (int b = 0; b < RB; ++b)
        p += partial[((size_t)(img*RB + b))*S2 + i];   // coalesced in i

    soa[0*stride + base + p] = p0;
    soa[1*stride + base + p] = p1;
    soa[2*stride + base + p] = p2;
    soa[3*stride + base + p] = p3;
    soa[4*stride + base + p] = p4;
    soa[5*stride + base + p] = q0;
    soa[6*stride + base + p] = q1;
    soa[7*stride + base + p] = q2;
    soa[8*stride + base + p] = q3;
    sgt[base + p] = gg;
}

// =====================================================================
// K2: suppression matrix, transposed layout supT[img][w][i] = bits over
// chunk-w elements j of sup(i,j) (valid by symmetry). Ballot runs over the
// 64 j-lanes for fixed i -> word jc of row i -> store supT[jc][i].
// Consumers only read supT[w][pos] for w <= pos>>6 -> only jc <= ic blocks.
// =====================================================================
__global__ __launch_bounds__(BLOCK) void supmat_kernel(
    const float* __restrict__ soa, unsigned long long* __restrict__ supT,
    int N, int imgs)
{
    const int ic = blockIdx.x, jc = blockIdx.y, img = blockIdx.z;
    if (ic < jc) return;   // only words w=jc <= ic = pos>>6 are ever read
    const int t = threadIdx.x, wave = t >> 6, lane = t & 63;
    const size_t stride = (size_t)imgs * S2, base = (size_t)img * S2;
    __shared__ float si[8][64];
    for (int idx = t; idx < 512; idx += BLOCK) {
        int f = idx >> 6, e = idx & 63;
        int a = (f < 4) ? f : f + 1;      // arrays {0,1,2,3,5,6,7,8}
        si[f][e] = soa[(size_t)a*stride + base + ic*64 + e];
    }
    __syncthreads();
    const int j = jc*64 + lane;
    const float jx1 = soa[0*stride+base+j], jy1 = soa[1*stride+base+j];
    const float jx2 = soa[2*stride+base+j], jy2 = soa[3*stride+base+j];
    const float j0  = soa[5*stride+base+j], j1  = soa[6*stride+base+j];
    const float j2  = soa[7*stride+base+j], j3  = soa[8*stride+base+j];
    const bool jin = (j < N);
    for (int ii = 0; ii < 16; ++ii) {
        int il = wave*16 + ii;
        int i  = ic*64 + il;
        float bx1 = si[0][il], by1 = si[1][il], bx2 = si[2][il], by2 = si[3][il];
        float f0  = si[4][il], f1  = si[5][il], f2  = si[6][il], f3  = si[7][il];
        bool s = false;
        if (jin && i < N) {
            float iw = fminf(jx2, bx2) - fmaxf(jx1, bx1);
            float ih = fminf(jy2, by2) - fmaxf(jy1, by1);
            if (iw > 0.f && ih > 0.f) {
                float d0 = j0-f0, d1 = j1-f1, d2 = j2-f2, d3 = j3-f3;
                float diff = 0.25f*(d0*d0 + d1*d1 + d2*d2 + d3*d3);
                s = diff < 0.1f;   // TAG_THR
            }
        }
        unsigned long long bb = __ballot(s);   // bits over j-lanes, fixed i
        if (lane == 0) supT[((size_t)img*NW + jc)*S2 + i] = bb;
    }
}

// =====================================================================
// K3: sequential chunked greedy, 256 threads per image, software-pipelined.
// =====================================================================
#define GREEDY_ISSUE(c, dst)                                                   \
    _Pragma("unroll")                                                          \
    for (int q = 0; q < 8; ++q) {                                              \
        int g = (c) + 1 + wave + 4*q;                                          \
        dst[q] = (g < NW) ? supT[matb + (size_t)(c)*S2 + g*64 + lane] : 0ull;  \
    }

#define GREEDY_STEP(c, cur, nxt)                                               \
    {                                                                          \
        if (wave == 0) {                                                       \
            const unsigned long long loc = sdiag[(c)*64 + lane];               \
            unsigned long long U = ~sdead[(c)];                                \
            unsigned long long sel = 0ull;                                     \
            while (U) {                                                        \
                bool inU = (U >> lane) & 1ull;                                 \
                unsigned long long A = __ballot(inU && ((loc & U & lowmask) == 0ull)); \
                sel |= A;                                                      \
                bool kill = inU && !((A >> lane) & 1ull) && ((loc & A) != 0ull); \
                unsigned long long K = __ballot(kill);                         \
                U &= ~(A | K);                                                 \
            }                                                                  \
            if (lane == 0) {                                                   \
                ssel_c = sel;                                                  \
                selw_out[(size_t)img*NW + (c)] = sel;                          \
            }                                                                  \
        }                                                                      \
        __syncthreads();                                                       \
        const unsigned long long sel = ssel_c;                                 \
        if ((c) + 1 < NCH) { GREEDY_ISSUE((c)+1, nxt) }                        \
        if (sel != 0ull) {                                                     \
            _Pragma("unroll")                                                  \
            for (int q = 0; q < 8; ++q) {                                      \
                int g = (c) + 1 + wave + 4*q;                                  \
                if (g < NW) {                                                  \
                    bool d = (cur[q] & sel) != 0ull;                           \
                    unsigned long long bb = __ballot(d);                       \
                    if (lane == 0 && bb) sdead[g] |= bb;                       \
                }                                                              \
            }                                                                  \
        }                                                                      \
        __syncthreads();                                                       \
    }

__global__ __launch_bounds__(BLOCK) void greedy_kernel(
    const unsigned long long* __restrict__ supT,
    const int* __restrict__ sgt, const float* __restrict__ soa,
    unsigned long long* __restrict__ selw_out, int imgs)
{
    const int img = blockIdx.x, t = threadIdx.x;
    const int lane = t & 63, wave = t >> 6;
    const size_t matb = (size_t)img * NW * S2;
    const size_t stride = (size_t)imgs * S2, base = (size_t)img * S2;
    __shared__ unsigned long long sdiag[S2];     // [c*64+l] = supT[c][c*64+l]
    __shared__ unsigned long long sdead[NW];
    __shared__ unsigned long long ssel_c;

    // preload all diagonal-block words (coalesced; one batched wait)
    for (int e = t; e < S2; e += BLOCK) {
        int c = e >> 6, l = e & 63;
        sdiag[e] = supT[matb + (size_t)c*S2 + c*64 + l];
    }
    // init dead = invalid (group-major so each wave's ballot covers a group)
    for (int g = wave; g < NW; g += NWAVES) {
        int j = g*64 + lane;
        int gg = sgt[base + j];
        float a = soa[1*stride + base + j];
        float b = soa[3*stride + base + j];
        bool invalid = !(gg >= 0 && (b - a) > 0.f);
        unsigned long long bb = __ballot(invalid);
        if (lane == 0) sdead[g] = bb;
    }
    __syncthreads();

    const unsigned long long lowmask = (lane == 0) ? 0ull : (~0ull >> (64 - lane));

    unsigned long long pfA[8], pfB[8];
    GREEDY_ISSUE(0, pfA)
    for (int cc = 0; cc < NCH; cc += 2) {
        GREEDY_STEP(cc,     pfA, pfB)
        GREEDY_STEP(cc + 1, pfB, pfA)
    }
}

// =====================================================================
// K4: merged eff + nsteps. One block per image. Scans only w <= j>>6.
// =====================================================================
__global__ __launch_bounds__(BLOCK) void effsteps_kernel(
    const unsigned long long* __restrict__ supT,
    const unsigned long long* __restrict__ selw,
    const int* __restrict__ sgt, const float* __restrict__ soa,
    int* __restrict__ eff, int* __restrict__ nsteps, int imgs)
{
    const int img = blockIdx.x, t = threadIdx.x;
    const int lane = t & 63, wave = t >> 6;
    const size_t stride = (size_t)imgs * S2, base = (size_t)img * S2;
    const unsigned long long* M = supT + (size_t)img * NW * S2;
    __shared__ unsigned long long ss[NW];
    __shared__ unsigned hist[S2];
    __shared__ int ints[2*NWAVES];
    __shared__ unsigned wsum[NWAVES];
    __shared__ int bm[NWAVES];
    if (t < NW) ss[t] = selw[(size_t)img*NW + t];
    for (int x = t; x < S2; x += BLOCK) hist[x] = 0u;
    __syncthreads();

    int myV = 0, mySc = 0;
#pragma unroll
    for (int k = 0; k < 8; ++k) {
        const int j = k*BLOCK + t;
        const int jw_ = j >> 6;
        int g = sgt[base + j];
        float a = soa[1*stride+base+j], b = soa[3*stride+base+j];
        bool valid = (g >= 0) && ((b - a) > 0.f);
        bool selb  = (ss[jw_] >> (j & 63)) & 1ull;
        int e;
        if (!valid) e = 0;
        else if (selb) { e = rank_of(ss, j); ++myV; ++mySc; }
        else {
            ++myV;
            int istar = -1;
#pragma unroll
            for (int w = 0; w < NW; ++w) {
                if (w <= jw_) {
                    unsigned long long f = M[(size_t)w*S2 + j] & ss[w];
                    if (istar < 0 && f) istar = w*64 + __builtin_ctzll(f);
                }
            }
            if (istar < 0) e = EFF_INF;
            else { e = rank_of(ss, istar) + 1; atomicAdd(&hist[e - 1], 1u); }
        }
        eff[(size_t)img*S2 + j] = e;
    }
    __syncthreads();

    int v = myV, sc = mySc;
    for (int o = 32; o > 0; o >>= 1) { v += __shfl_down(v, o); sc += __shfl_down(sc, o); }
    if (lane == 0) { ints[wave] = v; ints[NWAVES + wave] = sc; }
    __syncthreads();
    int V = 0, Sc = 0;
    for (int w = 0; w < NWAVES; ++w) { V += ints[w]; Sc += ints[NWAVES + w]; }

    unsigned loc[8]; unsigned s = 0;
#pragma unroll
    for (int k = 0; k < 8; ++k) { s += hist[t*8 + k]; loc[k] = s; }
    unsigned tot = s;
    for (int o = 1; o < 64; o <<= 1) {
        unsigned u = __shfl_up(tot, o);
        if (lane >= o) tot += u;
    }
    if (lane == 63) wsum[wave] = tot;
    __syncthreads();
    unsigned woff = 0;
    for (int w = 0; w < wave; ++w) woff += wsum[w];
    unsigned exclP = woff + tot - s;
    __syncthreads();
#pragma unroll
    for (int k = 0; k < 8; ++k) hist[t*8 + k] = exclP + loc[k];
    __syncthreads();

    int best = EFF_INF;
    for (int r = t; r < Sc; r += BLOCK) {
        unsigned rem = (r == 0) ? 0u : hist[r - 1];
        int alive = V - r - (int)rem;
        if (alive < 2) best = min(best, r);
    }
    for (int o = 32; o > 0; o >>= 1) best = min(best, __shfl_down(best, o));
    if (lane == 0) bm[wave] = best;
    __syncthreads();
    if (t == 0) {
        int b = bm[0];
        for (int w = 1; w < NWAVES; ++w) b = min(b, bm[w]);
        nsteps[img] = min(b, Sc);
    }
}

// =====================================================================
// K5: pair sums. Block = (16 selector slots, img); wave owns 4 slots in
// registers; per-block partials, no global atomics.
// =====================================================================
__global__ __launch_bounds__(BLOCK) void pairs_kernel(
    const float* __restrict__ soa, const int* __restrict__ sgt,
    const int* __restrict__ eff, const unsigned long long* __restrict__ selw,
    const int* __restrict__ nsteps, float* __restrict__ partials, int imgs)
{
    const int ic = blockIdx.x, img = blockIdx.y;
    const int t = threadIdx.x, wave = t >> 6, lane = t & 63;
    const size_t stride = (size_t)imgs * S2, base = (size_t)img * S2;
    __shared__ unsigned long long ss[NW];
    __shared__ float pw[NWAVES][4];
    __shared__ int anyact;
    if (t < NW) ss[t] = selw[(size_t)img*NW + t];
    if (t == 0) anyact = 0;
    __syncthreads();
    const int ns = nsteps[img];

    float bx1[4], by1[4], bx2[4], by2[4], f0[4], f1[4], f2[4], f3[4];
    int bgt[4], rk[4]; bool act[4];
    bool any = false;
#pragma unroll
    for (int u = 0; u < 4; ++u) {
        const int i = ic*SPB + wave*4 + u;
        bool selb = (ss[i>>6] >> (i & 63)) & 1ull;
        int r = rank_of(ss, i);
        rk[u] = r;
        act[u] = selb && (r < ns);
        any |= act[u];
        if (act[u]) {
            bx1[u] = soa[0*stride+base+i]; by1[u] = soa[1*stride+base+i];
            bx2[u] = soa[2*stride+base+i]; by2[u] = soa[3*stride+base+i];
            f0[u]  = soa[5*stride+base+i]; f1[u]  = soa[6*stride+base+i];
            f2[u]  = soa[7*stride+base+i]; f3[u]  = soa[8*stride+base+i];
            bgt[u] = sgt[base + i];
        } else {
            bx1[u]=by1[u]=bx2[u]=by2[u]=0.f; f0[u]=f1[u]=f2[u]=f3[u]=0.f; bgt[u]=-2;
        }
    }
    if (any && lane == 0) anyact = 1;   // benign same-value race
    __syncthreads();
    if (!anyact) {
        if (t < 4) partials[((size_t)img*PB + ic)*4 + t] = 0.f;
        return;
    }

    float ps[4] = {0,0,0,0}, pn[4] = {0,0,0,0}, qs[4] = {0,0,0,0}, qn[4] = {0,0,0,0};
    for (int jt = 0; jt < NCH; ++jt) {
        const int j = jt*64 + lane;
        const float jx1 = soa[0*stride+base+j], jy1 = soa[1*stride+base+j];
        const float jx2 = soa[2*stride+base+j], jy2 = soa[3*stride+base+j];
        const float jsc = soa[4*stride+base+j];
        const float j0  = soa[5*stride+base+j], j1  = soa[6*stride+base+j];
        const float j2  = soa[7*stride+base+j], j3  = soa[8*stride+base+j];
        const int   jgt = sgt[base + j];
        const int   jef = eff[(size_t)img*S2 + j];
#pragma unroll
        for (int u = 0; u < 4; ++u) {
            if (!act[u]) continue;                    // wave-uniform
            if (rk[u] < jef) {
                float iw = fminf(jx2, bx2[u]) - fmaxf(jx1, bx1[u]);
                float ih = fminf(jy2, by2[u]) - fmaxf(jy1, by1[u]);
                if (iw > 0.f && ih > 0.f) {
                    float d0 = j0 - f0[u], d1 = j1 - f1[u];
                    float d2 = j2 - f2[u], d3 = j3 - f3[u];
                    float diff = 0.25f*(d0*d0 + d1*d1 + d2*d2 + d3*d3);
                    bool check = diff < 0.1f;
                    bool same  = (jgt == bgt[u]);
                    if (same && !check)      { ps[u] += diff * jsc;       pn[u] += 1.f; }
                    else if (!same && check) { qs[u] += expf(-diff)*jsc;  qn[u] += 1.f; }
                }
            }
        }
    }

    float sPull = 0.f, cPull = 0.f, sPush = 0.f, cPush = 0.f;
#pragma unroll
    for (int u = 0; u < 4; ++u) {
        if (!act[u]) continue;                        // wave-uniform
        float a0 = ps[u], a1 = pn[u], a2 = qs[u], a3 = qn[u];
        for (int o = 32; o > 0; o >>= 1) {
            a0 += __shfl_down(a0, o); a1 += __shfl_down(a1, o);
            a2 += __shfl_down(a2, o); a3 += __shfl_down(a3, o);
        }
        if (lane == 0) {
            if (a1 > 0.f) { sPull += a0 / a1; cPull += 1.f; }
            if (a3 > 0.f) { sPush += a2 / a3; cPush += 1.f; }
        }
    }
    if (lane == 0) {
        pw[wave][0] = sPull; pw[wave][1] = cPull;
        pw[wave][2] = sPush; pw[wave][3] = cPush;
    }
    __syncthreads();
    if (t == 0) {
        float a = 0, b = 0, c = 0, d = 0;
        for (int w = 0; w < NWAVES; ++w) {
            a += pw[w][0]; b += pw[w][1]; c += pw[w][2]; d += pw[w][3];
        }
        float* p = partials + ((size_t)img*PB + ic)*4;
        p[0] = a; p[1] = b; p[2] = c; p[3] = d;
    }
}

// K6: sum per-block partials, form final losses.
__global__ __launch_bounds__(BLOCK) void finalize_kernel(
    const float* __restrict__ partials, float* __restrict__ out, int imgs)
{
    const int t = threadIdx.x;
    __shared__ float a[8][4];     // up to 8 images
    if (t < 32) ((float*)a)[t] = 0.f;
    __syncthreads();
    for (int e = t; e < imgs * PB; e += BLOCK) {
        int img = e / PB;
        const float* p = partials + (size_t)e * 4;
#pragma unroll
        for (int k = 0; k < 4; ++k) {
            float v = p[k];
            if (v != 0.f) atomicAdd(&a[img][k], v);
        }
    }
    __syncthreads();
    if (t == 0) {
        float push = 0.f, pull = 0.f;
        for (int i = 0; i < imgs; ++i) {
            pull += a[i][0] / (a[i][1] + 1e-6f);
            push += a[i][2] / (a[i][3] + 1e-6f);
        }
        out[0] = push / (float)imgs;   // push_loss
        out[1] = pull / (float)imgs;   // pull_loss
    }
}

// =====================================================================
// FALLBACK PATH (R1 kernel) — only if ws too small / N > 2048 / imgs > 8.
// =====================================================================
__global__ __launch_bounds__(BLOCK) void tagloss_kernel(
    const float* __restrict__ pred, const int* __restrict__ gt_inds,
    const float* __restrict__ proposals, float* __restrict__ ws, int N)
{
    const int img = blockIdx.x, t = threadIdx.x;
    const int lane = t & 63, wav = t >> 6;
    const float* P = proposals + (size_t)img * N * 5;
    const float* E = pred      + (size_t)img * N * 4;
    const int*   G = gt_inds   + (size_t)img * N;
    float x1[KMAX], y1[KMAX], x2[KMAX], y2[KMAX], sc[KMAX];
    float e0[KMAX], e1[KMAX], e2[KMAX], e3[KMAX];
    int gt[KMAX]; unsigned amask = 0u; int local_alive = 0;
#pragma unroll
    for (int k = 0; k < KMAX; ++k) {
        int j = k * BLOCK + t;
        if (j < N) {
            x1[k]=P[j*5+0]; y1[k]=P[j*5+1]; x2[k]=P[j*5+2]; y2[k]=P[j*5+3]; sc[k]=P[j*5+4];
            e0[k]=E[j*4+0]; e1[k]=E[j*4+1]; e2[k]=E[j*4+2]; e3[k]=E[j*4+3]; gt[k]=G[j];
            if (gt[k] >= 0 && (y2[k]-y1[k]) > 0.0f) { amask |= 1u<<k; local_alive++; }
        } else { x1[k]=y1[k]=x2[k]=y2[k]=0.f; sc[k]=0.f; e0[k]=e1[k]=e2[k]=e3[k]=0.f; gt[k]=-1; }
    }
    __shared__ unsigned long long s_key[NWAVES];
    __shared__ float s_b[9];
    __shared__ float s_part[NWAVES][5];
    int alive_count;
    {
        float v = (float)local_alive;
#pragma unroll
        for (int o = 32; o > 0; o >>= 1) v += __shfl_down(v, o);
        if (lane == 0) s_part[wav][0] = v;
        __syncthreads();
        float tot = 0.f;
        for (int w = 0; w < NWAVES; ++w) tot += s_part[w][0];
        alive_count = (int)tot;
    }
    float tot_pull=0.f, tot_push=0.f, pull_cnt=0.f, push_cnt=0.f;
    while (alive_count >= 2) {
        unsigned long long key = 0ull;
#pragma unroll
        for (int k = 0; k < KMAX; ++k)
            if (amask & (1u<<k)) {
                unsigned long long kk = ((unsigned long long)__float_as_uint(sc[k])<<32)
                                      | (unsigned long long)(0xFFFFFFFFu - (unsigned)(k*BLOCK+t));
                if (kk > key) key = kk;
            }
#pragma unroll
        for (int o = 32; o > 0; o >>= 1) {
            unsigned long long ok = __shfl_down(key, o);
            if (ok > key) key = ok;
        }
        if (lane == 0) s_key[wav] = key;
        __syncthreads();
        unsigned long long bk = s_key[0];
        for (int w = 1; w < NWAVES; ++w) if (s_key[w] > bk) bk = s_key[w];
        const int i = (int)(0xFFFFFFFFu - (unsigned)(bk & 0xFFFFFFFFull));
        if ((i & (BLOCK-1)) == t) {
            int k = i / BLOCK;
            s_b[0]=x1[k]; s_b[1]=y1[k]; s_b[2]=x2[k]; s_b[3]=y2[k];
            s_b[4]=e0[k]; s_b[5]=e1[k]; s_b[6]=e2[k]; s_b[7]=e3[k];
            s_b[8]=__int_as_float(gt[k]);
        }
        __syncthreads();
        const float bx1=s_b[0], by1=s_b[1], bx2=s_b[2], by2=s_b[3];
        const float f0=s_b[4], f1=s_b[5], f2=s_b[6], f3=s_b[7];
        const int bgt = __float_as_int(s_b[8]);
        const float areai = (bx2-bx1)*(by2-by1);
        float psum=0.f,qsum=0.f,pn=0.f,qn=0.f,scnt=0.f;
#pragma unroll
        for (int k = 0; k < KMAX; ++k) {
            if (!(amask & (1u<<k))) continue;
            int j = k*BLOCK+t;
            if (j == i) { amask &= ~(1u<<k); continue; }
            float iw = fmaxf(fminf(x2[k],bx2)-fmaxf(x1[k],bx1),0.f);
            float ih = fmaxf(fminf(y2[k],by2)-fmaxf(y1[k],by1),0.f);
            float inter = iw*ih;
            float uni = (x2[k]-x1[k])*(y2[k]-y1[k]) + areai - inter;
            float iou = inter / fmaxf(uni, 1e-12f);
            if (iou > 0.f) {
                float d0=e0[k]-f0,d1=e1[k]-f1,d2=e2[k]-f2,d3=e3[k]-f3;
                float diff = 0.25f*(d0*d0+d1*d1+d2*d2+d3*d3);
                bool check = diff < 0.1f;
                bool same = (gt[k]==bgt);
                if (same && !check) { psum += diff*sc[k]; pn += 1.f; }
                if (!same && check) { qsum += __expf(-diff)*sc[k]; qn += 1.f; }
                if (check)          { amask &= ~(1u<<k); scnt += 1.f; }
            }
        }
        float r0=psum,r1=pn,r2=qsum,r3=qn,r4=scnt;
#pragma unroll
        for (int o = 32; o > 0; o >>= 1) {
            r0+=__shfl_down(r0,o); r1+=__shfl_down(r1,o); r2+=__shfl_down(r2,o);
            r3+=__shfl_down(r3,o); r4+=__shfl_down(r4,o);
        }
        if (lane == 0) { s_part[wav][0]=r0;s_part[wav][1]=r1;s_part[wav][2]=r2;s_part[wav][3]=r3;s_part[wav][4]=r4; }
        __syncthreads();
        float T0=0,T1=0,T2=0,T3=0,T4=0;
        for (int w = 0; w < NWAVES; ++w) {
            T0+=s_part[w][0];T1+=s_part[w][1];T2+=s_part[w][2];T3+=s_part[w][3];T4+=s_part[w][4];
        }
        if (T1 > 0.f) { tot_pull += T0/T1; pull_cnt += 1.f; }
        if (T3 > 0.f) { tot_push += T2/T3; push_cnt += 1.f; }
        alive_count -= 1 + (int)T4;
    }
    if (t == 0) {
        ws[img*2+0] = tot_push / (push_cnt + 1e-6f);
        ws[img*2+1] = tot_pull / (pull_cnt + 1e-6f);
    }
}

__global__ void finalize_fb_kernel(const float* __restrict__ ws,
                                   float* __restrict__ out, int imgs)
{
    if (threadIdx.x == 0 && blockIdx.x == 0) {
        float push = 0.f, pull = 0.f;
        for (int k = 0; k < imgs; ++k) { push += ws[2*k]; pull += ws[2*k+1]; }
        out[0] = push / (float)imgs;
        out[1] = pull / (float)imgs;
    }
}

// =====================================================================
extern "C" void kernel_launch(void* const* d_in, const int* in_sizes, int n_in,
                              void* d_out, int out_size, void* d_ws, size_t ws_size,
                              hipStream_t stream) {
    const float* pred      = (const float*)d_in[0];
    const int*   gt_inds   = (const int*)  d_in[1];
    const float* proposals = (const float*)d_in[2];
    const int imgs = in_sizes[3] / 80;     // gt_bboxes (IMGS,20,4)
    const int N    = in_sizes[1] / imgs;   // gt_inds (IMGS,N)

    size_t off = 0;
    auto alloc = [&](size_t b) { size_t o = off; off += (b + 255) & ~(size_t)255; return o; };
    const size_t soa_off  = alloc((size_t)9 * imgs * S2 * 4);
    const size_t sgt_off  = alloc((size_t)imgs * S2 * 4);
    const size_t sel_off  = alloc((size_t)imgs * NW * 8);
    const size_t eff_off  = alloc((size_t)imgs * S2 * 4);
    const size_t sup_off  = alloc((size_t)imgs * S2 * NW * 8);
    const size_t nst_off  = alloc((size_t)imgs * 4);
    const size_t par_off  = alloc((size_t)imgs * PB * 16);
    const size_t rnk_off  = alloc((size_t)imgs * RB * S2 * 4);
    const size_t need = off;

    if (N <= S2 && imgs <= 8 && ws_size >= need) {
        char* w = (char*)d_ws;
        float*              soa  = (float*)(w + soa_off);
        int*                sgt  = (int*)(w + sgt_off);
        unsigned long long* sel  = (unsigned long long*)(w + sel_off);
        int*                eff  = (int*)(w + eff_off);
        unsigned long long* supT = (unsigned long long*)(w + sup_off);
        int*                nst  = (int*)(w + nst_off);
        float*              par  = (float*)(w + par_off);
        int*                rnk  = (int*)(w + rnk_off);

        rankcount_kernel<<<dim3(RB, RB, imgs), BLOCK, 0, stream>>>(
            proposals, rnk, N, imgs);
        rankscatter_kernel<<<dim3(RB, imgs), BLOCK, 0, stream>>>(
            pred, gt_inds, proposals, rnk, soa, sgt, N, imgs);
        supmat_kernel<<<dim3(NCH, NCH, imgs), BLOCK, 0, stream>>>(soa, supT, N, imgs);
        greedy_kernel<<<imgs, BLOCK, 0, stream>>>(supT, sgt, soa, sel, imgs);
        effsteps_kernel<<<imgs, BLOCK, 0, stream>>>(supT, sel, sgt, soa, eff, nst, imgs);
        pairs_kernel<<<dim3(PB, imgs), BLOCK, 0, stream>>>(soa, sgt, eff, sel,
                                                           nst, par, imgs);
        finalize_kernel<<<1, BLOCK, 0, stream>>>(par, (float*)d_out, imgs);
    } else {
        float* ws = (float*)d_ws;
        tagloss_kernel<<<imgs, BLOCK, 0, stream>>>(pred, gt_inds, proposals, ws, N);
        finalize_fb_kernel<<<1, 64, 0, stream>>>(ws, (float*)d_out, imgs);
    }
}

// Round 11
// 171.967 us; speedup vs baseline: 28.0350x; 1.0379x over previous
//
#include <hip/hip_runtime.h>
#include <stdint.h>

#define BLOCK 256
#define KMAX 8
#define NWAVES (BLOCK / 64)
#define S2 2048          // padded N (pow2); N=2000 fits
#define NW 32            // 64-bit words per row (S2/64)
#define NCH 32           // 64-element chunks (S2/64)
#define SPB 16           // selector slots per pairs-block
#define PB (S2 / SPB)    // pairs blocks per image (128)
#define RB (S2 / BLOCK)  // rank blocks / j-slices (8)
#define EFF_INF 0x7FFFFFFF

// rank(j) = number of selected elements with sorted index < j
__device__ inline int rank_of(const unsigned long long* ss, int j) {
    int jw = j >> 6, jb = j & 63;
    int rk = __popcll(ss[jw] & (jb ? (~0ull >> (64 - jb)) : 0ull));
    for (int w = 0; w < jw; ++w) rk += __popcll(ss[w]);
    return rk;
}

// =====================================================================
// K1a: rank counting, split over j-slices for parallelism.
// =====================================================================
__global__ __launch_bounds__(BLOCK) void rankcount_kernel(
    const float* __restrict__ proposals,
    int* __restrict__ partial, int N, int imgs)
{
    const int bi = blockIdx.x, bj = blockIdx.y, img = blockIdx.z;
    const int t = threadIdx.x;
    const float* P = proposals + (size_t)img * N * 5;
    __shared__ unsigned sj[BLOCK];
    const int jbase = bj * BLOCK;
    {
        int j = jbase + t;
        sj[t] = (j < N) ? __float_as_uint(P[j*5 + 4]) : 0u;
    }
    __syncthreads();
    const int i = bi * BLOCK + t;
    if (i >= N) return;
    const unsigned my = __float_as_uint(P[i*5 + 4]);
    int p = 0;
    const uint4* s4 = (const uint4*)sj;
#pragma unroll
    for (int q = 0; q < BLOCK/4; ++q) {
        uint4 v = s4[q];
        int jj = jbase + q*4;
        p += (int)((v.x > my) | ((v.x == my) & (jj + 0 < i)));
        p += (int)((v.y > my) | ((v.y == my) & (jj + 1 < i)));
        p += (int)((v.z > my) | ((v.z == my) & (jj + 2 < i)));
        p += (int)((v.w > my) | ((v.w == my) & (jj + 3 < i)));
    }
    partial[((size_t)(img*RB + bj))*S2 + i] = p;
}

// =====================================================================
// K1b: sum partials -> position; gather payload; scatter to sorted SoA.
// =====================================================================
__global__ __launch_bounds__(BLOCK) void rankscatter_kernel(
    const float* __restrict__ pred, const int* __restrict__ gt_inds,
    const float* __restrict__ proposals, const int* __restrict__ partial,
    float* __restrict__ soa, int* __restrict__ sgt, int N, int imgs)
{
    const int img = blockIdx.y, t = threadIdx.x;
    const int i = blockIdx.x * BLOCK + t;
    const size_t stride = (size_t)imgs * S2;
    const size_t base   = (size_t)img * S2;

    if (i >= N) {
        if (i < S2) {
#pragma unroll
            for (int a = 0; a < 9; ++a) soa[(size_t)a*stride + base + i] = 0.f;
            sgt[base + i] = -1;
        }
        return;
    }

    const float* P = proposals + (size_t)img * N * 5;
    const float* E = pred      + (size_t)img * N * 4;
    const int*   G = gt_inds   + (size_t)img * N;

    const float p0 = P[i*5+0], p1 = P[i*5+1], p2 = P[i*5+2],
                p3 = P[i*5+3], p4 = P[i*5+4];
    const float q0 = E[i*4+0], q1 = E[i*4+1], q2 = E[i*4+2], q3 = E[i*4+3];
    const int   gg = G[i];

    int p = 0;
#pragma unroll
    for (int b = 0; b < RB; ++b)
        p += partial[((size_t)(img*RB + b))*S2 + i];

    soa[0*stride + base + p] = p0;
    soa[1*stride + base + p] = p1;
    soa[2*stride + base + p] = p2;
    soa[3*stride + base + p] = p3;
    soa[4*stride + base + p] = p4;
    soa[5*stride + base + p] = q0;
    soa[6*stride + base + p] = q1;
    soa[7*stride + base + p] = q2;
    soa[8*stride + base + p] = q3;
    sgt[base + p] = gg;
}

// =====================================================================
// K2: suppression matrix, CHUNK-MAJOR layout ST[img][ci][w][l]:
// word w of row i = ci*64+l (bits over chunk-w j's). The block needed to
// resolve chunk c (w = 0..c) is contiguous (c+1)*512 B -> enables
// global_load_lds streaming in greedy. Only w=jc <= ic written (lower tri).
// =====================================================================
__global__ __launch_bounds__(BLOCK) void supmat_kernel(
    const float* __restrict__ soa, unsigned long long* __restrict__ supT,
    int N, int imgs)
{
    const int ic = blockIdx.x, jc = blockIdx.y, img = blockIdx.z;
    if (ic < jc) return;
    const int t = threadIdx.x, wave = t >> 6, lane = t & 63;
    const size_t stride = (size_t)imgs * S2, base = (size_t)img * S2;
    __shared__ float si[8][64];
    for (int idx = t; idx < 512; idx += BLOCK) {
        int f = idx >> 6, e = idx & 63;
        int a = (f < 4) ? f : f + 1;
        si[f][e] = soa[(size_t)a*stride + base + ic*64 + e];
    }
    __syncthreads();
    const int j = jc*64 + lane;
    const float jx1 = soa[0*stride+base+j], jy1 = soa[1*stride+base+j];
    const float jx2 = soa[2*stride+base+j], jy2 = soa[3*stride+base+j];
    const float j0  = soa[5*stride+base+j], j1  = soa[6*stride+base+j];
    const float j2  = soa[7*stride+base+j], j3  = soa[8*stride+base+j];
    const bool jin = (j < N);
    for (int ii = 0; ii < 16; ++ii) {
        int il = wave*16 + ii;
        int i  = ic*64 + il;
        float bx1 = si[0][il], by1 = si[1][il], bx2 = si[2][il], by2 = si[3][il];
        float f0  = si[4][il], f1  = si[5][il], f2  = si[6][il], f3  = si[7][il];
        bool s = false;
        if (jin && i < N) {
            float iw = fminf(jx2, bx2) - fmaxf(jx1, bx1);
            float ih = fminf(jy2, by2) - fmaxf(jy1, by1);
            if (iw > 0.f && ih > 0.f) {
                float d0 = j0-f0, d1 = j1-f1, d2 = j2-f2, d3 = j3-f3;
                float diff = 0.25f*(d0*d0 + d1*d1 + d2*d2 + d3*d3);
                s = diff < 0.1f;   // TAG_THR
            }
        }
        unsigned long long bb = __ballot(s);   // bits over j-lanes, fixed i
        if (lane == 0)
            supT[((size_t)img*NCH + ic)*(NW*64) + (size_t)jc*64 + il] = bb;
    }
}

// =====================================================================
// K3: greedy, SINGLE WAVE per image, barrier-free.
// Triple-buffered global_load_lds streaming of each chunk's contiguous
// block + manual fine-grained s_waitcnt vmcnt(N) (loads stay in flight
// across chunks; no register results -> no compiler auto-drain).
// =====================================================================
typedef __attribute__((address_space(1))) void* gas_vp;
typedef __attribute__((address_space(3))) void* las_vp;

#define SBW 2048                      // ull per staging buffer (16 KB)
#define LCNT(c) (((c) + 2) / 2)       // 1KB load_lds instructions for chunk c

#define GR_PRE(c)                                                              \
    {                                                                          \
        const unsigned long long* blk = MB + ((size_t)(c))*(NW*64);            \
        _Pragma("unroll")                                                      \
        for (int k = 0; k < LCNT(c); ++k) {                                    \
            __builtin_amdgcn_global_load_lds(                                  \
                (gas_vp)(blk + k*128 + l*2),                                   \
                (las_vp)(sbuf + ((c)%3)*SBW + k*128), 16, 0, 0);               \
        }                                                                      \
    }

#define GR_STEP(c)                                                             \
    {                                                                          \
        if ((c) + 2 < NCH) GR_PRE((c)+2)                                       \
        asm volatile("s_waitcnt vmcnt(%0)" :: "i"(                             \
            ((c)+2 < NCH) ? (LCNT((c)+1) + LCNT((c)+2)) :                      \
            (((c)+1 < NCH) ? LCNT((c)+1) : 0)) : "memory");                    \
        const unsigned long long* cb = sbuf + ((c)%3)*SBW;                     \
        unsigned long long acc = 0ull;                                         \
        _Pragma("unroll")                                                      \
        for (int w = 0; w < (c); ++w) acc |= cb[w*64 + l] & sselA[w];          \
        const unsigned long long loc = cb[(c)*64 + l];                         \
        bool alive = ((vmask >> (c)) & 1u) && (acc == 0ull);                   \
        unsigned long long U = __ballot(alive);                                \
        unsigned long long sel = 0ull;                                         \
        while (U) {                                                            \
            bool inU = (U >> l) & 1ull;                                        \
            unsigned long long A = __ballot(inU && ((loc & U & lowmask) == 0ull)); \
            sel |= A;                                                          \
            bool kill = inU && !((A >> l) & 1ull) && ((loc & A) != 0ull);      \
            unsigned long long K = __ballot(kill);                             \
            U &= ~(A | K);                                                     \
        }                                                                      \
        if (l == 0) sselA[(c)] = sel;                                          \
    }

__global__ __launch_bounds__(64) void greedy_kernel(
    const unsigned long long* __restrict__ supT,
    const int* __restrict__ sgt, const float* __restrict__ soa,
    unsigned long long* __restrict__ selw_out, int imgs)
{
    const int img = blockIdx.x, l = threadIdx.x;
    const size_t stride = (size_t)imgs * S2, base = (size_t)img * S2;
    const unsigned long long* MB = supT + (size_t)img * NCH * (NW*64);
    __shared__ __attribute__((aligned(16))) unsigned long long sbuf[3 * SBW];
    __shared__ unsigned long long sselA[NW];

    // per-lane validity bits (coalesced loads, consumed before streaming)
    unsigned vmask = 0u;
#pragma unroll
    for (int c = 0; c < NCH; ++c) {
        const int j = c*64 + l;
        int g = sgt[base + j];
        float a = soa[1*stride + base + j];
        float b = soa[3*stride + base + j];
        if (g >= 0 && (b - a) > 0.f) vmask |= (1u << c);
    }

    const unsigned long long lowmask = (l == 0) ? 0ull : (~0ull >> (64 - l));

    GR_PRE(0) GR_PRE(1)
    GR_STEP(0)  GR_STEP(1)  GR_STEP(2)  GR_STEP(3)
    GR_STEP(4)  GR_STEP(5)  GR_STEP(6)  GR_STEP(7)
    GR_STEP(8)  GR_STEP(9)  GR_STEP(10) GR_STEP(11)
    GR_STEP(12) GR_STEP(13) GR_STEP(14) GR_STEP(15)
    GR_STEP(16) GR_STEP(17) GR_STEP(18) GR_STEP(19)
    GR_STEP(20) GR_STEP(21) GR_STEP(22) GR_STEP(23)
    GR_STEP(24) GR_STEP(25) GR_STEP(26) GR_STEP(27)
    GR_STEP(28) GR_STEP(29) GR_STEP(30) GR_STEP(31)

    if (l < NW) selw_out[(size_t)img*NW + l] = sselA[l];
}

// =====================================================================
// K4: merged eff + nsteps. One block per image. Scans only w <= j>>6.
// (chunk-major index; M base offset identical to before since NCH*64 = S2)
// =====================================================================
__global__ __launch_bounds__(BLOCK) void effsteps_kernel(
    const unsigned long long* __restrict__ supT,
    const unsigned long long* __restrict__ selw,
    const int* __restrict__ sgt, const float* __restrict__ soa,
    int* __restrict__ eff, int* __restrict__ nsteps, int imgs)
{
    const int img = blockIdx.x, t = threadIdx.x;
    const int lane = t & 63, wave = t >> 6;
    const size_t stride = (size_t)imgs * S2, base = (size_t)img * S2;
    const unsigned long long* M = supT + (size_t)img * NW * S2;
    __shared__ unsigned long long ss[NW];
    __shared__ unsigned hist[S2];
    __shared__ int ints[2*NWAVES];
    __shared__ unsigned wsum[NWAVES];
    __shared__ int bm[NWAVES];
    if (t < NW) ss[t] = selw[(size_t)img*NW + t];
    for (int x = t; x < S2; x += BLOCK) hist[x] = 0u;
    __syncthreads();

    int myV = 0, mySc = 0;
#pragma unroll
    for (int k = 0; k < 8; ++k) {
        const int j = k*BLOCK + t;
        const int jw_ = j >> 6;
        int g = sgt[base + j];
        float a = soa[1*stride+base+j], b = soa[3*stride+base+j];
        bool valid = (g >= 0) && ((b - a) > 0.f);
        bool selb  = (ss[jw_] >> (j & 63)) & 1ull;
        int e;
        if (!valid) e = 0;
        else if (selb) { e = rank_of(ss, j); ++myV; ++mySc; }
        else {
            ++myV;
            int istar = -1;
#pragma unroll
            for (int w = 0; w < NW; ++w) {
                if (w <= jw_) {
                    unsigned long long f = M[((size_t)jw_*NW + w)*64 + (j & 63)] & ss[w];
                    if (istar < 0 && f) istar = w*64 + __builtin_ctzll(f);
                }
            }
            if (istar < 0) e = EFF_INF;
            else { e = rank_of(ss, istar) + 1; atomicAdd(&hist[e - 1], 1u); }
        }
        eff[(size_t)img*S2 + j] = e;
    }
    __syncthreads();

    int v = myV, sc = mySc;
    for (int o = 32; o > 0; o >>= 1) { v += __shfl_down(v, o); sc += __shfl_down(sc, o); }
    if (lane == 0) { ints[wave] = v; ints[NWAVES + wave] = sc; }
    __syncthreads();
    int V = 0, Sc = 0;
    for (int w = 0; w < NWAVES; ++w) { V += ints[w]; Sc += ints[NWAVES + w]; }

    unsigned loc[8]; unsigned s = 0;
#pragma unroll
    for (int k = 0; k < 8; ++k) { s += hist[t*8 + k]; loc[k] = s; }
    unsigned tot = s;
    for (int o = 1; o < 64; o <<= 1) {
        unsigned u = __shfl_up(tot, o);
        if (lane >= o) tot += u;
    }
    if (lane == 63) wsum[wave] = tot;
    __syncthreads();
    unsigned woff = 0;
    for (int w = 0; w < wave; ++w) woff += wsum[w];
    unsigned exclP = woff + tot - s;
    __syncthreads();
#pragma unroll
    for (int k = 0; k < 8; ++k) hist[t*8 + k] = exclP + loc[k];
    __syncthreads();

    int best = EFF_INF;
    for (int r = t; r < Sc; r += BLOCK) {
        unsigned rem = (r == 0) ? 0u : hist[r - 1];
        int alive = V - r - (int)rem;
        if (alive < 2) best = min(best, r);
    }
    for (int o = 32; o > 0; o >>= 1) best = min(best, __shfl_down(best, o));
    if (lane == 0) bm[wave] = best;
    __syncthreads();
    if (t == 0) {
        int b = bm[0];
        for (int w = 1; w < NWAVES; ++w) b = min(b, bm[w]);
        nsteps[img] = min(b, Sc);
    }
}

// =====================================================================
// K5: pair sums. Block = (16 selector slots, img); wave owns 4 slots in
// registers; per-block partials, no global atomics.
// =====================================================================
__global__ __launch_bounds__(BLOCK) void pairs_kernel(
    const float* __restrict__ soa, const int* __restrict__ sgt,
    const int* __restrict__ eff, const unsigned long long* __restrict__ selw,
    const int* __restrict__ nsteps, float* __restrict__ partials, int imgs)
{
    const int ic = blockIdx.x, img = blockIdx.y;
    const int t = threadIdx.x, wave = t >> 6, lane = t & 63;
    const size_t stride = (size_t)imgs * S2, base = (size_t)img * S2;
    __shared__ unsigned long long ss[NW];
    __shared__ float pw[NWAVES][4];
    __shared__ int anyact;
    if (t < NW) ss[t] = selw[(size_t)img*NW + t];
    if (t == 0) anyact = 0;
    __syncthreads();
    const int ns = nsteps[img];

    float bx1[4], by1[4], bx2[4], by2[4], f0[4], f1[4], f2[4], f3[4];
    int bgt[4], rk[4]; bool act[4];
    bool any = false;
#pragma unroll
    for (int u = 0; u < 4; ++u) {
        const int i = ic*SPB + wave*4 + u;
        bool selb = (ss[i>>6] >> (i & 63)) & 1ull;
        int r = rank_of(ss, i);
        rk[u] = r;
        act[u] = selb && (r < ns);
        any |= act[u];
        if (act[u]) {
            bx1[u] = soa[0*stride+base+i]; by1[u] = soa[1*stride+base+i];
            bx2[u] = soa[2*stride+base+i]; by2[u] = soa[3*stride+base+i];
            f0[u]  = soa[5*stride+base+i]; f1[u]  = soa[6*stride+base+i];
            f2[u]  = soa[7*stride+base+i]; f3[u]  = soa[8*stride+base+i];
            bgt[u] = sgt[base + i];
        } else {
            bx1[u]=by1[u]=bx2[u]=by2[u]=0.f; f0[u]=f1[u]=f2[u]=f3[u]=0.f; bgt[u]=-2;
        }
    }
    if (any && lane == 0) anyact = 1;   // benign same-value race
    __syncthreads();
    if (!anyact) {
        if (t < 4) partials[((size_t)img*PB + ic)*4 + t] = 0.f;
        return;
    }

    float ps[4] = {0,0,0,0}, pn[4] = {0,0,0,0}, qs[4] = {0,0,0,0}, qn[4] = {0,0,0,0};
    for (int jt = 0; jt < NCH; ++jt) {
        const int j = jt*64 + lane;
        const float jx1 = soa[0*stride+base+j], jy1 = soa[1*stride+base+j];
        const float jx2 = soa[2*stride+base+j], jy2 = soa[3*stride+base+j];
        const float jsc = soa[4*stride+base+j];
        const float j0  = soa[5*stride+base+j], j1  = soa[6*stride+base+j];
        const float j2  = soa[7*stride+base+j], j3  = soa[8*stride+base+j];
        const int   jgt = sgt[base + j];
        const int   jef = eff[(size_t)img*S2 + j];
#pragma unroll
        for (int u = 0; u < 4; ++u) {
            if (!act[u]) continue;                    // wave-uniform
            if (rk[u] < jef) {
                float iw = fminf(jx2, bx2[u]) - fmaxf(jx1, bx1[u]);
                float ih = fminf(jy2, by2[u]) - fmaxf(jy1, by1[u]);
                if (iw > 0.f && ih > 0.f) {
                    float d0 = j0 - f0[u], d1 = j1 - f1[u];
                    float d2 = j2 - f2[u], d3 = j3 - f3[u];
                    float diff = 0.25f*(d0*d0 + d1*d1 + d2*d2 + d3*d3);
                    bool check = diff < 0.1f;
                    bool same  = (jgt == bgt[u]);
                    if (same && !check)      { ps[u] += diff * jsc;       pn[u] += 1.f; }
                    else if (!same && check) { qs[u] += expf(-diff)*jsc;  qn[u] += 1.f; }
                }
            }
        }
    }

    float sPull = 0.f, cPull = 0.f, sPush = 0.f, cPush = 0.f;
#pragma unroll
    for (int u = 0; u < 4; ++u) {
        if (!act[u]) continue;                        // wave-uniform
        float a0 = ps[u], a1 = pn[u], a2 = qs[u], a3 = qn[u];
        for (int o = 32; o > 0; o >>= 1) {
            a0 += __shfl_down(a0, o); a1 += __shfl_down(a1, o);
            a2 += __shfl_down(a2, o); a3 += __shfl_down(a3, o);
        }
        if (lane == 0) {
            if (a1 > 0.f) { sPull += a0 / a1; cPull += 1.f; }
            if (a3 > 0.f) { sPush += a2 / a3; cPush += 1.f; }
        }
    }
    if (lane == 0) {
        pw[wave][0] = sPull; pw[wave][1] = cPull;
        pw[wave][2] = sPush; pw[wave][3] = cPush;
    }
    __syncthreads();
    if (t == 0) {
        float a = 0, b = 0, c = 0, d = 0;
        for (int w = 0; w < NWAVES; ++w) {
            a += pw[w][0]; b += pw[w][1]; c += pw[w][2]; d += pw[w][3];
        }
        float* p = partials + ((size_t)img*PB + ic)*4;
        p[0] = a; p[1] = b; p[2] = c; p[3] = d;
    }
}

// K6: sum per-block partials, form final losses.
__global__ __launch_bounds__(BLOCK) void finalize_kernel(
    const float* __restrict__ partials, float* __restrict__ out, int imgs)
{
    const int t = threadIdx.x;
    __shared__ float a[8][4];     // up to 8 images
    if (t < 32) ((float*)a)[t] = 0.f;
    __syncthreads();
    for (int e = t; e < imgs * PB; e += BLOCK) {
        int img = e / PB;
        const float* p = partials + (size_t)e * 4;
#pragma unroll
        for (int k = 0; k < 4; ++k) {
            float v = p[k];
            if (v != 0.f) atomicAdd(&a[img][k], v);
        }
    }
    __syncthreads();
    if (t == 0) {
        float push = 0.f, pull = 0.f;
        for (int i = 0; i < imgs; ++i) {
            pull += a[i][0] / (a[i][1] + 1e-6f);
            push += a[i][2] / (a[i][3] + 1e-6f);
        }
        out[0] = push / (float)imgs;   // push_loss
        out[1] = pull / (float)imgs;   // pull_loss
    }
}

// =====================================================================
// FALLBACK PATH (R1 kernel) — only if ws too small / N > 2048 / imgs > 8.
// =====================================================================
__global__ __launch_bounds__(BLOCK) void tagloss_kernel(
    const float* __restrict__ pred, const int* __restrict__ gt_inds,
    const float* __restrict__ proposals, float* __restrict__ ws, int N)
{
    const int img = blockIdx.x, t = threadIdx.x;
    const int lane = t & 63, wav = t >> 6;
    const float* P = proposals + (size_t)img * N * 5;
    const float* E = pred      + (size_t)img * N * 4;
    const int*   G = gt_inds   + (size_t)img * N;
    float x1[KMAX], y1[KMAX], x2[KMAX], y2[KMAX], sc[KMAX];
    float e0[KMAX], e1[KMAX], e2[KMAX], e3[KMAX];
    int gt[KMAX]; unsigned amask = 0u; int local_alive = 0;
#pragma unroll
    for (int k = 0; k < KMAX; ++k) {
        int j = k * BLOCK + t;
        if (j < N) {
            x1[k]=P[j*5+0]; y1[k]=P[j*5+1]; x2[k]=P[j*5+2]; y2[k]=P[j*5+3]; sc[k]=P[j*5+4];
            e0[k]=E[j*4+0]; e1[k]=E[j*4+1]; e2[k]=E[j*4+2]; e3[k]=E[j*4+3]; gt[k]=G[j];
            if (gt[k] >= 0 && (y2[k]-y1[k]) > 0.0f) { amask |= 1u<<k; local_alive++; }
        } else { x1[k]=y1[k]=x2[k]=y2[k]=0.f; sc[k]=0.f; e0[k]=e1[k]=e2[k]=e3[k]=0.f; gt[k]=-1; }
    }
    __shared__ unsigned long long s_key[NWAVES];
    __shared__ float s_b[9];
    __shared__ float s_part[NWAVES][5];
    int alive_count;
    {
        float v = (float)local_alive;
#pragma unroll
        for (int o = 32; o > 0; o >>= 1) v += __shfl_down(v, o);
        if (lane == 0) s_part[wav][0] = v;
        __syncthreads();
        float tot = 0.f;
        for (int w = 0; w < NWAVES; ++w) tot += s_part[w][0];
        alive_count = (int)tot;
    }
    float tot_pull=0.f, tot_push=0.f, pull_cnt=0.f, push_cnt=0.f;
    while (alive_count >= 2) {
        unsigned long long key = 0ull;
#pragma unroll
        for (int k = 0; k < KMAX; ++k)
            if (amask & (1u<<k)) {
                unsigned long long kk = ((unsigned long long)__float_as_uint(sc[k])<<32)
                                      | (unsigned long long)(0xFFFFFFFFu - (unsigned)(k*BLOCK+t));
                if (kk > key) key = kk;
            }
#pragma unroll
        for (int o = 32; o > 0; o >>= 1) {
            unsigned long long ok = __shfl_down(key, o);
            if (ok > key) key = ok;
        }
        if (lane == 0) s_key[wav] = key;
        __syncthreads();
        unsigned long long bk = s_key[0];
        for (int w = 1; w < NWAVES; ++w) if (s_key[w] > bk) bk = s_key[w];
        const int i = (int)(0xFFFFFFFFu - (unsigned)(bk & 0xFFFFFFFFull));
        if ((i & (BLOCK-1)) == t) {
            int k = i / BLOCK;
            s_b[0]=x1[k]; s_b[1]=y1[k]; s_b[2]=x2[k]; s_b[3]=y2[k];
            s_b[4]=e0[k]; s_b[5]=e1[k]; s_b[6]=e2[k]; s_b[7]=e3[k];
            s_b[8]=__int_as_float(gt[k]);
        }
        __syncthreads();
        const float bx1=s_b[0], by1=s_b[1], bx2=s_b[2], by2=s_b[3];
        const float f0=s_b[4], f1=s_b[5], f2=s_b[6], f3=s_b[7];
        const int bgt = __float_as_int(s_b[8]);
        const float areai = (bx2-bx1)*(by2-by1);
        float psum=0.f,qsum=0.f,pn=0.f,qn=0.f,scnt=0.f;
#pragma unroll
        for (int k = 0; k < KMAX; ++k) {
            if (!(amask & (1u<<k))) continue;
            int j = k*BLOCK+t;
            if (j == i) { amask &= ~(1u<<k); continue; }
            float iw = fmaxf(fminf(x2[k],bx2)-fmaxf(x1[k],bx1),0.f);
            float ih = fmaxf(fminf(y2[k],by2)-fmaxf(y1[k],by1),0.f);
            float inter = iw*ih;
            float uni = (x2[k]-x1[k])*(y2[k]-y1[k]) + areai - inter;
            float iou = inter / fmaxf(uni, 1e-12f);
            if (iou > 0.f) {
                float d0=e0[k]-f0,d1=e1[k]-f1,d2=e2[k]-f2,d3=e3[k]-f3;
                float diff = 0.25f*(d0*d0+d1*d1+d2*d2+d3*d3);
                bool check = diff < 0.1f;
                bool same = (gt[k]==bgt);
                if (same && !check) { psum += diff*sc[k]; pn += 1.f; }
                if (!same && check) { qsum += __expf(-diff)*sc[k]; qn += 1.f; }
                if (check)          { amask &= ~(1u<<k); scnt += 1.f; }
            }
        }
        float r0=psum,r1=pn,r2=qsum,r3=qn,r4=scnt;
#pragma unroll
        for (int o = 32; o > 0; o >>= 1) {
            r0+=__shfl_down(r0,o); r1+=__shfl_down(r1,o); r2+=__shfl_down(r2,o);
            r3+=__shfl_down(r3,o); r4+=__shfl_down(r4,o);
        }
        if (lane == 0) { s_part[wav][0]=r0;s_part[wav][1]=r1;s_part[wav][2]=r2;s_part[wav][3]=r3;s_part[wav][4]=r4; }
        __syncthreads();
        float T0=0,T1=0,T2=0,T3=0,T4=0;
        for (int w = 0; w < NWAVES; ++w) {
            T0+=s_part[w][0];T1+=s_part[w][1];T2+=s_part[w][2];T3+=s_part[w][3];T4+=s_part[w][4];
        }
        if (T1 > 0.f) { tot_pull += T0/T1; pull_cnt += 1.f; }
        if (T3 > 0.f) { tot_push += T2/T3; push_cnt += 1.f; }
        alive_count -= 1 + (int)T4;
    }
    if (t == 0) {
        ws[img*2+0] = tot_push / (push_cnt + 1e-6f);
        ws[img*2+1] = tot_pull / (pull_cnt + 1e-6f);
    }
}

__global__ void finalize_fb_kernel(const float* __restrict__ ws,
                                   float* __restrict__ out, int imgs)
{
    if (threadIdx.x == 0 && blockIdx.x == 0) {
        float push = 0.f, pull = 0.f;
        for (int k = 0; k < imgs; ++k) { push += ws[2*k]; pull += ws[2*k+1]; }
        out[0] = push / (float)imgs;
        out[1] = pull / (float)imgs;
    }
}

// =====================================================================
extern "C" void kernel_launch(void* const* d_in, const int* in_sizes, int n_in,
                              void* d_out, int out_size, void* d_ws, size_t ws_size,
                              hipStream_t stream) {
    const float* pred      = (const float*)d_in[0];
    const int*   gt_inds   = (const int*)  d_in[1];
    const float* proposals = (const float*)d_in[2];
    const int imgs = in_sizes[3] / 80;     // gt_bboxes (IMGS,20,4)
    const int N    = in_sizes[1] / imgs;   // gt_inds (IMGS,N)

    size_t off = 0;
    auto alloc = [&](size_t b) { size_t o = off; off += (b + 255) & ~(size_t)255; return o; };
    const size_t soa_off  = alloc((size_t)9 * imgs * S2 * 4);
    const size_t sgt_off  = alloc((size_t)imgs * S2 * 4);
    const size_t sel_off  = alloc((size_t)imgs * NW * 8);
    const size_t eff_off  = alloc((size_t)imgs * S2 * 4);
    const size_t sup_off  = alloc((size_t)imgs * S2 * NW * 8);
    const size_t nst_off  = alloc((size_t)imgs * 4);
    const size_t par_off  = alloc((size_t)imgs * PB * 16);
    const size_t rnk_off  = alloc((size_t)imgs * RB * S2 * 4);
    const size_t need = off;

    if (N <= S2 && imgs <= 8 && ws_size >= need) {
        char* w = (char*)d_ws;
        float*              soa  = (float*)(w + soa_off);
        int*                sgt  = (int*)(w + sgt_off);
        unsigned long long* sel  = (unsigned long long*)(w + sel_off);
        int*                eff  = (int*)(w + eff_off);
        unsigned long long* supT = (unsigned long long*)(w + sup_off);
        int*                nst  = (int*)(w + nst_off);
        float*              par  = (float*)(w + par_off);
        int*                rnk  = (int*)(w + rnk_off);

        rankcount_kernel<<<dim3(RB, RB, imgs), BLOCK, 0, stream>>>(
            proposals, rnk, N, imgs);
        rankscatter_kernel<<<dim3(RB, imgs), BLOCK, 0, stream>>>(
            pred, gt_inds, proposals, rnk, soa, sgt, N, imgs);
        supmat_kernel<<<dim3(NCH, NCH, imgs), BLOCK, 0, stream>>>(soa, supT, N, imgs);
        greedy_kernel<<<imgs, 64, 0, stream>>>(supT, sgt, soa, sel, imgs);
        effsteps_kernel<<<imgs, BLOCK, 0, stream>>>(supT, sel, sgt, soa, eff, nst, imgs);
        pairs_kernel<<<dim3(PB, imgs), BLOCK, 0, stream>>>(soa, sgt, eff, sel,
                                                           nst, par, imgs);
        finalize_kernel<<<1, BLOCK, 0, stream>>>(par, (float*)d_out, imgs);
    } else {
        float* ws = (float*)d_ws;
        tagloss_kernel<<<imgs, BLOCK, 0, stream>>>(pred, gt_inds, proposals, ws, N);
        finalize_fb_kernel<<<1, 64, 0, stream>>>(ws, (float*)d_out, imgs);
    }
}